// Round 3
// baseline (574.929 us; speedup 1.0000x reference)
//
#include <hip/hip_runtime.h>

typedef unsigned int uint;
typedef unsigned short ushort;

typedef __attribute__((ext_vector_type(8))) short bf8;
typedef __attribute__((ext_vector_type(4))) float f32x4;
typedef _Float16 half_t;
typedef __attribute__((ext_vector_type(2))) half_t h2;

__device__ __forceinline__ ushort f2bf(float f){
  uint u = __builtin_bit_cast(uint, f);
  u = u + 0x7FFFu + ((u >> 16) & 1u);
  return (ushort)(u >> 16);
}
__device__ __forceinline__ float bfl(uint u){ return __builtin_bit_cast(float, u << 16); }
__device__ __forceinline__ float bfh(uint u){ return __builtin_bit_cast(float, u & 0xFFFF0000u); }
__device__ __forceinline__ uint pkh2(float a, float b){
  return __builtin_bit_cast(uint, __builtin_amdgcn_cvt_pkrtz(a, b));
}
__device__ __forceinline__ float dot2u(uint w, uint v, float acc){
#if __has_builtin(__builtin_amdgcn_fdot2)
  return __builtin_amdgcn_fdot2(__builtin_bit_cast(h2, w), __builtin_bit_cast(h2, v), acc, false);
#else
  h2 a = __builtin_bit_cast(h2, w), b = __builtin_bit_cast(h2, v);
  return acc + (float)a[0]*(float)b[0] + (float)a[1]*(float)b[1];
#endif
}
__device__ __forceinline__ float sigmoidf_(float x){ return 1.0f/(1.0f + __expf(-x)); }
__device__ __forceinline__ float tanhf_(float x){
  x = fminf(15.0f, fmaxf(-15.0f, x));
  float t = __expf(-2.0f*x);
  return (1.0f - t)/(1.0f + t);
}

// ---------------- node prep: type = argmax(one-hot), compact masked (type<2) ----
__global__ __launch_bounds__(256) void k_prep(const float* __restrict__ x,
    int* __restrict__ typ, int* __restrict__ mlist, int* __restrict__ cnt, int N){
  int n = blockIdx.x*256 + threadIdx.x;
  if (n >= N) return;
  const float* xr = x + (size_t)n*16;
  int t = 0;
  #pragma unroll
  for (int i=0;i<16;i++) if (xr[i] > 0.5f) t = i;
  typ[n] = t;
  if (t < 2){
    int p = atomicAdd(cnt, 1);
    mlist[p] = n;
  }
}

// ---------------- convert weight matrices to bf16 ------------------------------
__global__ __launch_bounds__(256) void k_cvtw(
    const float* wq, const float* wk, const float* wv,
    const float* w1, const float* w2, const float* wih, const float* whh,
    ushort* oq, ushort* ok, ushort* ov, ushort* o1, ushort* o2, ushort* oih, ushort* ohh){
  int i = blockIdx.x*256 + threadIdx.x;
  int stride = gridDim.x*256;
  for (int j=i; j<16384; j+=stride){
    oq[j]=f2bf(wq[j]); ok[j]=f2bf(wk[j]); ov[j]=f2bf(wv[j]);
    o1[j]=f2bf(w1[j]); o2[j]=f2bf(w2[j]);
  }
  for (int j=i; j<49152; j+=stride){ oih[j]=f2bf(wih[j]); ohh[j]=f2bf(whh[j]); }
}

// ---------------- edge-feature table EF[512][128] = pe[et] + op_emb[op] --------
__global__ __launch_bounds__(256) void k_ef(const float* __restrict__ op_emb, ushort* __restrict__ EF){
  int idx = blockIdx.x*256 + threadIdx.x;
  if (idx >= 512*128) return;
  int i = idx >> 7, d = idx & 127;
  int et = i >> 4, op = i & 15;
  int j = d >> 1;
  float inv = __expf(-0.1439115683f * (float)j);   // 10000^(-j/64)
  float ang = (float)et * inv;
  float v = (d & 1) ? __cosf(ang) : __sinf(ang);
  EF[idx] = f2bf(v + op_emb[op*128 + d]);
}

// ---------------- generic bf16 MFMA GEMM: C[M,N] = act(A[M,128] @ B[N,128]^T + bias)
template<int RELU, int HASBIAS>
__global__ __launch_bounds__(256) void k_gemm(
    const ushort* __restrict__ A, const ushort* __restrict__ B,
    const float* __restrict__ bias, ushort* __restrict__ C, int M, int N){
  int lane = threadIdx.x & 63, wv = threadIdx.x >> 6;
  int tM = blockIdx.x*64 + (wv>>1)*32;
  int tN = blockIdx.y*64 + (wv&1)*32;
  int r16 = lane & 15, kg = (lane>>4)*8;
  f32x4 acc[2][2];
  #pragma unroll
  for (int i=0;i<2;i++)
    #pragma unroll
    for (int j=0;j<2;j++) acc[i][j] = (f32x4)0.0f;
  for (int k0=0;k0<128;k0+=32){
    bf8 a[2], b[2];
    #pragma unroll
    for (int i=0;i<2;i++){
      int row = tM + i*16 + r16; if (row > M-1) row = M-1;
      a[i] = *(const bf8*)(A + (size_t)row*128 + k0 + kg);
    }
    #pragma unroll
    for (int j=0;j<2;j++){
      int col = tN + j*16 + r16;
      b[j] = *(const bf8*)(B + (size_t)col*128 + k0 + kg);
    }
    #pragma unroll
    for (int i=0;i<2;i++)
      #pragma unroll
      for (int j=0;j<2;j++)
        acc[i][j] = __builtin_amdgcn_mfma_f32_16x16x32_bf16(a[i], b[j], acc[i][j], 0, 0, 0);
  }
  #pragma unroll
  for (int i=0;i<2;i++)
    #pragma unroll
    for (int j=0;j<2;j++){
      int col = tN + j*16 + r16;
      float bs = HASBIAS ? bias[col] : 0.0f;
      #pragma unroll
      for (int q=0;q<4;q++){
        int row = tM + i*16 + (lane>>4)*4 + q;
        if (row < M){
          float v = acc[i][j][q] + bs;
          if (RELU) v = fmaxf(v, 0.0f);
          C[(size_t)row*N + col] = f2bf(v);
        }
      }
    }
}

// ---------------- 2-layer GRU encoder: one 192-thread block per masked node ----
__global__ __launch_bounds__(192) void k_encoder(
    const float* __restrict__ sim_res, const int* __restrict__ seqlen,
    const float* __restrict__ Wih0, const float* __restrict__ Whh0,
    const float* __restrict__ bih0, const float* __restrict__ bhh0,
    const float* __restrict__ Wih1, const float* __restrict__ Whh1,
    const float* __restrict__ bih1, const float* __restrict__ bhh1,
    const int* __restrict__ mlist, const int* __restrict__ cntp,
    float* __restrict__ Hf, ushort* __restrict__ Hb){
  int b = blockIdx.x;
  if (b >= *cntp) return;
  int node = mlist[b];
  int r = threadIdx.x;   // gate row 0..191
  int T = *seqlen; if (T > 32) T = 32; if (T < 0) T = 0;

  // pack this row's weights into f16 pairs held in registers
  uint wih0[16], whh0[32], wih1[32], whh1[32];
  {
    const float4* p0 = (const float4*)(Wih0 + (size_t)r*32);
    #pragma unroll
    for (int m=0;m<8;m++){ float4 f = p0[m]; wih0[2*m] = pkh2(f.x,f.y); wih0[2*m+1] = pkh2(f.z,f.w); }
    const float4* p1 = (const float4*)(Whh0 + (size_t)r*64);
    #pragma unroll
    for (int m=0;m<16;m++){ float4 f = p1[m]; whh0[2*m] = pkh2(f.x,f.y); whh0[2*m+1] = pkh2(f.z,f.w); }
    const float4* p2 = (const float4*)(Wih1 + (size_t)r*64);
    #pragma unroll
    for (int m=0;m<16;m++){ float4 f = p2[m]; wih1[2*m] = pkh2(f.x,f.y); wih1[2*m+1] = pkh2(f.z,f.w); }
    const float4* p3 = (const float4*)(Whh1 + (size_t)r*64);
    #pragma unroll
    for (int m=0;m<16;m++){ float4 f = p3[m]; whh1[2*m] = pkh2(f.x,f.y); whh1[2*m+1] = pkh2(f.z,f.w); }
  }
  float bi0 = bih0[r], bh0 = bhh0[r], bi1 = bih1[r], bh1 = bhh1[r];

  __shared__ uint Xp[512];        // f16x2 pairs of x_t, [t][m], m<16
  __shared__ uint H0p[32], H1p[32];
  __shared__ float GI[192], GH[192];

  for (int i=r; i<T*16; i+=192){
    int t = i>>4, m = i&15;
    float2 v = *(const float2*)(sim_res + (size_t)node*1024 + t*32 + 2*m);
    Xp[i] = pkh2(v.x, v.y);
  }
  if (r < 32){ H0p[r] = 0u; H1p[r] = 0u; }
  float h0 = 0.f, h1 = 0.f;
  __syncthreads();

  for (int t=0; t<T; ++t){
    // ---- layer 0 gate rows
    float gi = bi0, gh = bh0;
    const uint* xp = Xp + t*16;
    #pragma unroll
    for (int m=0;m<16;m++) gi = dot2u(wih0[m], xp[m], gi);
    #pragma unroll
    for (int m=0;m<32;m++) gh = dot2u(whh0[m], H0p[m], gh);
    GI[r] = gi; GH[r] = gh;
    __syncthreads();
    if (r < 64){
      float g_r = sigmoidf_(GI[r] + GH[r]);
      float g_z = sigmoidf_(GI[64+r] + GH[64+r]);
      float g_n = tanhf_(GI[128+r] + g_r*GH[128+r]);
      h0 = (1.f - g_z)*g_n + g_z*h0;
      float o = __shfl_xor(h0, 1);
      if (!(r & 1)) H0p[r>>1] = pkh2(h0, o);
    }
    __syncthreads();
    // ---- layer 1 gate rows (input = new h0)
    float gi1 = bi1, gh1 = bh1;
    #pragma unroll
    for (int m=0;m<32;m++) gi1 = dot2u(wih1[m], H0p[m], gi1);
    #pragma unroll
    for (int m=0;m<32;m++) gh1 = dot2u(whh1[m], H1p[m], gh1);
    GI[r] = gi1; GH[r] = gh1;
    __syncthreads();
    if (r < 64){
      float g_r = sigmoidf_(GI[r] + GH[r]);
      float g_z = sigmoidf_(GI[64+r] + GH[64+r]);
      float g_n = tanhf_(GI[128+r] + g_r*GH[128+r]);
      h1 = (1.f - g_z)*g_n + g_z*h1;
      float o = __shfl_xor(h1, 1);
      if (!(r & 1)) H1p[r>>1] = pkh2(h1, o);
    }
    __syncthreads();
  }
  if (r < 64){
    Hf[(size_t)node*128 + r]      = h0;
    Hf[(size_t)node*128 + 64 + r] = h1;
    Hb[(size_t)node*128 + r]      = f2bf(h0);
    Hb[(size_t)node*128 + 64 + r] = f2bf(h1);
  }
}

// ---------------- CSR build -----------------------------------------------------
__global__ __launch_bounds__(256) void k_deg(const int* __restrict__ dst, int* __restrict__ deg, int E){
  int e = blockIdx.x*256 + threadIdx.x;
  if (e < E) atomicAdd(&deg[dst[e]], 1);
}

__global__ __launch_bounds__(1024) void k_scan(const int* __restrict__ deg,
    int* __restrict__ rowptr, int* __restrict__ cursor, int N){
  __shared__ int wsum[16];
  __shared__ int carry_s;
  int tid = threadIdx.x, lane = tid & 63, wid = tid >> 6;
  if (tid == 0) carry_s = 0;
  __syncthreads();
  int nch = (N + 1023) / 1024;
  for (int c=0; c<nch; ++c){
    int i = c*1024 + tid;
    int v = (i < N) ? deg[i] : 0;
    int x = v;
    #pragma unroll
    for (int off=1; off<64; off<<=1){
      int t = __shfl_up(x, off, 64);
      if (lane >= off) x += t;
    }
    if (lane == 63) wsum[wid] = x;
    __syncthreads();
    int base = carry_s;
    int woff = 0;
    for (int w2=0; w2<wid; ++w2) woff += wsum[w2];
    int excl = base + woff + x - v;
    if (i < N){ rowptr[i] = excl; cursor[i] = excl; }
    __syncthreads();
    if (tid == 0){
      int s = 0;
      for (int w2=0; w2<16; ++w2) s += wsum[w2];
      carry_s = base + s;
    }
    __syncthreads();
  }
  if (tid == 0) rowptr[N] = carry_s;
}

__global__ __launch_bounds__(256) void k_scatter(const int* __restrict__ src,
    const int* __restrict__ dst, const int* __restrict__ etype, const int* __restrict__ typ,
    int* __restrict__ cursor, int* __restrict__ es_src, int* __restrict__ es_tab, int E){
  int e = blockIdx.x*256 + threadIdx.x;
  if (e < E){
    int d = dst[e];
    int pos = atomicAdd(&cursor[d], 1);
    es_src[pos] = src[e];
    es_tab[pos] = etype[e]*16 + typ[d];
  }
}

// ---------------- attention: one wave per dst node, online softmax --------------
__global__ __launch_bounds__(256) void k_attn(
    const uint* __restrict__ Qn, const uint* __restrict__ Kn, const uint* __restrict__ Vn,
    const uint* __restrict__ Ktab, const uint* __restrict__ Vtab,
    const int* __restrict__ rowptr, const int* __restrict__ es_src, const int* __restrict__ es_tab,
    uint* __restrict__ aggr, int N){
  int w = threadIdx.x >> 6, lane = threadIdx.x & 63;
  int dst = blockIdx.x*4 + w;
  if (dst >= N) return;
  uint qu = Qn[(size_t)dst*64 + lane];
  const float scale = 0.08838834764831845f;  // 1/sqrt(128)
  float q0 = bfl(qu)*scale, q1 = bfh(qu)*scale;
  int s0 = rowptr[dst], s1 = rowptr[dst+1];
  float m = -1e30f, den = 0.f, a0 = 0.f, a1 = 0.f;
  for (int p = s0; p < s1; ++p){
    int src = es_src[p], tb = es_tab[p];
    uint ku = Kn[(size_t)src*64 + lane], kt = Ktab[(size_t)tb*64 + lane];
    float k0 = bfl(ku) + bfl(kt), k1 = bfh(ku) + bfh(kt);
    float s = q0*k0 + q1*k1;
    #pragma unroll
    for (int off=32; off; off>>=1) s += __shfl_xor(s, off);
    uint vu = Vn[(size_t)src*64 + lane], vt = Vtab[(size_t)tb*64 + lane];
    float v0 = bfl(vu) + bfl(vt), v1 = bfh(vu) + bfh(vt);
    float nm = fmaxf(m, s);
    float c  = __expf(m - nm);
    float pw = __expf(s - nm);
    den = den*c + pw;
    a0  = a0*c + pw*v0;
    a1  = a1*c + pw*v1;
    m = nm;
  }
  float inv = 1.0f/(den + 1e-9f);
  a0 *= inv; a1 *= inv;
  aggr[(size_t)dst*64 + lane] = ((uint)f2bf(a1) << 16) | (uint)f2bf(a0);
}

// ---------------- fused GRU cell: gi = Xin@Wih^T, gh = H@Whh^T, gate ------------
// NOTE: Hbf/Hb_out and Hf_in/Hf_out may alias (in-place round) — no __restrict__.
__global__ __launch_bounds__(256) void k_gru(
    const ushort* __restrict__ Xb, const ushort* Hbf,
    const ushort* __restrict__ Wih, const ushort* __restrict__ Whh,
    const float* __restrict__ bih, const float* __restrict__ bhh,
    const float* Hf_in, float* Hf_out, ushort* Hb_out, int M){
  int lane = threadIdx.x & 63, wv = threadIdx.x >> 6;
  int nb = blockIdx.x * 32;
  int r16 = lane & 15, kg = (lane>>4)*8;
  f32x4 gi[2][6], gh[2][6];
  #pragma unroll
  for (int i=0;i<2;i++)
    #pragma unroll
    for (int c=0;c<6;c++){ gi[i][c] = (f32x4)0.0f; gh[i][c] = (f32x4)0.0f; }
  int cts[6] = {2*wv, 2*wv+1, 2*wv+8, 2*wv+9, 2*wv+16, 2*wv+17};
  for (int k0=0;k0<128;k0+=32){
    bf8 ax[2], ah[2];
    #pragma unroll
    for (int i=0;i<2;i++){
      int row = nb + i*16 + r16; if (row > M-1) row = M-1;
      ax[i] = *(const bf8*)(Xb  + (size_t)row*128 + k0 + kg);
      ah[i] = *(const bf8*)(Hbf + (size_t)row*128 + k0 + kg);
    }
    #pragma unroll
    for (int c=0;c<6;c++){
      bf8 bi = *(const bf8*)(Wih + (size_t)(cts[c]*16 + r16)*128 + k0 + kg);
      bf8 bh = *(const bf8*)(Whh + (size_t)(cts[c]*16 + r16)*128 + k0 + kg);
      #pragma unroll
      for (int i=0;i<2;i++){
        gi[i][c] = __builtin_amdgcn_mfma_f32_16x16x32_bf16(ax[i], bi, gi[i][c], 0, 0, 0);
        gh[i][c] = __builtin_amdgcn_mfma_f32_16x16x32_bf16(ah[i], bh, gh[i][c], 0, 0, 0);
      }
    }
  }
  __syncthreads();   // all Hbf reads in this block done before in-place writes
  #pragma unroll
  for (int i=0;i<2;i++)
    #pragma unroll
    for (int p=0;p<2;p++){
      int jcol = (2*wv + p)*16 + r16;            // 0..127
      float bir = bih[jcol], biz = bih[128+jcol], bin = bih[256+jcol];
      float bhr = bhh[jcol], bhz = bhh[128+jcol], bhn = bhh[256+jcol];
      #pragma unroll
      for (int q=0;q<4;q++){
        int node = nb + i*16 + (lane>>4)*4 + q;
        if (node < M){
          float gr  = gi[i][p][q]   + bir + gh[i][p][q]   + bhr;
          float gz  = gi[i][2+p][q] + biz + gh[i][2+p][q] + bhz;
          float inn = gi[i][4+p][q] + bin;
          float hnn = gh[i][4+p][q] + bhn;
          float rr = sigmoidf_(gr), zz = sigmoidf_(gz);
          float nn = tanhf_(inn + rr*hnn);
          float h = Hf_in[(size_t)node*128 + jcol];
          float o = (1.f - zz)*nn + zz*h;
          Hf_out[(size_t)node*128 + jcol] = o;
          Hb_out[(size_t)node*128 + jcol] = f2bf(o);
        }
      }
    }
}

extern "C" void kernel_launch(void* const* d_in, const int* in_sizes, int n_in,
                              void* d_out, int out_size, void* d_ws, size_t ws_size,
                              hipStream_t stream){
  const float* x       = (const float*)d_in[0];
  const int*   ei      = (const int*)d_in[1];
  const int*   etype   = (const int*)d_in[2];
  const float* sim_res = (const float*)d_in[3];
  const int*   seqlen  = (const int*)d_in[4];
  const float* eWih0 = (const float*)d_in[5];
  const float* eWhh0 = (const float*)d_in[6];
  const float* ebih0 = (const float*)d_in[7];
  const float* ebhh0 = (const float*)d_in[8];
  const float* eWih1 = (const float*)d_in[9];
  const float* eWhh1 = (const float*)d_in[10];
  const float* ebih1 = (const float*)d_in[11];
  const float* ebhh1 = (const float*)d_in[12];
  const float* Wq = (const float*)d_in[13];
  const float* Wk = (const float*)d_in[14];
  const float* Wv = (const float*)d_in[15];
  const float* op_emb = (const float*)d_in[16];
  const float* W1 = (const float*)d_in[17];
  const float* b1 = (const float*)d_in[18];
  const float* W2 = (const float*)d_in[19];
  const float* b2 = (const float*)d_in[20];
  const float* gWih = (const float*)d_in[21];
  const float* gWhh = (const float*)d_in[22];
  const float* gbih = (const float*)d_in[23];
  const float* gbhh = (const float*)d_in[24];

  const int N = in_sizes[0] / 16;
  const int E = in_sizes[2];

  char* p = (char*)d_ws;
  auto take = [&](size_t b)->void*{ void* r = (void*)p; p += (b + 255) & ~(size_t)255; return r; };

  float*  Hf   = (float*) take((size_t)N*128*4);
  ushort* Hb   = (ushort*)take((size_t)N*128*2);
  ushort* Qn   = (ushort*)take((size_t)N*128*2);
  ushort* Kn   = (ushort*)take((size_t)N*128*2);
  ushort* Vn   = (ushort*)take((size_t)N*128*2);
  ushort* Ag   = (ushort*)take((size_t)N*128*2);
  ushort* T1   = (ushort*)take((size_t)N*128*2);
  ushort* Xin  = (ushort*)take((size_t)N*128*2);
  ushort* EF   = (ushort*)take((size_t)512*128*2);
  ushort* Ktab = (ushort*)take((size_t)512*128*2);
  ushort* Vtab = (ushort*)take((size_t)512*128*2);
  ushort* wq_b = (ushort*)take((size_t)16384*2);
  ushort* wk_b = (ushort*)take((size_t)16384*2);
  ushort* wv_b = (ushort*)take((size_t)16384*2);
  ushort* w1_b = (ushort*)take((size_t)16384*2);
  ushort* w2_b = (ushort*)take((size_t)16384*2);
  ushort* wih_b= (ushort*)take((size_t)49152*2);
  ushort* whh_b= (ushort*)take((size_t)49152*2);
  int* typ    = (int*)take((size_t)N*4);
  int* mlist  = (int*)take((size_t)N*4);
  int* cnt    = (int*)take(256);
  int* deg    = (int*)take((size_t)N*4);
  int* rowptr = (int*)take((size_t)(N+1)*4);
  int* cursor = (int*)take((size_t)N*4);
  int* es_src = (int*)take((size_t)E*4);
  int* es_tab = (int*)take((size_t)E*4);

  hipMemsetAsync(cnt, 0, 4, stream);
  hipMemsetAsync(deg, 0, (size_t)N*4, stream);
  hipMemsetAsync(Hf, 0, (size_t)N*128*4, stream);
  hipMemsetAsync(Hb, 0, (size_t)N*128*2, stream);

  k_prep<<<(N+255)/256, 256, 0, stream>>>(x, typ, mlist, cnt, N);
  k_cvtw<<<64, 256, 0, stream>>>(Wq, Wk, Wv, W1, W2, gWih, gWhh,
                                 wq_b, wk_b, wv_b, w1_b, w2_b, wih_b, whh_b);
  k_ef<<<(512*128+255)/256, 256, 0, stream>>>(op_emb, EF);
  dim3 gt(8, 2);
  k_gemm<0,0><<<gt, 256, 0, stream>>>(EF, wk_b, nullptr, Ktab, 512, 128);
  k_gemm<0,0><<<gt, 256, 0, stream>>>(EF, wv_b, nullptr, Vtab, 512, 128);
  k_encoder<<<N, 192, 0, stream>>>(sim_res, seqlen, eWih0, eWhh0, ebih0, ebhh0,
                                   eWih1, eWhh1, ebih1, ebhh1, mlist, cnt, Hf, Hb);
  k_deg<<<(E+255)/256, 256, 0, stream>>>(ei + E, deg, E);
  k_scan<<<1, 1024, 0, stream>>>(deg, rowptr, cursor, N);
  k_scatter<<<(E+255)/256, 256, 0, stream>>>(ei, ei + E, etype, typ, cursor, es_src, es_tab, E);

  dim3 g1((N+63)/64, 2);
  for (int r=0; r<2; ++r){
    k_gemm<0,0><<<g1, 256, 0, stream>>>(Hb, wq_b, nullptr, Qn, N, 128);
    k_gemm<0,0><<<g1, 256, 0, stream>>>(Hb, wk_b, nullptr, Kn, N, 128);
    k_gemm<0,0><<<g1, 256, 0, stream>>>(Hb, wv_b, nullptr, Vn, N, 128);
    k_attn<<<(N+3)/4, 256, 0, stream>>>((const uint*)Qn, (const uint*)Kn, (const uint*)Vn,
        (const uint*)Ktab, (const uint*)Vtab, rowptr, es_src, es_tab, (uint*)Ag, N);
    k_gemm<1,1><<<g1, 256, 0, stream>>>(Ag, w1_b, b1, T1, N, 128);
    k_gemm<0,1><<<g1, 256, 0, stream>>>(T1, w2_b, b2, Xin, N, 128);
    float* hf_out = (r == 1) ? (float*)d_out : Hf;
    k_gru<<<(N+31)/32, 256, 0, stream>>>(Xin, Hb, wih_b, whh_b, gbih, gbhh,
                                         Hf, hf_out, Hb, N);
  }
}

// Round 4
// 473.211 us; speedup vs baseline: 1.2150x; 1.2150x over previous
//
#include <hip/hip_runtime.h>

typedef unsigned int uint;
typedef unsigned short ushort;

typedef __attribute__((ext_vector_type(8))) short bf8;
typedef __attribute__((ext_vector_type(4))) float f32x4;
typedef _Float16 half_t;
typedef __attribute__((ext_vector_type(8))) half_t h8;

__device__ __forceinline__ ushort f2bf(float f){
  uint u = __builtin_bit_cast(uint, f);
  u = u + 0x7FFFu + ((u >> 16) & 1u);
  return (ushort)(u >> 16);
}
__device__ __forceinline__ float bfl(uint u){ return __builtin_bit_cast(float, u << 16); }
__device__ __forceinline__ float bfh(uint u){ return __builtin_bit_cast(float, u & 0xFFFF0000u); }
__device__ __forceinline__ float sigmoidf_(float x){ return 1.0f/(1.0f + __expf(-x)); }
__device__ __forceinline__ float tanhf_(float x){
  x = fminf(15.0f, fmaxf(-15.0f, x));
  float t = __expf(-2.0f*x);
  return (1.0f - t)/(1.0f + t);
}
__device__ __forceinline__ f32x4 mfma_f16(h8 a, h8 b, f32x4 c){
  return __builtin_amdgcn_mfma_f32_16x16x32_f16(a, b, c, 0, 0, 0);
}

// ---------------- node prep: type = argmax(one-hot), compact masked (type<2) ----
__global__ __launch_bounds__(256) void k_prep(const float* __restrict__ x,
    int* __restrict__ typ, int* __restrict__ mlist, int* __restrict__ cnt, int N){
  int n = blockIdx.x*256 + threadIdx.x;
  if (n >= N) return;
  const float* xr = x + (size_t)n*16;
  int t = 0;
  #pragma unroll
  for (int i=0;i<16;i++) if (xr[i] > 0.5f) t = i;
  typ[n] = t;
  if (t < 2){
    int p = atomicAdd(cnt, 1);
    mlist[p] = n;
  }
}

// ---------------- convert weight matrices to bf16 ------------------------------
__global__ __launch_bounds__(256) void k_cvtw(
    const float* wq, const float* wk, const float* wv,
    const float* w1, const float* w2, const float* wih, const float* whh,
    ushort* oq, ushort* ok, ushort* ov, ushort* o1, ushort* o2, ushort* oih, ushort* ohh){
  int i = blockIdx.x*256 + threadIdx.x;
  int stride = gridDim.x*256;
  for (int j=i; j<16384; j+=stride){
    oq[j]=f2bf(wq[j]); ok[j]=f2bf(wk[j]); ov[j]=f2bf(wv[j]);
    o1[j]=f2bf(w1[j]); o2[j]=f2bf(w2[j]);
  }
  for (int j=i; j<49152; j+=stride){ oih[j]=f2bf(wih[j]); ohh[j]=f2bf(whh[j]); }
}

// ---------------- edge-feature table EF[512][128] = pe[et] + op_emb[op] --------
__global__ __launch_bounds__(256) void k_ef(const float* __restrict__ op_emb, ushort* __restrict__ EF){
  int idx = blockIdx.x*256 + threadIdx.x;
  if (idx >= 512*128) return;
  int i = idx >> 7, d = idx & 127;
  int et = i >> 4, op = i & 15;
  int j = d >> 1;
  float inv = __expf(-0.1439115683f * (float)j);   // 10000^(-j/64)
  float ang = (float)et * inv;
  float v = (d & 1) ? __cosf(ang) : __sinf(ang);
  EF[idx] = f2bf(v + op_emb[op*128 + d]);
}

// ---------------- generic bf16 MFMA GEMM: C[M,N] = act(A[M,128] @ B[N,128]^T + bias)
template<int RELU, int HASBIAS>
__global__ __launch_bounds__(256) void k_gemm(
    const ushort* __restrict__ A, const ushort* __restrict__ B,
    const float* __restrict__ bias, ushort* __restrict__ C, int M, int N){
  int lane = threadIdx.x & 63, wv = threadIdx.x >> 6;
  int tM = blockIdx.x*64 + (wv>>1)*32;
  int tN = blockIdx.y*64 + (wv&1)*32;
  int r16 = lane & 15, kg = (lane>>4)*8;
  f32x4 acc[2][2];
  #pragma unroll
  for (int i=0;i<2;i++)
    #pragma unroll
    for (int j=0;j<2;j++) acc[i][j] = (f32x4)0.0f;
  for (int k0=0;k0<128;k0+=32){
    bf8 a[2], b[2];
    #pragma unroll
    for (int i=0;i<2;i++){
      int row = tM + i*16 + r16; if (row > M-1) row = M-1;
      a[i] = *(const bf8*)(A + (size_t)row*128 + k0 + kg);
    }
    #pragma unroll
    for (int j=0;j<2;j++){
      int col = tN + j*16 + r16;
      b[j] = *(const bf8*)(B + (size_t)col*128 + k0 + kg);
    }
    #pragma unroll
    for (int i=0;i<2;i++)
      #pragma unroll
      for (int j=0;j<2;j++)
        acc[i][j] = __builtin_amdgcn_mfma_f32_16x16x32_bf16(a[i], b[j], acc[i][j], 0, 0, 0);
  }
  #pragma unroll
  for (int i=0;i<2;i++)
    #pragma unroll
    for (int j=0;j<2;j++){
      int col = tN + j*16 + r16;
      float bs = HASBIAS ? bias[col] : 0.0f;
      #pragma unroll
      for (int q=0;q<4;q++){
        int row = tM + i*16 + (lane>>4)*4 + q;
        if (row < M){
          float v = acc[i][j][q] + bs;
          if (RELU) v = fmaxf(v, 0.0f);
          C[(size_t)row*N + col] = f2bf(v);
        }
      }
    }
}

// ---------------- MFMA-batched 2-layer GRU encoder ------------------------------
// 32 masked nodes per block, 4 waves. Per step: gi/gh via 16x16x32 f16 MFMA,
// gate phase through LDS. h-state: f32 master in LDS + f16 swizzled copy for MFMA A.
#define GIS 196   // padded f32 stride for GI/GH (196 % 32 == 4 -> bank spread)
__global__ __launch_bounds__(256, 1) void k_enc2(
    const float* __restrict__ sim_res, const int* __restrict__ seqlen,
    const float* __restrict__ Wih0, const float* __restrict__ Whh0,
    const float* __restrict__ bih0, const float* __restrict__ bhh0,
    const float* __restrict__ Wih1, const float* __restrict__ Whh1,
    const float* __restrict__ bih1, const float* __restrict__ bhh1,
    const int* __restrict__ mlist, const int* __restrict__ cntp,
    float* __restrict__ Hf, ushort* __restrict__ Hb){
  int C = *cntp;
  int base = blockIdx.x * 32;
  if (base >= C || C == 0) return;
  int tid = threadIdx.x;
  int w = tid >> 6, lane = tid & 63;
  int r16 = lane & 15, kq = lane >> 4;

  __shared__ int nod[32];
  __shared__ float GI[32*GIS], GH[32*GIS];
  __shared__ __align__(16) ushort H0h[32*64], H1h[32*64];  // f16, 128B rows, XOR-swizzled
  __shared__ float H0f[32*64], H1f[32*64];                 // f32 master state

  if (tid < 32){
    int idx = base + tid;
    nod[tid] = mlist[idx < C ? idx : (C-1)];
  }
  for (int i = tid; i < 32*64; i += 256){
    H0h[i] = 0; H1h[i] = 0; H0f[i] = 0.f; H1f[i] = 0.f;
  }

  // ---- per-wave weight B-fragments (cols = gate rows (3w+nf)*16 + r16) ----
  h8 Bih0[3], Bhh0[3][2], Bih1[3][2], Bhh1[3][2];
  float bi0[3], bh0[3], bi1[3], bh1[3];
  #pragma unroll
  for (int nf=0; nf<3; ++nf){
    int g = (w*3+nf)*16 + r16;
    {
      f32x4 f0 = *(const f32x4*)(Wih0 + (size_t)g*32 + kq*8);
      f32x4 f1 = *(const f32x4*)(Wih0 + (size_t)g*32 + kq*8 + 4);
      h8 v;
      #pragma unroll
      for (int j=0;j<4;j++){ v[j] = (half_t)f0[j]; v[4+j] = (half_t)f1[j]; }
      Bih0[nf] = v;
    }
    #pragma unroll
    for (int ks=0; ks<2; ++ks){
      {
        f32x4 f0 = *(const f32x4*)(Whh0 + (size_t)g*64 + ks*32 + kq*8);
        f32x4 f1 = *(const f32x4*)(Whh0 + (size_t)g*64 + ks*32 + kq*8 + 4);
        h8 v;
        #pragma unroll
        for (int j=0;j<4;j++){ v[j] = (half_t)f0[j]; v[4+j] = (half_t)f1[j]; }
        Bhh0[nf][ks] = v;
      }
      {
        f32x4 f0 = *(const f32x4*)(Wih1 + (size_t)g*64 + ks*32 + kq*8);
        f32x4 f1 = *(const f32x4*)(Wih1 + (size_t)g*64 + ks*32 + kq*8 + 4);
        h8 v;
        #pragma unroll
        for (int j=0;j<4;j++){ v[j] = (half_t)f0[j]; v[4+j] = (half_t)f1[j]; }
        Bih1[nf][ks] = v;
      }
      {
        f32x4 f0 = *(const f32x4*)(Whh1 + (size_t)g*64 + ks*32 + kq*8);
        f32x4 f1 = *(const f32x4*)(Whh1 + (size_t)g*64 + ks*32 + kq*8 + 4);
        h8 v;
        #pragma unroll
        for (int j=0;j<4;j++){ v[j] = (half_t)f0[j]; v[4+j] = (half_t)f1[j]; }
        Bhh1[nf][ks] = v;
      }
    }
    bi0[nf] = bih0[g]; bh0[nf] = bhh0[g];
    bi1[nf] = bih1[g]; bh1[nf] = bhh1[g];
  }

  int T = *seqlen; if (T > 32) T = 32; if (T < 0) T = 0;
  __syncthreads();

  // x prefetch (f32, converted at use). Wave reads 16 full 128B lines per frag.
  f32x4 xpA[2], xpB[2];
  if (T > 0){
    #pragma unroll
    for (int i=0;i<2;i++){
      int node = nod[i*16 + r16];
      const float* s = sim_res + (size_t)node*1024 + kq*8;
      xpA[i] = *(const f32x4*)s;
      xpB[i] = *(const f32x4*)(s+4);
    }
  }

  for (int t=0; t<T; ++t){
    // ===== P1: layer-0 MFMA: gi = x@Wih0^T + bi0, gh = h0@Whh0^T + bh0 =====
    f32x4 gi[2][3], gh[2][3];
    #pragma unroll
    for (int i=0;i<2;i++)
      #pragma unroll
      for (int nf=0;nf<3;nf++){ gi[i][nf] = (f32x4)(bi0[nf]); gh[i][nf] = (f32x4)(bh0[nf]); }
    h8 xa[2];
    #pragma unroll
    for (int i=0;i<2;i++){
      h8 v;
      #pragma unroll
      for (int j=0;j<4;j++){ v[j] = (half_t)xpA[i][j]; v[4+j] = (half_t)xpB[i][j]; }
      xa[i] = v;
    }
    h8 ha[2][2];
    #pragma unroll
    for (int i=0;i<2;i++)
      #pragma unroll
      for (int ks=0;ks<2;ks++){
        int row = i*16 + r16;
        int off = row*128 + ((ks*64 + kq*16) ^ ((row&7)<<4));
        ha[i][ks] = *(const h8*)((const char*)H0h + off);
      }
    #pragma unroll
    for (int i=0;i<2;i++)
      #pragma unroll
      for (int nf=0;nf<3;nf++){
        gi[i][nf] = mfma_f16(xa[i], Bih0[nf], gi[i][nf]);
        gh[i][nf] = mfma_f16(ha[i][0], Bhh0[nf][0], gh[i][nf]);
        gh[i][nf] = mfma_f16(ha[i][1], Bhh0[nf][1], gh[i][nf]);
      }
    // prefetch x for t+1 (latency hidden under gate/layer-1 phases)
    if (t+1 < T){
      #pragma unroll
      for (int i=0;i<2;i++){
        int node = nod[i*16 + r16];
        const float* s = sim_res + (size_t)node*1024 + (t+1)*32 + kq*8;
        xpA[i] = *(const f32x4*)s;
        xpB[i] = *(const f32x4*)(s+4);
      }
    }
    #pragma unroll
    for (int i=0;i<2;i++)
      #pragma unroll
      for (int nf=0;nf<3;nf++){
        int col = (w*3+nf)*16 + r16;
        #pragma unroll
        for (int q=0;q<4;q++){
          int n = i*16 + kq*4 + q;
          GI[n*GIS + col] = gi[i][nf][q];
          GH[n*GIS + col] = gh[i][nf][q];
        }
      }
    __syncthreads();

    // ===== P2: layer-0 gates =====
    #pragma unroll
    for (int it=0; it<8; ++it){
      int n = it*4 + w, j = lane;
      float gr  = GI[n*GIS + j]      + GH[n*GIS + j];
      float gz  = GI[n*GIS + 64 + j] + GH[n*GIS + 64 + j];
      float inn = GI[n*GIS + 128 + j];
      float hnn = GH[n*GIS + 128 + j];
      float rr = sigmoidf_(gr), zz = sigmoidf_(gz);
      float nn = tanhf_(inn + rr*hnn);
      float h  = H0f[n*64 + j];
      float o  = (1.f - zz)*nn + zz*h;
      H0f[n*64 + j] = o;
      *(ushort*)((char*)H0h + n*128 + ((j*2) ^ ((n&7)<<4))) = __builtin_bit_cast(ushort, (half_t)o);
    }
    __syncthreads();

    // ===== P3: layer-1 MFMA: gi = h0_new@Wih1^T + bi1, gh = h1@Whh1^T + bh1 =====
    #pragma unroll
    for (int i=0;i<2;i++)
      #pragma unroll
      for (int nf=0;nf<3;nf++){ gi[i][nf] = (f32x4)(bi1[nf]); gh[i][nf] = (f32x4)(bh1[nf]); }
    h8 h0a[2][2], h1a[2][2];
    #pragma unroll
    for (int i=0;i<2;i++)
      #pragma unroll
      for (int ks=0;ks<2;ks++){
        int row = i*16 + r16;
        int off = row*128 + ((ks*64 + kq*16) ^ ((row&7)<<4));
        h0a[i][ks] = *(const h8*)((const char*)H0h + off);
        h1a[i][ks] = *(const h8*)((const char*)H1h + off);
      }
    #pragma unroll
    for (int i=0;i<2;i++)
      #pragma unroll
      for (int nf=0;nf<3;nf++){
        gi[i][nf] = mfma_f16(h0a[i][0], Bih1[nf][0], gi[i][nf]);
        gi[i][nf] = mfma_f16(h0a[i][1], Bih1[nf][1], gi[i][nf]);
        gh[i][nf] = mfma_f16(h1a[i][0], Bhh1[nf][0], gh[i][nf]);
        gh[i][nf] = mfma_f16(h1a[i][1], Bhh1[nf][1], gh[i][nf]);
      }
    #pragma unroll
    for (int i=0;i<2;i++)
      #pragma unroll
      for (int nf=0;nf<3;nf++){
        int col = (w*3+nf)*16 + r16;
        #pragma unroll
        for (int q=0;q<4;q++){
          int n = i*16 + kq*4 + q;
          GI[n*GIS + col] = gi[i][nf][q];
          GH[n*GIS + col] = gh[i][nf][q];
        }
      }
    __syncthreads();

    // ===== P4: layer-1 gates =====
    #pragma unroll
    for (int it=0; it<8; ++it){
      int n = it*4 + w, j = lane;
      float gr  = GI[n*GIS + j]      + GH[n*GIS + j];
      float gz  = GI[n*GIS + 64 + j] + GH[n*GIS + 64 + j];
      float inn = GI[n*GIS + 128 + j];
      float hnn = GH[n*GIS + 128 + j];
      float rr = sigmoidf_(gr), zz = sigmoidf_(gz);
      float nn = tanhf_(inn + rr*hnn);
      float h  = H1f[n*64 + j];
      float o  = (1.f - zz)*nn + zz*h;
      H1f[n*64 + j] = o;
      *(ushort*)((char*)H1h + n*128 + ((j*2) ^ ((n&7)<<4))) = __builtin_bit_cast(ushort, (half_t)o);
    }
    __syncthreads();
  }

  // ===== final write: enc = [h0, h1] for valid slots =====
  #pragma unroll
  for (int it=0; it<8; ++it){
    int n = it*4 + w, j = lane;
    if (base + n < C){
      int node = nod[n];
      float h0 = H0f[n*64 + j], h1 = H1f[n*64 + j];
      Hf[(size_t)node*128 + j]      = h0;
      Hf[(size_t)node*128 + 64 + j] = h1;
      Hb[(size_t)node*128 + j]      = f2bf(h0);
      Hb[(size_t)node*128 + 64 + j] = f2bf(h1);
    }
  }
}

// ---------------- CSR build -----------------------------------------------------
__global__ __launch_bounds__(256) void k_deg(const int* __restrict__ dst, int* __restrict__ deg, int E){
  int e = blockIdx.x*256 + threadIdx.x;
  if (e < E) atomicAdd(&deg[dst[e]], 1);
}

__global__ __launch_bounds__(1024) void k_scan(const int* __restrict__ deg,
    int* __restrict__ rowptr, int* __restrict__ cursor, int N){
  __shared__ int wsum[16];
  __shared__ int carry_s;
  int tid = threadIdx.x, lane = tid & 63, wid = tid >> 6;
  if (tid == 0) carry_s = 0;
  __syncthreads();
  int nch = (N + 1023) / 1024;
  for (int c=0; c<nch; ++c){
    int i = c*1024 + tid;
    int v = (i < N) ? deg[i] : 0;
    int x = v;
    #pragma unroll
    for (int off=1; off<64; off<<=1){
      int t = __shfl_up(x, off, 64);
      if (lane >= off) x += t;
    }
    if (lane == 63) wsum[wid] = x;
    __syncthreads();
    int base = carry_s;
    int woff = 0;
    for (int w2=0; w2<wid; ++w2) woff += wsum[w2];
    int excl = base + woff + x - v;
    if (i < N){ rowptr[i] = excl; cursor[i] = excl; }
    __syncthreads();
    if (tid == 0){
      int s = 0;
      for (int w2=0; w2<16; ++w2) s += wsum[w2];
      carry_s = base + s;
    }
    __syncthreads();
  }
  if (tid == 0) rowptr[N] = carry_s;
}

__global__ __launch_bounds__(256) void k_scatter(const int* __restrict__ src,
    const int* __restrict__ dst, const int* __restrict__ etype, const int* __restrict__ typ,
    int* __restrict__ cursor, int* __restrict__ es_src, int* __restrict__ es_tab, int E){
  int e = blockIdx.x*256 + threadIdx.x;
  if (e < E){
    int d = dst[e];
    int pos = atomicAdd(&cursor[d], 1);
    es_src[pos] = src[e];
    es_tab[pos] = etype[e]*16 + typ[d];
  }
}

// ---------------- attention: one wave per dst node, online softmax --------------
// QKV rows: [q(64 uint) | k(64 uint) | v(64 uint)] = 192 uints per node
__global__ __launch_bounds__(256) void k_attn(
    const uint* __restrict__ QKV,
    const uint* __restrict__ Ktab, const uint* __restrict__ Vtab,
    const int* __restrict__ rowptr, const int* __restrict__ es_src, const int* __restrict__ es_tab,
    uint* __restrict__ aggr, int N){
  int w = threadIdx.x >> 6, lane = threadIdx.x & 63;
  int dst = blockIdx.x*4 + w;
  if (dst >= N) return;
  uint qu = QKV[(size_t)dst*192 + lane];
  const float scale = 0.08838834764831845f;  // 1/sqrt(128)
  float q0 = bfl(qu)*scale, q1 = bfh(qu)*scale;
  int s0 = rowptr[dst], s1 = rowptr[dst+1];
  float m = -1e30f, den = 0.f, a0 = 0.f, a1 = 0.f;
  for (int p = s0; p < s1; ++p){
    int src = es_src[p], tb = es_tab[p];
    uint ku = QKV[(size_t)src*192 + 64 + lane], kt = Ktab[(size_t)tb*64 + lane];
    float k0 = bfl(ku) + bfl(kt), k1 = bfh(ku) + bfh(kt);
    float s = q0*k0 + q1*k1;
    #pragma unroll
    for (int off=32; off; off>>=1) s += __shfl_xor(s, off);
    uint vu = QKV[(size_t)src*192 + 128 + lane], vt = Vtab[(size_t)tb*64 + lane];
    float v0 = bfl(vu) + bfl(vt), v1 = bfh(vu) + bfh(vt);
    float nm = fmaxf(m, s);
    float c  = __expf(m - nm);
    float pw = __expf(s - nm);
    den = den*c + pw;
    a0  = a0*c + pw*v0;
    a1  = a1*c + pw*v1;
    m = nm;
  }
  float inv = 1.0f/(den + 1e-9f);
  a0 *= inv; a1 *= inv;
  aggr[(size_t)dst*64 + lane] = ((uint)f2bf(a1) << 16) | (uint)f2bf(a0);
}

// ---------------- fused GRU cell: gi = Xin@Wih^T, gh = H@Whh^T, gate ------------
// NOTE: Hbf/Hb_out and Hf_in/Hf_out may alias (in-place round) — no __restrict__.
__global__ __launch_bounds__(256) void k_gru(
    const ushort* __restrict__ Xb, const ushort* Hbf,
    const ushort* __restrict__ Wih, const ushort* __restrict__ Whh,
    const float* __restrict__ bih, const float* __restrict__ bhh,
    const float* Hf_in, float* Hf_out, ushort* Hb_out, int M){
  int lane = threadIdx.x & 63, wv = threadIdx.x >> 6;
  int nb = blockIdx.x * 32;
  int r16 = lane & 15, kg = (lane>>4)*8;
  f32x4 gi[2][6], gh[2][6];
  #pragma unroll
  for (int i=0;i<2;i++)
    #pragma unroll
    for (int c=0;c<6;c++){ gi[i][c] = (f32x4)0.0f; gh[i][c] = (f32x4)0.0f; }
  int cts[6] = {2*wv, 2*wv+1, 2*wv+8, 2*wv+9, 2*wv+16, 2*wv+17};
  for (int k0=0;k0<128;k0+=32){
    bf8 ax[2], ah[2];
    #pragma unroll
    for (int i=0;i<2;i++){
      int row = nb + i*16 + r16; if (row > M-1) row = M-1;
      ax[i] = *(const bf8*)(Xb  + (size_t)row*128 + k0 + kg);
      ah[i] = *(const bf8*)(Hbf + (size_t)row*128 + k0 + kg);
    }
    #pragma unroll
    for (int c=0;c<6;c++){
      bf8 bi = *(const bf8*)(Wih + (size_t)(cts[c]*16 + r16)*128 + k0 + kg);
      bf8 bh = *(const bf8*)(Whh + (size_t)(cts[c]*16 + r16)*128 + k0 + kg);
      #pragma unroll
      for (int i=0;i<2;i++){
        gi[i][c] = __builtin_amdgcn_mfma_f32_16x16x32_bf16(ax[i], bi, gi[i][c], 0, 0, 0);
        gh[i][c] = __builtin_amdgcn_mfma_f32_16x16x32_bf16(ah[i], bh, gh[i][c], 0, 0, 0);
      }
    }
  }
  __syncthreads();   // all Hbf reads in this block done before in-place writes
  #pragma unroll
  for (int i=0;i<2;i++)
    #pragma unroll
    for (int p=0;p<2;p++){
      int jcol = (2*wv + p)*16 + r16;            // 0..127
      float bir = bih[jcol], biz = bih[128+jcol], bin = bih[256+jcol];
      float bhr = bhh[jcol], bhz = bhh[128+jcol], bhn = bhh[256+jcol];
      #pragma unroll
      for (int q=0;q<4;q++){
        int node = nb + i*16 + (lane>>4)*4 + q;
        if (node < M){
          float gr  = gi[i][p][q]   + bir + gh[i][p][q]   + bhr;
          float gz  = gi[i][2+p][q] + biz + gh[i][2+p][q] + bhz;
          float inn = gi[i][4+p][q] + bin;
          float hnn = gh[i][4+p][q] + bhn;
          float rr = sigmoidf_(gr), zz = sigmoidf_(gz);
          float nn = tanhf_(inn + rr*hnn);
          float h = Hf_in[(size_t)node*128 + jcol];
          float o = (1.f - zz)*nn + zz*h;
          Hf_out[(size_t)node*128 + jcol] = o;
          Hb_out[(size_t)node*128 + jcol] = f2bf(o);
        }
      }
    }
}

extern "C" void kernel_launch(void* const* d_in, const int* in_sizes, int n_in,
                              void* d_out, int out_size, void* d_ws, size_t ws_size,
                              hipStream_t stream){
  const float* x       = (const float*)d_in[0];
  const int*   ei      = (const int*)d_in[1];
  const int*   etype   = (const int*)d_in[2];
  const float* sim_res = (const float*)d_in[3];
  const int*   seqlen  = (const int*)d_in[4];
  const float* eWih0 = (const float*)d_in[5];
  const float* eWhh0 = (const float*)d_in[6];
  const float* ebih0 = (const float*)d_in[7];
  const float* ebhh0 = (const float*)d_in[8];
  const float* eWih1 = (const float*)d_in[9];
  const float* eWhh1 = (const float*)d_in[10];
  const float* ebih1 = (const float*)d_in[11];
  const float* ebhh1 = (const float*)d_in[12];
  const float* Wq = (const float*)d_in[13];
  const float* Wk = (const float*)d_in[14];
  const float* Wv = (const float*)d_in[15];
  const float* op_emb = (const float*)d_in[16];
  const float* W1 = (const float*)d_in[17];
  const float* b1 = (const float*)d_in[18];
  const float* W2 = (const float*)d_in[19];
  const float* b2 = (const float*)d_in[20];
  const float* gWih = (const float*)d_in[21];
  const float* gWhh = (const float*)d_in[22];
  const float* gbih = (const float*)d_in[23];
  const float* gbhh = (const float*)d_in[24];

  const int N = in_sizes[0] / 16;
  const int E = in_sizes[2];

  char* p = (char*)d_ws;
  auto take = [&](size_t b)->void*{ void* r = (void*)p; p += (b + 255) & ~(size_t)255; return r; };

  float*  Hf   = (float*) take((size_t)N*128*4);
  ushort* Hb   = (ushort*)take((size_t)N*128*2);
  ushort* QKV  = (ushort*)take((size_t)N*384*2);
  ushort* Ag   = (ushort*)take((size_t)N*128*2);
  ushort* T1   = (ushort*)take((size_t)N*128*2);
  ushort* Xin  = (ushort*)take((size_t)N*128*2);
  ushort* EF   = (ushort*)take((size_t)512*128*2);
  ushort* Ktab = (ushort*)take((size_t)512*128*2);
  ushort* Vtab = (ushort*)take((size_t)512*128*2);
  ushort* wqkv = (ushort*)take((size_t)3*16384*2);   // [wq | wk | wv] rows
  ushort* w1_b = (ushort*)take((size_t)16384*2);
  ushort* w2_b = (ushort*)take((size_t)16384*2);
  ushort* wih_b= (ushort*)take((size_t)49152*2);
  ushort* whh_b= (ushort*)take((size_t)49152*2);
  int* typ    = (int*)take((size_t)N*4);
  int* mlist  = (int*)take((size_t)N*4);
  int* cnt    = (int*)take(256);
  int* deg    = (int*)take((size_t)N*4);
  int* rowptr = (int*)take((size_t)(N+1)*4);
  int* cursor = (int*)take((size_t)N*4);
  int* es_src = (int*)take((size_t)E*4);
  int* es_tab = (int*)take((size_t)E*4);

  ushort* wq_b = wqkv;
  ushort* wk_b = wqkv + 16384;
  ushort* wv_b = wqkv + 32768;

  hipMemsetAsync(cnt, 0, 4, stream);
  hipMemsetAsync(deg, 0, (size_t)N*4, stream);
  hipMemsetAsync(Hf, 0, (size_t)N*128*4, stream);
  hipMemsetAsync(Hb, 0, (size_t)N*128*2, stream);

  k_prep<<<(N+255)/256, 256, 0, stream>>>(x, typ, mlist, cnt, N);
  k_cvtw<<<64, 256, 0, stream>>>(Wq, Wk, Wv, W1, W2, gWih, gWhh,
                                 wq_b, wk_b, wv_b, w1_b, w2_b, wih_b, whh_b);
  k_ef<<<(512*128+255)/256, 256, 0, stream>>>(op_emb, EF);
  dim3 gt(8, 2);
  k_gemm<0,0><<<gt, 256, 0, stream>>>(EF, wk_b, nullptr, Ktab, 512, 128);
  k_gemm<0,0><<<gt, 256, 0, stream>>>(EF, wv_b, nullptr, Vtab, 512, 128);
  k_enc2<<<(N+31)/32, 256, 0, stream>>>(sim_res, seqlen, eWih0, eWhh0, ebih0, ebhh0,
                                        eWih1, eWhh1, ebih1, ebhh1, mlist, cnt, Hf, Hb);
  k_deg<<<(E+255)/256, 256, 0, stream>>>(ei + E, deg, E);
  k_scan<<<1, 1024, 0, stream>>>(deg, rowptr, cursor, N);
  k_scatter<<<(E+255)/256, 256, 0, stream>>>(ei, ei + E, etype, typ, cursor, es_src, es_tab, E);

  dim3 gq((N+63)/64, 6);   // fused QKV: N_out = 384
  dim3 g1((N+63)/64, 2);
  for (int r=0; r<2; ++r){
    k_gemm<0,0><<<gq, 256, 0, stream>>>(Hb, wqkv, nullptr, QKV, N, 384);
    k_attn<<<(N+3)/4, 256, 0, stream>>>((const uint*)QKV,
        (const uint*)Ktab, (const uint*)Vtab, rowptr, es_src, es_tab, (uint*)Ag, N);
    k_gemm<1,1><<<g1, 256, 0, stream>>>(Ag, w1_b, b1, T1, N, 128);
    k_gemm<0,1><<<g1, 256, 0, stream>>>(T1, w2_b, b2, Xin, N, 128);
    float* hf_out = (r == 1) ? (float*)d_out : Hf;
    k_gru<<<(N+31)/32, 256, 0, stream>>>(Xin, Hb, wih_b, whh_b, gbih, gbhh,
                                         Hf, hf_out, Hb, N);
  }
}

// Round 6
// 397.193 us; speedup vs baseline: 1.4475x; 1.1914x over previous
//
#include <hip/hip_runtime.h>

typedef unsigned int uint;
typedef unsigned short ushort;

typedef __attribute__((ext_vector_type(8))) short bf8;
typedef __attribute__((ext_vector_type(4))) float f32x4;
typedef _Float16 half_t;
typedef __attribute__((ext_vector_type(8))) half_t h8;

__device__ __forceinline__ ushort f2bf(float f){
  uint u = __builtin_bit_cast(uint, f);
  u = u + 0x7FFFu + ((u >> 16) & 1u);
  return (ushort)(u >> 16);
}
__device__ __forceinline__ float bfl(uint u){ return __builtin_bit_cast(float, u << 16); }
__device__ __forceinline__ float bfh(uint u){ return __builtin_bit_cast(float, u & 0xFFFF0000u); }
__device__ __forceinline__ uint pkhalf(float a, float b){
  ushort lo = __builtin_bit_cast(ushort, (half_t)a);
  ushort hi = __builtin_bit_cast(ushort, (half_t)b);
  return (uint)lo | ((uint)hi << 16);
}
__device__ __forceinline__ float sigmoidf_(float x){ return 1.0f/(1.0f + __expf(-x)); }
__device__ __forceinline__ float tanhf_(float x){
  x = fminf(15.0f, fmaxf(-15.0f, x));
  float t = __expf(-2.0f*x);
  return (1.0f - t)/(1.0f + t);
}
__device__ __forceinline__ f32x4 mfma_f16(h8 a, h8 b, f32x4 c){
  return __builtin_amdgcn_mfma_f32_16x16x32_f16(a, b, c, 0, 0, 0);
}
// load 8 consecutive f32 -> h8 (f16)
__device__ __forceinline__ h8 ldw8(const float* p){
  f32x4 a = *(const f32x4*)p, b = *(const f32x4*)(p+4);
  h8 v;
  #pragma unroll
  for (int j=0;j<4;j++){ v[j] = (half_t)a[j]; v[4+j] = (half_t)b[j]; }
  return v;
}

// ---------------- node prep: type = argmax(one-hot), compact masked (type<2) ----
__global__ __launch_bounds__(256) void k_prep(const float* __restrict__ x,
    int* __restrict__ typ, int* __restrict__ mlist, int* __restrict__ cnt, int N){
  int n = blockIdx.x*256 + threadIdx.x;
  if (n >= N) return;
  const float* xr = x + (size_t)n*16;
  int t = 0;
  #pragma unroll
  for (int i=0;i<16;i++) if (xr[i] > 0.5f) t = i;
  typ[n] = t;
  if (t < 2){
    int p = atomicAdd(cnt, 1);
    mlist[p] = n;
  }
}

// ---------------- convert weight matrices to bf16 ------------------------------
__global__ __launch_bounds__(256) void k_cvtw(
    const float* wq, const float* wk, const float* wv,
    const float* w1, const float* w2, const float* wih, const float* whh,
    ushort* oq, ushort* ok, ushort* ov, ushort* o1, ushort* o2, ushort* oih, ushort* ohh){
  int i = blockIdx.x*256 + threadIdx.x;
  int stride = gridDim.x*256;
  for (int j=i; j<16384; j+=stride){
    oq[j]=f2bf(wq[j]); ok[j]=f2bf(wk[j]); ov[j]=f2bf(wv[j]);
    o1[j]=f2bf(w1[j]); o2[j]=f2bf(w2[j]);
  }
  for (int j=i; j<49152; j+=stride){ oih[j]=f2bf(wih[j]); ohh[j]=f2bf(whh[j]); }
}

// ---------------- edge-feature table EF[512][128] = pe[et] + op_emb[op] --------
__global__ __launch_bounds__(256) void k_ef(const float* __restrict__ op_emb, ushort* __restrict__ EF){
  int idx = blockIdx.x*256 + threadIdx.x;
  if (idx >= 512*128) return;
  int i = idx >> 7, d = idx & 127;
  int et = i >> 4, op = i & 15;
  int j = d >> 1;
  float inv = __expf(-0.1439115683f * (float)j);   // 10000^(-j/64)
  float ang = (float)et * inv;
  float v = (d & 1) ? __cosf(ang) : __sinf(ang);
  EF[idx] = f2bf(v + op_emb[op*128 + d]);
}

// ---------------- generic bf16 MFMA GEMM: C[M,N] = act(A[M,128] @ B[N,128]^T + bias)
template<int RELU, int HASBIAS>
__global__ __launch_bounds__(256) void k_gemm(
    const ushort* __restrict__ A, const ushort* __restrict__ B,
    const float* __restrict__ bias, ushort* __restrict__ C, int M, int N){
  int lane = threadIdx.x & 63, wv = threadIdx.x >> 6;
  int tM = blockIdx.x*64 + (wv>>1)*32;
  int tN = blockIdx.y*64 + (wv&1)*32;
  int r16 = lane & 15, kg = (lane>>4)*8;
  f32x4 acc[2][2];
  #pragma unroll
  for (int i=0;i<2;i++)
    #pragma unroll
    for (int j=0;j<2;j++) acc[i][j] = (f32x4)0.0f;
  for (int k0=0;k0<128;k0+=32){
    bf8 a[2], b[2];
    #pragma unroll
    for (int i=0;i<2;i++){
      int row = tM + i*16 + r16; if (row > M-1) row = M-1;
      a[i] = *(const bf8*)(A + (size_t)row*128 + k0 + kg);
    }
    #pragma unroll
    for (int j=0;j<2;j++){
      int col = tN + j*16 + r16;
      b[j] = *(const bf8*)(B + (size_t)col*128 + k0 + kg);
    }
    #pragma unroll
    for (int i=0;i<2;i++)
      #pragma unroll
      for (int j=0;j<2;j++)
        acc[i][j] = __builtin_amdgcn_mfma_f32_16x16x32_bf16(a[i], b[j], acc[i][j], 0, 0, 0);
  }
  #pragma unroll
  for (int i=0;i<2;i++)
    #pragma unroll
    for (int j=0;j<2;j++){
      int col = tN + j*16 + r16;
      float bs = HASBIAS ? bias[col] : 0.0f;
      #pragma unroll
      for (int q=0;q<4;q++){
        int row = tM + i*16 + (lane>>4)*4 + q;
        if (row < M){
          float v = acc[i][j][q] + bs;
          if (RELU) v = fmaxf(v, 0.0f);
          C[(size_t)row*N + col] = f2bf(v);
        }
      }
    }
}

// ---------------- swapped-MFMA 2-layer GRU encoder ------------------------------
// 16 masked nodes per block, 4 waves. Wave w owns gate tiles {w, 4+w, 8+w} =
// r/z/n rows for hidden slice [16w, 16w+16): gates are computed fully in-lane.
// D = mfma(A=W_tile[16 gates x K], B=state^T[K x 16 nodes]) -> row=gate, col=node.
// Only the f16 h-state (16x64 per layer) crosses waves, XOR-swizzled in LDS.
// x for all 32 steps staged in LDS once (source-pre-swizzled chunks).
__global__ __launch_bounds__(256, 1) void k_enc3(
    const float* __restrict__ sim_res, const int* __restrict__ seqlen,
    const float* __restrict__ Wih0, const float* __restrict__ Whh0,
    const float* __restrict__ bih0, const float* __restrict__ bhh0,
    const float* __restrict__ Wih1, const float* __restrict__ Whh1,
    const float* __restrict__ bih1, const float* __restrict__ bhh1,
    const int* __restrict__ mlist, const int* __restrict__ cntp,
    float* __restrict__ Hf, ushort* __restrict__ Hb){
  int C = *cntp;
  int base = blockIdx.x * 16;
  if (C == 0 || base >= C) return;
  int tid = threadIdx.x;
  int w = tid >> 6, l = tid & 63;
  int node = l & 15, hi = l >> 4;

  __shared__ int nod[16];
  __shared__ __align__(16) float  Xs[16*32*32];           // 16 nodes x 32 t x 32 f32 = 64KB
  __shared__ __align__(16) ushort H0h[16*64], H1h[16*64]; // f16 state, swizzled rows

  if (tid < 16){
    int idx = base + tid;
    nod[tid] = mlist[idx < C ? idx : C-1];
  }
  __syncthreads();

  // ---- stage x: chunk m = [node(4b)][t(5b)][c(3b)]; LDS logical chunk c holds
  // source chunk c^(node&7) so per-step reads are bank-conflict-free.
  for (int m = tid; m < 4096; m += 256){
    int nm = m >> 8, tt = (m >> 3) & 31, c = m & 7;
    int cs = c ^ (nm & 7);
    f32x4 v = *(const f32x4*)(sim_res + (size_t)nod[nm]*1024 + tt*32 + cs*4);
    *(f32x4*)(Xs + m*4) = v;
  }

  // ---- per-wave weight A-fragments: A[row = l&15 within tile][k = hi*8..+8]
  int rr = 16*w + node;           // r-gate row; z = 64+rr; n = 128+rr
  h8 Aih0_r = ldw8(Wih0 + (size_t)rr*32        + hi*8);
  h8 Aih0_z = ldw8(Wih0 + (size_t)(64+rr)*32   + hi*8);
  h8 Aih0_n = ldw8(Wih0 + (size_t)(128+rr)*32  + hi*8);
  h8 Ahh0_r[2], Ahh0_z[2], Ahh0_n[2], Aih1_r[2], Aih1_z[2], Aih1_n[2], Ahh1_r[2], Ahh1_z[2], Ahh1_n[2];
  #pragma unroll
  for (int s=0;s<2;s++){
    Ahh0_r[s] = ldw8(Whh0 + (size_t)rr*64       + s*32 + hi*8);
    Ahh0_z[s] = ldw8(Whh0 + (size_t)(64+rr)*64  + s*32 + hi*8);
    Ahh0_n[s] = ldw8(Whh0 + (size_t)(128+rr)*64 + s*32 + hi*8);
    Aih1_r[s] = ldw8(Wih1 + (size_t)rr*64       + s*32 + hi*8);
    Aih1_z[s] = ldw8(Wih1 + (size_t)(64+rr)*64  + s*32 + hi*8);
    Aih1_n[s] = ldw8(Wih1 + (size_t)(128+rr)*64 + s*32 + hi*8);
    Ahh1_r[s] = ldw8(Whh1 + (size_t)rr*64       + s*32 + hi*8);
    Ahh1_z[s] = ldw8(Whh1 + (size_t)(64+rr)*64  + s*32 + hi*8);
    Ahh1_n[s] = ldw8(Whh1 + (size_t)(128+rr)*64 + s*32 + hi*8);
  }

  // ---- biases: acc row q -> gate row 16w + hi*4 + q
  float br0[4], bz0[4], bin0[4], bhn0[4], br1[4], bz1[4], bin1[4], bhn1[4];
  #pragma unroll
  for (int q=0;q<4;q++){
    int row = 16*w + hi*4 + q;
    br0[q]  = bih0[row]      + bhh0[row];
    bz0[q]  = bih0[64+row]   + bhh0[64+row];
    bin0[q] = bih0[128+row];
    bhn0[q] = bhh0[128+row];
    br1[q]  = bih1[row]      + bhh1[row];
    bz1[q]  = bih1[64+row]   + bhh1[64+row];
    bin1[q] = bih1[128+row];
    bhn1[q] = bhh1[128+row];
  }

  int T = *seqlen; if (T > 32) T = 32; if (T < 0) T = 0;

  float h0m[4] = {0.f,0.f,0.f,0.f}, h1m[4] = {0.f,0.f,0.f,0.f};
  h8 h0f[2], h1f[2];
  #pragma unroll
  for (int s=0;s<2;s++){
    #pragma unroll
    for (int j=0;j<8;j++){ h0f[s][j] = (half_t)0.f; h1f[s][j] = (half_t)0.f; }
  }

  char* H0c = (char*)H0h;
  char* H1c = (char*)H1h;
  const int swz = (node & 7) << 4;
  const int wo  = node * 128;
  const int wba = (32*w + 8*hi);              // byte of j*2 base (q=0,1)
  const int rd0 = wo + ((16*hi) ^ swz);       // frag s=0 (k 0..31)
  const int rd1 = wo + ((64 + 16*hi) ^ swz);  // frag s=1 (k 32..63)
  const int xc0 = (2*hi) ^ (node & 7);
  const int xc1 = (2*hi+1) ^ (node & 7);
  const float* xrow = Xs + node*1024;

  __syncthreads();   // Xs staged

  for (int t = 0; t < T; ++t){
    // ---- x fragment from LDS (data chunks 2hi, 2hi+1 -> k = hi*8..+8)
    f32x4 xa = *(const f32x4*)(xrow + t*32 + xc0*4);
    f32x4 xb = *(const f32x4*)(xrow + t*32 + xc1*4);
    h8 xf;
    #pragma unroll
    for (int j=0;j<4;j++){ xf[j] = (half_t)xa[j]; xf[4+j] = (half_t)xb[j]; }

    // ===== layer 0: acc chains (r,z fuse gi+gh; n split) =====
    f32x4 ar = {br0[0],br0[1],br0[2],br0[3]};
    f32x4 az = {bz0[0],bz0[1],bz0[2],bz0[3]};
    f32x4 ain = {bin0[0],bin0[1],bin0[2],bin0[3]};
    f32x4 ahn = {bhn0[0],bhn0[1],bhn0[2],bhn0[3]};
    ar = mfma_f16(Aih0_r, xf, ar);
    az = mfma_f16(Aih0_z, xf, az);
    ain = mfma_f16(Aih0_n, xf, ain);
    #pragma unroll
    for (int s=0;s<2;s++){
      ar  = mfma_f16(Ahh0_r[s], h0f[s], ar);
      az  = mfma_f16(Ahh0_z[s], h0f[s], az);
      ahn = mfma_f16(Ahh0_n[s], h0f[s], ahn);
    }
    #pragma unroll
    for (int q=0;q<4;q++){
      float r = sigmoidf_(ar[q]);
      float z = sigmoidf_(az[q]);
      float n = tanhf_(ain[q] + r*ahn[q]);
      h0m[q] = (1.f - z)*n + z*h0m[q];
    }
    *(uint*)(H0c + wo + ( wba      ^ swz)) = pkhalf(h0m[0], h0m[1]);
    *(uint*)(H0c + wo + ((wba + 4) ^ swz)) = pkhalf(h0m[2], h0m[3]);
    __syncthreads();
    h0f[0] = *(const h8*)(H0c + rd0);
    h0f[1] = *(const h8*)(H0c + rd1);

    // ===== layer 1 =====
    f32x4 ar1 = {br1[0],br1[1],br1[2],br1[3]};
    f32x4 az1 = {bz1[0],bz1[1],bz1[2],bz1[3]};
    f32x4 ain1 = {bin1[0],bin1[1],bin1[2],bin1[3]};
    f32x4 ahn1 = {bhn1[0],bhn1[1],bhn1[2],bhn1[3]};
    #pragma unroll
    for (int s=0;s<2;s++){
      ar1  = mfma_f16(Aih1_r[s], h0f[s], ar1);
      az1  = mfma_f16(Aih1_z[s], h0f[s], az1);
      ain1 = mfma_f16(Aih1_n[s], h0f[s], ain1);
      ar1  = mfma_f16(Ahh1_r[s], h1f[s], ar1);
      az1  = mfma_f16(Ahh1_z[s], h1f[s], az1);
      ahn1 = mfma_f16(Ahh1_n[s], h1f[s], ahn1);
    }
    #pragma unroll
    for (int q=0;q<4;q++){
      float r = sigmoidf_(ar1[q]);
      float z = sigmoidf_(az1[q]);
      float n = tanhf_(ain1[q] + r*ahn1[q]);
      h1m[q] = (1.f - z)*n + z*h1m[q];
    }
    *(uint*)(H1c + wo + ( wba      ^ swz)) = pkhalf(h1m[0], h1m[1]);
    *(uint*)(H1c + wo + ((wba + 4) ^ swz)) = pkhalf(h1m[2], h1m[3]);
    __syncthreads();
    h1f[0] = *(const h8*)(H1c + rd0);
    h1f[1] = *(const h8*)(H1c + rd1);
  }

  // ---- output: enc = [h0 | h1]
  if (base + node < C){
    int nd = nod[node];
    #pragma unroll
    for (int q=0;q<4;q++){
      int j = 16*w + hi*4 + q;
      Hf[(size_t)nd*128 + j]       = h0m[q];
      Hf[(size_t)nd*128 + 64 + j]  = h1m[q];
      Hb[(size_t)nd*128 + j]       = f2bf(h0m[q]);
      Hb[(size_t)nd*128 + 64 + j]  = f2bf(h1m[q]);
    }
  }
}

// ---------------- CSR build -----------------------------------------------------
__global__ __launch_bounds__(256) void k_deg(const int* __restrict__ dst, int* __restrict__ deg, int E){
  int e = blockIdx.x*256 + threadIdx.x;
  if (e < E) atomicAdd(&deg[dst[e]], 1);
}

__global__ __launch_bounds__(1024) void k_scan(const int* __restrict__ deg,
    int* __restrict__ rowptr, int* __restrict__ cursor, int N){
  __shared__ int wsum[16];
  __shared__ int carry_s;
  int tid = threadIdx.x, lane = tid & 63, wid = tid >> 6;
  if (tid == 0) carry_s = 0;
  __syncthreads();
  int nch = (N + 1023) / 1024;
  for (int c=0; c<nch; ++c){
    int i = c*1024 + tid;
    int v = (i < N) ? deg[i] : 0;
    int x = v;
    #pragma unroll
    for (int off=1; off<64; off<<=1){
      int t = __shfl_up(x, off, 64);
      if (lane >= off) x += t;
    }
    if (lane == 63) wsum[wid] = x;
    __syncthreads();
    int base = carry_s;
    int woff = 0;
    for (int w2=0; w2<wid; ++w2) woff += wsum[w2];
    int excl = base + woff + x - v;
    if (i < N){ rowptr[i] = excl; cursor[i] = excl; }
    __syncthreads();
    if (tid == 0){
      int s = 0;
      for (int w2=0; w2<16; ++w2) s += wsum[w2];
      carry_s = base + s;
    }
    __syncthreads();
  }
  if (tid == 0) rowptr[N] = carry_s;
}

__global__ __launch_bounds__(256) void k_scatter(const int* __restrict__ src,
    const int* __restrict__ dst, const int* __restrict__ etype, const int* __restrict__ typ,
    int* __restrict__ cursor, int* __restrict__ es_src, int* __restrict__ es_tab, int E){
  int e = blockIdx.x*256 + threadIdx.x;
  if (e < E){
    int d = dst[e];
    int pos = atomicAdd(&cursor[d], 1);
    es_src[pos] = src[e];
    es_tab[pos] = etype[e]*16 + typ[d];
  }
}

// ---------------- attention: one wave per dst node, online softmax --------------
// QKV rows: [q(64 uint) | k(64 uint) | v(64 uint)] = 192 uints per node
__global__ __launch_bounds__(256) void k_attn(
    const uint* __restrict__ QKV,
    const uint* __restrict__ Ktab, const uint* __restrict__ Vtab,
    const int* __restrict__ rowptr, const int* __restrict__ es_src, const int* __restrict__ es_tab,
    uint* __restrict__ aggr, int N){
  int w = threadIdx.x >> 6, lane = threadIdx.x & 63;
  int dst = blockIdx.x*4 + w;
  if (dst >= N) return;
  uint qu = QKV[(size_t)dst*192 + lane];
  const float scale = 0.08838834764831845f;  // 1/sqrt(128)
  float q0 = bfl(qu)*scale, q1 = bfh(qu)*scale;
  int s0 = rowptr[dst], s1 = rowptr[dst+1];
  float m = -1e30f, den = 0.f, a0 = 0.f, a1 = 0.f;
  for (int p = s0; p < s1; ++p){
    int src = es_src[p], tb = es_tab[p];
    uint ku = QKV[(size_t)src*192 + 64 + lane], kt = Ktab[(size_t)tb*64 + lane];
    float k0 = bfl(ku) + bfl(kt), k1 = bfh(ku) + bfh(kt);
    float s = q0*k0 + q1*k1;
    #pragma unroll
    for (int off=32; off; off>>=1) s += __shfl_xor(s, off);
    uint vu = QKV[(size_t)src*192 + 128 + lane], vt = Vtab[(size_t)tb*64 + lane];
    float v0 = bfl(vu) + bfl(vt), v1 = bfh(vu) + bfh(vt);
    float nm = fmaxf(m, s);
    float c  = __expf(m - nm);
    float pw = __expf(s - nm);
    den = den*c + pw;
    a0  = a0*c + pw*v0;
    a1  = a1*c + pw*v1;
    m = nm;
  }
  float inv = 1.0f/(den + 1e-9f);
  a0 *= inv; a1 *= inv;
  aggr[(size_t)dst*64 + lane] = ((uint)f2bf(a1) << 16) | (uint)f2bf(a0);
}

// ---------------- fused GRU cell: gi = Xin@Wih^T, gh = H@Whh^T, gate ------------
// NOTE: Hbf/Hb_out and Hf_in/Hf_out may alias (in-place round) — no __restrict__.
__global__ __launch_bounds__(256) void k_gru(
    const ushort* __restrict__ Xb, const ushort* Hbf,
    const ushort* __restrict__ Wih, const ushort* __restrict__ Whh,
    const float* __restrict__ bih, const float* __restrict__ bhh,
    const float* Hf_in, float* Hf_out, ushort* Hb_out, int M){
  int lane = threadIdx.x & 63, wv = threadIdx.x >> 6;
  int nb = blockIdx.x * 32;
  int r16 = lane & 15, kg = (lane>>4)*8;
  f32x4 gi[2][6], gh[2][6];
  #pragma unroll
  for (int i=0;i<2;i++)
    #pragma unroll
    for (int c=0;c<6;c++){ gi[i][c] = (f32x4)0.0f; gh[i][c] = (f32x4)0.0f; }
  int cts[6] = {2*wv, 2*wv+1, 2*wv+8, 2*wv+9, 2*wv+16, 2*wv+17};
  for (int k0=0;k0<128;k0+=32){
    bf8 ax[2], ah[2];
    #pragma unroll
    for (int i=0;i<2;i++){
      int row = nb + i*16 + r16; if (row > M-1) row = M-1;
      ax[i] = *(const bf8*)(Xb  + (size_t)row*128 + k0 + kg);
      ah[i] = *(const bf8*)(Hbf + (size_t)row*128 + k0 + kg);
    }
    #pragma unroll
    for (int c=0;c<6;c++){
      bf8 bi = *(const bf8*)(Wih + (size_t)(cts[c]*16 + r16)*128 + k0 + kg);
      bf8 bh = *(const bf8*)(Whh + (size_t)(cts[c]*16 + r16)*128 + k0 + kg);
      #pragma unroll
      for (int i=0;i<2;i++){
        gi[i][c] = __builtin_amdgcn_mfma_f32_16x16x32_bf16(ax[i], bi, gi[i][c], 0, 0, 0);
        gh[i][c] = __builtin_amdgcn_mfma_f32_16x16x32_bf16(ah[i], bh, gh[i][c], 0, 0, 0);
      }
    }
  }
  __syncthreads();   // all Hbf reads in this block done before in-place writes
  #pragma unroll
  for (int i=0;i<2;i++)
    #pragma unroll
    for (int p=0;p<2;p++){
      int jcol = (2*wv + p)*16 + r16;            // 0..127
      float bir = bih[jcol], biz = bih[128+jcol], bin = bih[256+jcol];
      float bhr = bhh[jcol], bhz = bhh[128+jcol], bhn = bhh[256+jcol];
      #pragma unroll
      for (int q=0;q<4;q++){
        int node = nb + i*16 + (lane>>4)*4 + q;
        if (node < M){
          float gr  = gi[i][p][q]   + bir + gh[i][p][q]   + bhr;
          float gz  = gi[i][2+p][q] + biz + gh[i][2+p][q] + bhz;
          float inn = gi[i][4+p][q] + bin;
          float hnn = gh[i][4+p][q] + bhn;
          float rr = sigmoidf_(gr), zz = sigmoidf_(gz);
          float nn = tanhf_(inn + rr*hnn);
          float h = Hf_in[(size_t)node*128 + jcol];
          float o = (1.f - zz)*nn + zz*h;
          Hf_out[(size_t)node*128 + jcol] = o;
          Hb_out[(size_t)node*128 + jcol] = f2bf(o);
        }
      }
    }
}

extern "C" void kernel_launch(void* const* d_in, const int* in_sizes, int n_in,
                              void* d_out, int out_size, void* d_ws, size_t ws_size,
                              hipStream_t stream){
  const float* x       = (const float*)d_in[0];
  const int*   ei      = (const int*)d_in[1];
  const int*   etype   = (const int*)d_in[2];
  const float* sim_res = (const float*)d_in[3];
  const int*   seqlen  = (const int*)d_in[4];
  const float* eWih0 = (const float*)d_in[5];
  const float* eWhh0 = (const float*)d_in[6];
  const float* ebih0 = (const float*)d_in[7];
  const float* ebhh0 = (const float*)d_in[8];
  const float* eWih1 = (const float*)d_in[9];
  const float* eWhh1 = (const float*)d_in[10];
  const float* ebih1 = (const float*)d_in[11];
  const float* ebhh1 = (const float*)d_in[12];
  const float* Wq = (const float*)d_in[13];
  const float* Wk = (const float*)d_in[14];
  const float* Wv = (const float*)d_in[15];
  const float* op_emb = (const float*)d_in[16];
  const float* W1 = (const float*)d_in[17];
  const float* b1 = (const float*)d_in[18];
  const float* W2 = (const float*)d_in[19];
  const float* b2 = (const float*)d_in[20];
  const float* gWih = (const float*)d_in[21];
  const float* gWhh = (const float*)d_in[22];
  const float* gbih = (const float*)d_in[23];
  const float* gbhh = (const float*)d_in[24];

  const int N = in_sizes[0] / 16;
  const int E = in_sizes[2];

  char* p = (char*)d_ws;
  auto take = [&](size_t b)->void*{ void* r = (void*)p; p += (b + 255) & ~(size_t)255; return r; };

  float*  Hf   = (float*) take((size_t)N*128*4);
  ushort* Hb   = (ushort*)take((size_t)N*128*2);
  ushort* QKV  = (ushort*)take((size_t)N*384*2);
  ushort* Ag   = (ushort*)take((size_t)N*128*2);
  ushort* T1   = (ushort*)take((size_t)N*128*2);
  ushort* Xin  = (ushort*)take((size_t)N*128*2);
  ushort* EF   = (ushort*)take((size_t)512*128*2);
  ushort* Ktab = (ushort*)take((size_t)512*128*2);
  ushort* Vtab = (ushort*)take((size_t)512*128*2);
  ushort* wqkv = (ushort*)take((size_t)3*16384*2);   // [wq | wk | wv] rows
  ushort* w1_b = (ushort*)take((size_t)16384*2);
  ushort* w2_b = (ushort*)take((size_t)16384*2);
  ushort* wih_b= (ushort*)take((size_t)49152*2);
  ushort* whh_b= (ushort*)take((size_t)49152*2);
  int* typ    = (int*)take((size_t)N*4);
  int* mlist  = (int*)take((size_t)N*4);
  int* cnt    = (int*)take(256);
  int* deg    = (int*)take((size_t)N*4);
  int* rowptr = (int*)take((size_t)(N+1)*4);
  int* cursor = (int*)take((size_t)N*4);
  int* es_src = (int*)take((size_t)E*4);
  int* es_tab = (int*)take((size_t)E*4);

  ushort* wq_b = wqkv;
  ushort* wk_b = wqkv + 16384;
  ushort* wv_b = wqkv + 32768;

  hipMemsetAsync(cnt, 0, 4, stream);
  hipMemsetAsync(deg, 0, (size_t)N*4, stream);
  hipMemsetAsync(Hf, 0, (size_t)N*128*4, stream);
  hipMemsetAsync(Hb, 0, (size_t)N*128*2, stream);

  k_prep<<<(N+255)/256, 256, 0, stream>>>(x, typ, mlist, cnt, N);
  k_cvtw<<<64, 256, 0, stream>>>(Wq, Wk, Wv, W1, W2, gWih, gWhh,
                                 wq_b, wk_b, wv_b, w1_b, w2_b, wih_b, whh_b);
  k_ef<<<(512*128+255)/256, 256, 0, stream>>>(op_emb, EF);
  dim3 gt(8, 2);
  k_gemm<0,0><<<gt, 256, 0, stream>>>(EF, wk_b, nullptr, Ktab, 512, 128);
  k_gemm<0,0><<<gt, 256, 0, stream>>>(EF, wv_b, nullptr, Vtab, 512, 128);
  k_enc3<<<(N+15)/16, 256, 0, stream>>>(sim_res, seqlen, eWih0, eWhh0, ebih0, ebhh0,
                                        eWih1, eWhh1, ebih1, ebhh1, mlist, cnt, Hf, Hb);
  k_deg<<<(E+255)/256, 256, 0, stream>>>(ei + E, deg, E);
  k_scan<<<1, 1024, 0, stream>>>(deg, rowptr, cursor, N);
  k_scatter<<<(E+255)/256, 256, 0, stream>>>(ei, ei + E, etype, typ, cursor, es_src, es_tab, E);

  dim3 gq((N+63)/64, 6);   // fused QKV: N_out = 384
  dim3 g1((N+63)/64, 2);
  for (int r=0; r<2; ++r){
    k_gemm<0,0><<<gq, 256, 0, stream>>>(Hb, wqkv, nullptr, QKV, N, 384);
    k_attn<<<(N+3)/4, 256, 0, stream>>>((const uint*)QKV,
        (const uint*)Ktab, (const uint*)Vtab, rowptr, es_src, es_tab, (uint*)Ag, N);
    k_gemm<1,1><<<g1, 256, 0, stream>>>(Ag, w1_b, b1, T1, N, 128);
    k_gemm<0,1><<<g1, 256, 0, stream>>>(T1, w2_b, b2, Xin, N, 128);
    float* hf_out = (r == 1) ? (float*)d_out : Hf;
    k_gru<<<(N+31)/32, 256, 0, stream>>>(Xin, Hb, wih_b, whh_b, gbih, gbhh,
                                         Hf, hf_out, Hb, N);
  }
}

// Round 7
// 341.048 us; speedup vs baseline: 1.6858x; 1.1646x over previous
//
#include <hip/hip_runtime.h>

typedef unsigned int uint;
typedef unsigned short ushort;

typedef __attribute__((ext_vector_type(8))) short bf8;
typedef __attribute__((ext_vector_type(4))) float f32x4;
typedef _Float16 half_t;
typedef __attribute__((ext_vector_type(8))) half_t h8;

__device__ __forceinline__ ushort f2bf(float f){
  uint u = __builtin_bit_cast(uint, f);
  u = u + 0x7FFFu + ((u >> 16) & 1u);
  return (ushort)(u >> 16);
}
__device__ __forceinline__ float bfl(uint u){ return __builtin_bit_cast(float, u << 16); }
__device__ __forceinline__ float bfh(uint u){ return __builtin_bit_cast(float, u & 0xFFFF0000u); }
__device__ __forceinline__ uint pkhalf(float a, float b){
  ushort lo = __builtin_bit_cast(ushort, (half_t)a);
  ushort hi = __builtin_bit_cast(ushort, (half_t)b);
  return (uint)lo | ((uint)hi << 16);
}
__device__ __forceinline__ float sigmoidf_(float x){ return 1.0f/(1.0f + __expf(-x)); }
__device__ __forceinline__ float tanhf_(float x){
  x = fminf(15.0f, fmaxf(-15.0f, x));
  float t = __expf(-2.0f*x);
  return (1.0f - t)/(1.0f + t);
}
__device__ __forceinline__ f32x4 mfma_f16(h8 a, h8 b, f32x4 c){
  return __builtin_amdgcn_mfma_f32_16x16x32_f16(a, b, c, 0, 0, 0);
}
__device__ __forceinline__ h8 ldw8(const float* p){
  f32x4 a = *(const f32x4*)p, b = *(const f32x4*)(p+4);
  h8 v;
  #pragma unroll
  for (int j=0;j<4;j++){ v[j] = (half_t)a[j]; v[4+j] = (half_t)b[j]; }
  return v;
}

// ---- fused prep: node type + mask-compact + edge degree + Hf/Hb zero-init ------
__global__ __launch_bounds__(256) void k_prep(const float* __restrict__ x,
    const int* __restrict__ dst,
    int* __restrict__ typ, int* __restrict__ mlist, int* __restrict__ cnt,
    int* __restrict__ deg, float* __restrict__ Hf, ushort* __restrict__ Hb,
    int N, int E){
  int i = blockIdx.x*256 + threadIdx.x;
  int total = gridDim.x*256;
  if (i < N){
    const float* xr = x + (size_t)i*16;
    int t = 0;
    #pragma unroll
    for (int j=0;j<16;j++) if (xr[j] > 0.5f) t = j;
    typ[i] = t;
    if (t < 2){
      int p = atomicAdd(cnt, 1);
      mlist[p] = i;
    }
  }
  if (i < E) atomicAdd(&deg[dst[i]], 1);
  f32x4 z4 = (f32x4)0.0f;
  for (int j = i; j < N*32; j += total) ((f32x4*)Hf)[j] = z4;
  uint2 z2; z2.x = 0u; z2.y = 0u;
  for (int j = i; j < N*32; j += total) ((uint2*)Hb)[j] = z2;
}

// ---- fused weight-convert + edge-feature table EF[512][128] ---------------------
__global__ __launch_bounds__(256) void k_cvt(
    const float* wq, const float* wk, const float* wv,
    const float* w1, const float* w2, const float* wih, const float* whh,
    const float* __restrict__ op_emb,
    ushort* oqkv, ushort* o1, ushort* o2, ushort* oih, ushort* ohh,
    ushort* __restrict__ EF){
  int i = blockIdx.x*256 + threadIdx.x;
  int stride = gridDim.x*256;
  for (int j=i; j<16384; j+=stride){
    oqkv[j]       = f2bf(wq[j]);
    oqkv[16384+j] = f2bf(wk[j]);
    oqkv[32768+j] = f2bf(wv[j]);
    o1[j] = f2bf(w1[j]);
    o2[j] = f2bf(w2[j]);
  }
  for (int j=i; j<49152; j+=stride){ oih[j]=f2bf(wih[j]); ohh[j]=f2bf(whh[j]); }
  for (int idx=i; idx<512*128; idx+=stride){
    int r = idx >> 7, d = idx & 127;
    int et = r >> 4, op = r & 15;
    int j = d >> 1;
    float inv = __expf(-0.1439115683f * (float)j);   // 10000^(-j/64)
    float ang = (float)et * inv;
    float v = (d & 1) ? __cosf(ang) : __sinf(ang);
    EF[idx] = f2bf(v + op_emb[op*128 + d]);
  }
}

// ---- generic bf16 MFMA GEMM: C[M,N] = act(A[M,128] @ B[N,128]^T + bias) --------
template<int RELU, int HASBIAS>
__global__ __launch_bounds__(256) void k_gemm(
    const ushort* __restrict__ A, const ushort* __restrict__ B,
    const float* __restrict__ bias, ushort* __restrict__ C, int M, int N){
  int lane = threadIdx.x & 63, wv = threadIdx.x >> 6;
  int tM = blockIdx.x*64 + (wv>>1)*32;
  int tN = blockIdx.y*64 + (wv&1)*32;
  int r16 = lane & 15, kg = (lane>>4)*8;
  f32x4 acc[2][2];
  #pragma unroll
  for (int i=0;i<2;i++)
    #pragma unroll
    for (int j=0;j<2;j++) acc[i][j] = (f32x4)0.0f;
  for (int k0=0;k0<128;k0+=32){
    bf8 a[2], b[2];
    #pragma unroll
    for (int i=0;i<2;i++){
      int row = tM + i*16 + r16; if (row > M-1) row = M-1;
      a[i] = *(const bf8*)(A + (size_t)row*128 + k0 + kg);
    }
    #pragma unroll
    for (int j=0;j<2;j++){
      int col = tN + j*16 + r16;
      b[j] = *(const bf8*)(B + (size_t)col*128 + k0 + kg);
    }
    #pragma unroll
    for (int i=0;i<2;i++)
      #pragma unroll
      for (int j=0;j<2;j++)
        acc[i][j] = __builtin_amdgcn_mfma_f32_16x16x32_bf16(a[i], b[j], acc[i][j], 0, 0, 0);
  }
  #pragma unroll
  for (int i=0;i<2;i++)
    #pragma unroll
    for (int j=0;j<2;j++){
      int col = tN + j*16 + r16;
      float bs = HASBIAS ? bias[col] : 0.0f;
      #pragma unroll
      for (int q=0;q<4;q++){
        int row = tM + i*16 + (lane>>4)*4 + q;
        if (row < M){
          float v = acc[i][j][q] + bs;
          if (RELU) v = fmaxf(v, 0.0f);
          C[(size_t)row*N + col] = f2bf(v);
        }
      }
    }
}

// ---- pipelined swapped-MFMA 2-layer GRU encoder ---------------------------------
// 16 nodes/block, 8 waves. Waves 0-3 = layer 0 (tick k computes h0 step k),
// waves 4-7 = layer 1 (tick k computes h1 step k-1). Double-buffered h0/h1 in
// LDS (XOR-swizzled f16). One barrier per tick. x staged in LDS once.
__global__ __launch_bounds__(512, 1) void k_enc4(
    const float* __restrict__ sim_res, const int* __restrict__ seqlen,
    const float* __restrict__ Wih0, const float* __restrict__ Whh0,
    const float* __restrict__ bih0, const float* __restrict__ bhh0,
    const float* __restrict__ Wih1, const float* __restrict__ Whh1,
    const float* __restrict__ bih1, const float* __restrict__ bhh1,
    const int* __restrict__ mlist, const int* __restrict__ cntp,
    float* __restrict__ Hf, ushort* __restrict__ Hb){
  int C = *cntp;
  int base = blockIdx.x * 16;
  if (C == 0 || base >= C) return;
  int tid = threadIdx.x;
  int w = tid >> 6, l = tid & 63;
  int node = l & 15, hi = l >> 4;
  int grp = w >> 2;          // 0 = layer 0 group, 1 = layer 1 group
  int ws  = w & 3;           // hidden-slice owner within group

  __shared__ int nod[16];
  __shared__ __align__(16) float  Xs[16*32*32];               // 64 KB
  __shared__ __align__(16) ushort H0h[2][16*64], H1h[2][16*64];

  if (tid < 16){
    int idx = base + tid;
    nod[tid] = mlist[idx < C ? idx : C-1];
  }
  for (int i = tid; i < 16*64; i += 512){
    H0h[0][i] = 0; H0h[1][i] = 0; H1h[0][i] = 0; H1h[1][i] = 0;
  }
  __syncthreads();   // nod ready

  // stage x: chunk m = [node(4b)][t(5b)][c(3b)]; logical chunk c holds source
  // chunk c^(node&7) so per-step reads are conflict-free.
  for (int m = tid; m < 4096; m += 512){
    int nm = m >> 8, tt = (m >> 3) & 31, c = m & 7;
    int cs = c ^ (nm & 7);
    f32x4 v = *(const f32x4*)(sim_res + (size_t)nod[nm]*1024 + tt*32 + cs*4);
    *(f32x4*)(Xs + m*4) = v;
  }

  // per-wave weight A-fragments (A row within tile = node, k = hi*8..+8)
  int rr = 16*ws + node;       // r-gate row; z = 64+rr; n = 128+rr
  h8 zf;
  #pragma unroll
  for (int j=0;j<8;j++) zf[j] = (half_t)0.f;
  h8 Ai_r[2] = {zf, zf}, Ai_z[2] = {zf, zf}, Ai_n[2] = {zf, zf};
  h8 Ah_r[2], Ah_z[2], Ah_n[2];
  if (grp == 0){
    Ai_r[0] = ldw8(Wih0 + (size_t)rr*32        + hi*8);
    Ai_z[0] = ldw8(Wih0 + (size_t)(64+rr)*32   + hi*8);
    Ai_n[0] = ldw8(Wih0 + (size_t)(128+rr)*32  + hi*8);
    #pragma unroll
    for (int s=0;s<2;s++){
      Ah_r[s] = ldw8(Whh0 + (size_t)rr*64       + s*32 + hi*8);
      Ah_z[s] = ldw8(Whh0 + (size_t)(64+rr)*64  + s*32 + hi*8);
      Ah_n[s] = ldw8(Whh0 + (size_t)(128+rr)*64 + s*32 + hi*8);
    }
  } else {
    #pragma unroll
    for (int s=0;s<2;s++){
      Ai_r[s] = ldw8(Wih1 + (size_t)rr*64       + s*32 + hi*8);
      Ai_z[s] = ldw8(Wih1 + (size_t)(64+rr)*64  + s*32 + hi*8);
      Ai_n[s] = ldw8(Wih1 + (size_t)(128+rr)*64 + s*32 + hi*8);
      Ah_r[s] = ldw8(Whh1 + (size_t)rr*64       + s*32 + hi*8);
      Ah_z[s] = ldw8(Whh1 + (size_t)(64+rr)*64  + s*32 + hi*8);
      Ah_n[s] = ldw8(Whh1 + (size_t)(128+rr)*64 + s*32 + hi*8);
    }
  }
  const float* bi = grp ? bih1 : bih0;
  const float* bh = grp ? bhh1 : bhh0;
  float br[4], bz[4], bni[4], bnh[4];
  #pragma unroll
  for (int q=0;q<4;q++){
    int row = 16*ws + hi*4 + q;
    br[q]  = bi[row]      + bh[row];
    bz[q]  = bi[64+row]   + bh[64+row];
    bni[q] = bi[128+row];
    bnh[q] = bh[128+row];
  }

  int T = *seqlen; if (T > 32) T = 32; if (T < 0) T = 0;
  float hm[4] = {0.f, 0.f, 0.f, 0.f};

  const int swz = (node & 7) << 4;
  const int wo  = node * 128;
  const int wba = 32*ws + 8*hi;
  const int rd0 = wo + ((16*hi) ^ swz);
  const int rd1 = wo + ((64 + 16*hi) ^ swz);
  const int xc0 = (2*hi)   ^ (node & 7);
  const int xc1 = (2*hi+1) ^ (node & 7);
  const float* xrow = Xs + node*1024;

  __syncthreads();   // Xs + zeroed state buffers ready

  for (int k = 0; k <= T; ++k){
    int cur = k & 1;
    bool act = grp ? (k >= 1) : (k < T);
    if (act){
      h8 in0 = zf, in1 = zf, st0, st1;
      if (grp == 0){
        f32x4 xa = *(const f32x4*)(xrow + k*32 + xc0*4);
        f32x4 xb = *(const f32x4*)(xrow + k*32 + xc1*4);
        #pragma unroll
        for (int j=0;j<4;j++){ in0[j] = (half_t)xa[j]; in0[4+j] = (half_t)xb[j]; }
        st0 = *(const h8*)((const char*)H0h[cur] + rd0);
        st1 = *(const h8*)((const char*)H0h[cur] + rd1);
      } else {
        in0 = *(const h8*)((const char*)H0h[cur] + rd0);
        in1 = *(const h8*)((const char*)H0h[cur] + rd1);
        st0 = *(const h8*)((const char*)H1h[cur] + rd0);
        st1 = *(const h8*)((const char*)H1h[cur] + rd1);
      }
      f32x4 ar = {br[0],br[1],br[2],br[3]};
      f32x4 az = {bz[0],bz[1],bz[2],bz[3]};
      f32x4 an = {bni[0],bni[1],bni[2],bni[3]};
      f32x4 hn = {bnh[0],bnh[1],bnh[2],bnh[3]};
      ar = mfma_f16(Ai_r[0], in0, ar);
      az = mfma_f16(Ai_z[0], in0, az);
      an = mfma_f16(Ai_n[0], in0, an);
      if (grp){
        ar = mfma_f16(Ai_r[1], in1, ar);
        az = mfma_f16(Ai_z[1], in1, az);
        an = mfma_f16(Ai_n[1], in1, an);
      }
      ar = mfma_f16(Ah_r[0], st0, ar); ar = mfma_f16(Ah_r[1], st1, ar);
      az = mfma_f16(Ah_z[0], st0, az); az = mfma_f16(Ah_z[1], st1, az);
      hn = mfma_f16(Ah_n[0], st0, hn); hn = mfma_f16(Ah_n[1], st1, hn);
      #pragma unroll
      for (int q=0;q<4;q++){
        float r = sigmoidf_(ar[q]);
        float z = sigmoidf_(az[q]);
        float n = tanhf_(an[q] + r*hn[q]);
        hm[q] = (1.f - z)*n + z*hm[q];
      }
      char* outb = grp ? (char*)H1h[cur^1] : (char*)H0h[cur^1];
      *(uint*)(outb + wo + ( wba      ^ swz)) = pkhalf(hm[0], hm[1]);
      *(uint*)(outb + wo + ((wba + 4) ^ swz)) = pkhalf(hm[2], hm[3]);
    }
    __syncthreads();
  }

  // output: enc = [h0 | h1]; grp0 writes cols 0..63, grp1 cols 64..127
  if (base + node < C){
    int nd = nod[node];
    int off = grp ? 64 : 0;
    #pragma unroll
    for (int q=0;q<4;q++){
      int j = off + 16*ws + hi*4 + q;
      Hf[(size_t)nd*128 + j] = hm[q];
      Hb[(size_t)nd*128 + j] = f2bf(hm[q]);
    }
  }
}

// ---- CSR build -------------------------------------------------------------------
__global__ __launch_bounds__(1024) void k_scan(const int* __restrict__ deg,
    int* __restrict__ rowptr, int* __restrict__ cursor, int N){
  __shared__ int wsum[16];
  __shared__ int carry_s;
  int tid = threadIdx.x, lane = tid & 63, wid = tid >> 6;
  if (tid == 0) carry_s = 0;
  __syncthreads();
  int nch = (N + 1023) / 1024;
  for (int c=0; c<nch; ++c){
    int i = c*1024 + tid;
    int v = (i < N) ? deg[i] : 0;
    int x = v;
    #pragma unroll
    for (int off=1; off<64; off<<=1){
      int t = __shfl_up(x, off, 64);
      if (lane >= off) x += t;
    }
    if (lane == 63) wsum[wid] = x;
    __syncthreads();
    int base = carry_s;
    int woff = 0;
    for (int w2=0; w2<wid; ++w2) woff += wsum[w2];
    int excl = base + woff + x - v;
    if (i < N){ rowptr[i] = excl; cursor[i] = excl; }
    __syncthreads();
    if (tid == 0){
      int s = 0;
      for (int w2=0; w2<16; ++w2) s += wsum[w2];
      carry_s = base + s;
    }
    __syncthreads();
  }
  if (tid == 0) rowptr[N] = carry_s;
}

__global__ __launch_bounds__(256) void k_scatter(const int* __restrict__ src,
    const int* __restrict__ dst, const int* __restrict__ etype, const int* __restrict__ typ,
    int* __restrict__ cursor, int* __restrict__ es_src, int* __restrict__ es_tab, int E){
  int e = blockIdx.x*256 + threadIdx.x;
  if (e < E){
    int d = dst[e];
    int pos = atomicAdd(&cursor[d], 1);
    es_src[pos] = src[e];
    es_tab[pos] = etype[e]*16 + typ[d];
  }
}

// ---- attention: one wave per dst node, online softmax, 2-edge unrolled -----------
// QKV rows: [q(64 uint) | k(64 uint) | v(64 uint)]; KVT rows: [ktab(64) | vtab(64)]
__global__ __launch_bounds__(256) void k_attn(
    const uint* __restrict__ QKV, const uint* __restrict__ KVT,
    const int* __restrict__ rowptr, const int* __restrict__ es_src, const int* __restrict__ es_tab,
    uint* __restrict__ aggr, int N){
  int w = threadIdx.x >> 6, lane = threadIdx.x & 63;
  int dst = blockIdx.x*4 + w;
  if (dst >= N) return;
  uint qu = QKV[(size_t)dst*192 + lane];
  const float scale = 0.08838834764831845f;  // 1/sqrt(128)
  float q0 = bfl(qu)*scale, q1 = bfh(qu)*scale;
  int s0 = rowptr[dst], s1 = rowptr[dst+1];
  float m = -1e30f, den = 0.f, a0 = 0.f, a1 = 0.f;
  int p = s0;
  for (; p + 2 <= s1; p += 2){
    int srcA = es_src[p],   tbA = es_tab[p];
    int srcB = es_src[p+1], tbB = es_tab[p+1];
    uint kuA = QKV[(size_t)srcA*192 + 64 + lane],  ktA = KVT[(size_t)tbA*128 + lane];
    uint vuA = QKV[(size_t)srcA*192 + 128 + lane], vtA = KVT[(size_t)tbA*128 + 64 + lane];
    uint kuB = QKV[(size_t)srcB*192 + 64 + lane],  ktB = KVT[(size_t)tbB*128 + lane];
    uint vuB = QKV[(size_t)srcB*192 + 128 + lane], vtB = KVT[(size_t)tbB*128 + 64 + lane];
    float sA = q0*(bfl(kuA)+bfl(ktA)) + q1*(bfh(kuA)+bfh(ktA));
    float sB = q0*(bfl(kuB)+bfl(ktB)) + q1*(bfh(kuB)+bfh(ktB));
    #pragma unroll
    for (int off=32; off; off>>=1){
      sA += __shfl_xor(sA, off);
      sB += __shfl_xor(sB, off);
    }
    float nm = fmaxf(m, fmaxf(sA, sB));
    float c  = __expf(m - nm);
    float pA = __expf(sA - nm), pB = __expf(sB - nm);
    den = den*c + pA + pB;
    a0  = a0*c + pA*(bfl(vuA)+bfl(vtA)) + pB*(bfl(vuB)+bfl(vtB));
    a1  = a1*c + pA*(bfh(vuA)+bfh(vtA)) + pB*(bfh(vuB)+bfh(vtB));
    m = nm;
  }
  for (; p < s1; ++p){
    int src = es_src[p], tb = es_tab[p];
    uint ku = QKV[(size_t)src*192 + 64 + lane],  kt = KVT[(size_t)tb*128 + lane];
    uint vu = QKV[(size_t)src*192 + 128 + lane], vt = KVT[(size_t)tb*128 + 64 + lane];
    float s = q0*(bfl(ku)+bfl(kt)) + q1*(bfh(ku)+bfh(kt));
    #pragma unroll
    for (int off=32; off; off>>=1) s += __shfl_xor(s, off);
    float nm = fmaxf(m, s);
    float c  = __expf(m - nm);
    float pw = __expf(s - nm);
    den = den*c + pw;
    a0  = a0*c + pw*(bfl(vu)+bfl(vt));
    a1  = a1*c + pw*(bfh(vu)+bfh(vt));
    m = nm;
  }
  float inv = 1.0f/(den + 1e-9f);
  a0 *= inv; a1 *= inv;
  aggr[(size_t)dst*64 + lane] = ((uint)f2bf(a1) << 16) | (uint)f2bf(a0);
}

// ---- fused GRU cell: gi = Xin@Wih^T, gh = H@Whh^T, gate ---------------------------
// NOTE: Hbf/Hb_out and Hf_in/Hf_out may alias (in-place round) — no __restrict__.
__global__ __launch_bounds__(256) void k_gru(
    const ushort* __restrict__ Xb, const ushort* Hbf,
    const ushort* __restrict__ Wih, const ushort* __restrict__ Whh,
    const float* __restrict__ bih, const float* __restrict__ bhh,
    const float* Hf_in, float* Hf_out, ushort* Hb_out, int M){
  int lane = threadIdx.x & 63, wv = threadIdx.x >> 6;
  int nb = blockIdx.x * 32;
  int r16 = lane & 15, kg = (lane>>4)*8;
  f32x4 gi[2][6], gh[2][6];
  #pragma unroll
  for (int i=0;i<2;i++)
    #pragma unroll
    for (int c=0;c<6;c++){ gi[i][c] = (f32x4)0.0f; gh[i][c] = (f32x4)0.0f; }
  int cts[6] = {2*wv, 2*wv+1, 2*wv+8, 2*wv+9, 2*wv+16, 2*wv+17};
  for (int k0=0;k0<128;k0+=32){
    bf8 ax[2], ah[2];
    #pragma unroll
    for (int i=0;i<2;i++){
      int row = nb + i*16 + r16; if (row > M-1) row = M-1;
      ax[i] = *(const bf8*)(Xb  + (size_t)row*128 + k0 + kg);
      ah[i] = *(const bf8*)(Hbf + (size_t)row*128 + k0 + kg);
    }
    #pragma unroll
    for (int c=0;c<6;c++){
      bf8 bi = *(const bf8*)(Wih + (size_t)(cts[c]*16 + r16)*128 + k0 + kg);
      bf8 bh = *(const bf8*)(Whh + (size_t)(cts[c]*16 + r16)*128 + k0 + kg);
      #pragma unroll
      for (int i=0;i<2;i++){
        gi[i][c] = __builtin_amdgcn_mfma_f32_16x16x32_bf16(ax[i], bi, gi[i][c], 0, 0, 0);
        gh[i][c] = __builtin_amdgcn_mfma_f32_16x16x32_bf16(ah[i], bh, gh[i][c], 0, 0, 0);
      }
    }
  }
  __syncthreads();   // all Hbf reads in this block done before in-place writes
  #pragma unroll
  for (int i=0;i<2;i++)
    #pragma unroll
    for (int p=0;p<2;p++){
      int jcol = (2*wv + p)*16 + r16;            // 0..127
      float bir = bih[jcol], biz = bih[128+jcol], bin = bih[256+jcol];
      float bhr = bhh[jcol], bhz = bhh[128+jcol], bhn = bhh[256+jcol];
      #pragma unroll
      for (int q=0;q<4;q++){
        int node = nb + i*16 + (lane>>4)*4 + q;
        if (node < M){
          float gr  = gi[i][p][q]   + bir + gh[i][p][q]   + bhr;
          float gz  = gi[i][2+p][q] + biz + gh[i][2+p][q] + bhz;
          float inn = gi[i][4+p][q] + bin;
          float hnn = gh[i][4+p][q] + bhn;
          float rr = sigmoidf_(gr), zz = sigmoidf_(gz);
          float nn = tanhf_(inn + rr*hnn);
          float h = Hf_in[(size_t)node*128 + jcol];
          float o = (1.f - zz)*nn + zz*h;
          Hf_out[(size_t)node*128 + jcol] = o;
          Hb_out[(size_t)node*128 + jcol] = f2bf(o);
        }
      }
    }
}

extern "C" void kernel_launch(void* const* d_in, const int* in_sizes, int n_in,
                              void* d_out, int out_size, void* d_ws, size_t ws_size,
                              hipStream_t stream){
  const float* x       = (const float*)d_in[0];
  const int*   ei      = (const int*)d_in[1];
  const int*   etype   = (const int*)d_in[2];
  const float* sim_res = (const float*)d_in[3];
  const int*   seqlen  = (const int*)d_in[4];
  const float* eWih0 = (const float*)d_in[5];
  const float* eWhh0 = (const float*)d_in[6];
  const float* ebih0 = (const float*)d_in[7];
  const float* ebhh0 = (const float*)d_in[8];
  const float* eWih1 = (const float*)d_in[9];
  const float* eWhh1 = (const float*)d_in[10];
  const float* ebih1 = (const float*)d_in[11];
  const float* ebhh1 = (const float*)d_in[12];
  const float* Wq = (const float*)d_in[13];
  const float* Wk = (const float*)d_in[14];
  const float* Wv = (const float*)d_in[15];
  const float* op_emb = (const float*)d_in[16];
  const float* W1 = (const float*)d_in[17];
  const float* b1 = (const float*)d_in[18];
  const float* W2 = (const float*)d_in[19];
  const float* b2 = (const float*)d_in[20];
  const float* gWih = (const float*)d_in[21];
  const float* gWhh = (const float*)d_in[22];
  const float* gbih = (const float*)d_in[23];
  const float* gbhh = (const float*)d_in[24];

  const int N = in_sizes[0] / 16;
  const int E = in_sizes[2];

  char* p = (char*)d_ws;
  auto take = [&](size_t b)->void*{ void* r = (void*)p; p += (b + 255) & ~(size_t)255; return r; };

  float*  Hf    = (float*) take((size_t)N*128*4);
  ushort* Hb    = (ushort*)take((size_t)N*128*2);
  ushort* QKV   = (ushort*)take((size_t)N*384*2);
  ushort* Ag    = (ushort*)take((size_t)N*128*2);
  ushort* T1    = (ushort*)take((size_t)N*128*2);
  ushort* Xin   = (ushort*)take((size_t)N*128*2);
  ushort* EF    = (ushort*)take((size_t)512*128*2);
  ushort* KVtab = (ushort*)take((size_t)512*256*2);
  ushort* wqkv  = (ushort*)take((size_t)3*16384*2);   // [wq | wk | wv] rows
  ushort* w1_b  = (ushort*)take((size_t)16384*2);
  ushort* w2_b  = (ushort*)take((size_t)16384*2);
  ushort* wih_b = (ushort*)take((size_t)49152*2);
  ushort* whh_b = (ushort*)take((size_t)49152*2);
  int* typ    = (int*)take((size_t)N*4);
  int* mlist  = (int*)take((size_t)N*4);
  int* cnt    = (int*)take(256);
  int* deg    = (int*)take((size_t)N*4);
  int* rowptr = (int*)take((size_t)(N+1)*4);
  int* cursor = (int*)take((size_t)N*4);
  int* es_src = (int*)take((size_t)E*4);
  int* es_tab = (int*)take((size_t)E*4);

  hipMemsetAsync(cnt, 0, 4, stream);
  hipMemsetAsync(deg, 0, (size_t)N*4, stream);

  int gE = (E + 255) / 256;
  k_prep<<<gE, 256, 0, stream>>>(x, ei + E, typ, mlist, cnt, deg, Hf, Hb, N, E);
  k_cvt<<<256, 256, 0, stream>>>(Wq, Wk, Wv, W1, W2, gWih, gWhh, op_emb,
                                 wqkv, w1_b, w2_b, wih_b, whh_b, EF);
  k_gemm<0,0><<<dim3(8,4), 256, 0, stream>>>(EF, wqkv + 16384, nullptr, KVtab, 512, 256);
  k_enc4<<<(N+15)/16, 512, 0, stream>>>(sim_res, seqlen, eWih0, eWhh0, ebih0, ebhh0,
                                        eWih1, eWhh1, ebih1, ebhh1, mlist, cnt, Hf, Hb);
  k_scan<<<1, 1024, 0, stream>>>(deg, rowptr, cursor, N);
  k_scatter<<<gE, 256, 0, stream>>>(ei, ei + E, etype, typ, cursor, es_src, es_tab, E);

  dim3 gq((N+63)/64, 6);   // fused QKV: N_out = 384
  dim3 g1((N+63)/64, 2);
  for (int r=0; r<2; ++r){
    k_gemm<0,0><<<gq, 256, 0, stream>>>(Hb, wqkv, nullptr, QKV, N, 384);
    k_attn<<<(N+3)/4, 256, 0, stream>>>((const uint*)QKV, (const uint*)KVtab,
                                        rowptr, es_src, es_tab, (uint*)Ag, N);
    k_gemm<1,1><<<g1, 256, 0, stream>>>(Ag, w1_b, b1, T1, N, 128);
    k_gemm<0,1><<<g1, 256, 0, stream>>>(T1, w2_b, b2, Xin, N, 128);
    float* hf_out = (r == 1) ? (float*)d_out : Hf;
    k_gru<<<(N+31)/32, 256, 0, stream>>>(Xin, Hb, wih_b, whh_b, gbih, gbhh,
                                         Hf, hf_out, Hb, N);
  }
}

// Round 8
// 314.665 us; speedup vs baseline: 1.8271x; 1.0838x over previous
//
#include <hip/hip_runtime.h>

typedef unsigned int uint;
typedef unsigned short ushort;

typedef __attribute__((ext_vector_type(8))) short bf8;
typedef __attribute__((ext_vector_type(4))) float f32x4;
typedef _Float16 half_t;
typedef __attribute__((ext_vector_type(8))) half_t h8;

__device__ __forceinline__ ushort f2bf(float f){
  uint u = __builtin_bit_cast(uint, f);
  u = u + 0x7FFFu + ((u >> 16) & 1u);
  return (ushort)(u >> 16);
}
__device__ __forceinline__ float bfl(uint u){ return __builtin_bit_cast(float, u << 16); }
__device__ __forceinline__ float bfh(uint u){ return __builtin_bit_cast(float, u & 0xFFFF0000u); }
__device__ __forceinline__ uint pkhalf(float a, float b){
  ushort lo = __builtin_bit_cast(ushort, (half_t)a);
  ushort hi = __builtin_bit_cast(ushort, (half_t)b);
  return (uint)lo | ((uint)hi << 16);
}
__device__ __forceinline__ float sigmoidf_(float x){ return 1.0f/(1.0f + __expf(-x)); }
__device__ __forceinline__ float tanhf_(float x){
  x = fminf(15.0f, fmaxf(-15.0f, x));
  float t = __expf(-2.0f*x);
  return (1.0f - t)/(1.0f + t);
}
__device__ __forceinline__ f32x4 mfma_f16(h8 a, h8 b, f32x4 c){
  return __builtin_amdgcn_mfma_f32_16x16x32_f16(a, b, c, 0, 0, 0);
}
__device__ __forceinline__ f32x4 mfma_bf(bf8 a, bf8 b, f32x4 c){
  return __builtin_amdgcn_mfma_f32_16x16x32_bf16(a, b, c, 0, 0, 0);
}
__device__ __forceinline__ h8 ldw8(const float* p){
  f32x4 a = *(const f32x4*)p, b = *(const f32x4*)(p+4);
  h8 v;
  #pragma unroll
  for (int j=0;j<4;j++){ v[j] = (half_t)a[j]; v[4+j] = (half_t)b[j]; }
  return v;
}

// ---- fused prep: node type + mask-compact + edge degree + Hf/Hb zero-init ------
__global__ __launch_bounds__(256) void k_prep(const float* __restrict__ x,
    const int* __restrict__ dst,
    int* __restrict__ typ, int* __restrict__ mlist, int* __restrict__ cnt,
    int* __restrict__ deg, float* __restrict__ Hf, ushort* __restrict__ Hb,
    int N, int E){
  int i = blockIdx.x*256 + threadIdx.x;
  int total = gridDim.x*256;
  if (i < N){
    const float* xr = x + (size_t)i*16;
    int t = 0;
    #pragma unroll
    for (int j=0;j<16;j++) if (xr[j] > 0.5f) t = j;
    typ[i] = t;
    if (t < 2){
      int p = atomicAdd(cnt, 1);
      mlist[p] = i;
    }
  }
  if (i < E) atomicAdd(&deg[dst[i]], 1);
  f32x4 z4 = (f32x4)0.0f;
  for (int j = i; j < N*32; j += total) ((f32x4*)Hf)[j] = z4;
  uint2 z2; z2.x = 0u; z2.y = 0u;
  for (int j = i; j < N*32; j += total) ((uint2*)Hb)[j] = z2;
}

// ---- fused weight-convert + edge-feature table EF[512][128] ---------------------
__global__ __launch_bounds__(256) void k_cvt(
    const float* wq, const float* wk, const float* wv,
    const float* w1, const float* w2, const float* wih, const float* whh,
    const float* __restrict__ op_emb,
    ushort* oqkv, ushort* o1, ushort* o2, ushort* oih, ushort* ohh,
    ushort* __restrict__ EF){
  int i = blockIdx.x*256 + threadIdx.x;
  int stride = gridDim.x*256;
  for (int j=i; j<16384; j+=stride){
    oqkv[j]       = f2bf(wq[j]);
    oqkv[16384+j] = f2bf(wk[j]);
    oqkv[32768+j] = f2bf(wv[j]);
    o1[j] = f2bf(w1[j]);
    o2[j] = f2bf(w2[j]);
  }
  for (int j=i; j<49152; j+=stride){ oih[j]=f2bf(wih[j]); ohh[j]=f2bf(whh[j]); }
  for (int idx=i; idx<512*128; idx+=stride){
    int r = idx >> 7, d = idx & 127;
    int et = r >> 4, op = r & 15;
    int j = d >> 1;
    float inv = __expf(-0.1439115683f * (float)j);   // 10000^(-j/64)
    float ang = (float)et * inv;
    float v = (d & 1) ? __cosf(ang) : __sinf(ang);
    EF[idx] = f2bf(v + op_emb[op*128 + d]);
  }
}

// ---- generic bf16 MFMA GEMM: C[M,N] = act(A[M,128] @ B[N,128]^T + bias) --------
template<int RELU, int HASBIAS>
__global__ __launch_bounds__(256) void k_gemm(
    const ushort* __restrict__ A, const ushort* __restrict__ B,
    const float* __restrict__ bias, ushort* __restrict__ C, int M, int N){
  int lane = threadIdx.x & 63, wv = threadIdx.x >> 6;
  int tM = blockIdx.x*64 + (wv>>1)*32;
  int tN = blockIdx.y*64 + (wv&1)*32;
  int r16 = lane & 15, kg = (lane>>4)*8;
  f32x4 acc[2][2];
  #pragma unroll
  for (int i=0;i<2;i++)
    #pragma unroll
    for (int j=0;j<2;j++) acc[i][j] = (f32x4)0.0f;
  #pragma unroll
  for (int k0=0;k0<128;k0+=32){
    bf8 a[2], b[2];
    #pragma unroll
    for (int i=0;i<2;i++){
      int row = tM + i*16 + r16; if (row > M-1) row = M-1;
      a[i] = *(const bf8*)(A + (size_t)row*128 + k0 + kg);
    }
    #pragma unroll
    for (int j=0;j<2;j++){
      int col = tN + j*16 + r16;
      b[j] = *(const bf8*)(B + (size_t)col*128 + k0 + kg);
    }
    #pragma unroll
    for (int i=0;i<2;i++)
      #pragma unroll
      for (int j=0;j<2;j++)
        acc[i][j] = __builtin_amdgcn_mfma_f32_16x16x32_bf16(a[i], b[j], acc[i][j], 0, 0, 0);
  }
  #pragma unroll
  for (int i=0;i<2;i++)
    #pragma unroll
    for (int j=0;j<2;j++){
      int col = tN + j*16 + r16;
      float bs = HASBIAS ? bias[col] : 0.0f;
      #pragma unroll
      for (int q=0;q<4;q++){
        int row = tM + i*16 + (lane>>4)*4 + q;
        if (row < M){
          float v = acc[i][j][q] + bs;
          if (RELU) v = fmaxf(v, 0.0f);
          C[(size_t)row*N + col] = f2bf(v);
        }
      }
    }
}

// ---- pipelined swapped-MFMA 2-layer GRU encoder ---------------------------------
__global__ __launch_bounds__(512, 1) void k_enc4(
    const float* __restrict__ sim_res, const int* __restrict__ seqlen,
    const float* __restrict__ Wih0, const float* __restrict__ Whh0,
    const float* __restrict__ bih0, const float* __restrict__ bhh0,
    const float* __restrict__ Wih1, const float* __restrict__ Whh1,
    const float* __restrict__ bih1, const float* __restrict__ bhh1,
    const int* __restrict__ mlist, const int* __restrict__ cntp,
    float* __restrict__ Hf, ushort* __restrict__ Hb){
  int C = *cntp;
  int base = blockIdx.x * 16;
  if (C == 0 || base >= C) return;
  int tid = threadIdx.x;
  int w = tid >> 6, l = tid & 63;
  int node = l & 15, hi = l >> 4;
  int grp = w >> 2;          // 0 = layer 0 group, 1 = layer 1 group
  int ws  = w & 3;           // hidden-slice owner within group

  __shared__ int nod[16];
  __shared__ __align__(16) float  Xs[16*32*32];               // 64 KB
  __shared__ __align__(16) ushort H0h[2][16*64], H1h[2][16*64];

  if (tid < 16){
    int idx = base + tid;
    nod[tid] = mlist[idx < C ? idx : C-1];
  }
  for (int i = tid; i < 16*64; i += 512){
    H0h[0][i] = 0; H0h[1][i] = 0; H1h[0][i] = 0; H1h[1][i] = 0;
  }
  __syncthreads();   // nod ready

  for (int m = tid; m < 4096; m += 512){
    int nm = m >> 8, tt = (m >> 3) & 31, c = m & 7;
    int cs = c ^ (nm & 7);
    f32x4 v = *(const f32x4*)(sim_res + (size_t)nod[nm]*1024 + tt*32 + cs*4);
    *(f32x4*)(Xs + m*4) = v;
  }

  int rr = 16*ws + node;
  h8 zf;
  #pragma unroll
  for (int j=0;j<8;j++) zf[j] = (half_t)0.f;
  h8 Ai_r[2] = {zf, zf}, Ai_z[2] = {zf, zf}, Ai_n[2] = {zf, zf};
  h8 Ah_r[2], Ah_z[2], Ah_n[2];
  if (grp == 0){
    Ai_r[0] = ldw8(Wih0 + (size_t)rr*32        + hi*8);
    Ai_z[0] = ldw8(Wih0 + (size_t)(64+rr)*32   + hi*8);
    Ai_n[0] = ldw8(Wih0 + (size_t)(128+rr)*32  + hi*8);
    #pragma unroll
    for (int s=0;s<2;s++){
      Ah_r[s] = ldw8(Whh0 + (size_t)rr*64       + s*32 + hi*8);
      Ah_z[s] = ldw8(Whh0 + (size_t)(64+rr)*64  + s*32 + hi*8);
      Ah_n[s] = ldw8(Whh0 + (size_t)(128+rr)*64 + s*32 + hi*8);
    }
  } else {
    #pragma unroll
    for (int s=0;s<2;s++){
      Ai_r[s] = ldw8(Wih1 + (size_t)rr*64       + s*32 + hi*8);
      Ai_z[s] = ldw8(Wih1 + (size_t)(64+rr)*64  + s*32 + hi*8);
      Ai_n[s] = ldw8(Wih1 + (size_t)(128+rr)*64 + s*32 + hi*8);
      Ah_r[s] = ldw8(Whh1 + (size_t)rr*64       + s*32 + hi*8);
      Ah_z[s] = ldw8(Whh1 + (size_t)(64+rr)*64  + s*32 + hi*8);
      Ah_n[s] = ldw8(Whh1 + (size_t)(128+rr)*64 + s*32 + hi*8);
    }
  }
  const float* bi = grp ? bih1 : bih0;
  const float* bh = grp ? bhh1 : bhh0;
  float br[4], bz[4], bni[4], bnh[4];
  #pragma unroll
  for (int q=0;q<4;q++){
    int row = 16*ws + hi*4 + q;
    br[q]  = bi[row]      + bh[row];
    bz[q]  = bi[64+row]   + bh[64+row];
    bni[q] = bi[128+row];
    bnh[q] = bh[128+row];
  }

  int T = *seqlen; if (T > 32) T = 32; if (T < 0) T = 0;
  float hm[4] = {0.f, 0.f, 0.f, 0.f};

  const int swz = (node & 7) << 4;
  const int wo  = node * 128;
  const int wba = 32*ws + 8*hi;
  const int rd0 = wo + ((16*hi) ^ swz);
  const int rd1 = wo + ((64 + 16*hi) ^ swz);
  const int xc0 = (2*hi)   ^ (node & 7);
  const int xc1 = (2*hi+1) ^ (node & 7);
  const float* xrow = Xs + node*1024;

  __syncthreads();   // Xs + zeroed state buffers ready

  for (int k = 0; k <= T; ++k){
    int cur = k & 1;
    bool act = grp ? (k >= 1) : (k < T);
    if (act){
      h8 in0 = zf, in1 = zf, st0, st1;
      if (grp == 0){
        f32x4 xa = *(const f32x4*)(xrow + k*32 + xc0*4);
        f32x4 xb = *(const f32x4*)(xrow + k*32 + xc1*4);
        #pragma unroll
        for (int j=0;j<4;j++){ in0[j] = (half_t)xa[j]; in0[4+j] = (half_t)xb[j]; }
        st0 = *(const h8*)((const char*)H0h[cur] + rd0);
        st1 = *(const h8*)((const char*)H0h[cur] + rd1);
      } else {
        in0 = *(const h8*)((const char*)H0h[cur] + rd0);
        in1 = *(const h8*)((const char*)H0h[cur] + rd1);
        st0 = *(const h8*)((const char*)H1h[cur] + rd0);
        st1 = *(const h8*)((const char*)H1h[cur] + rd1);
      }
      f32x4 ar = {br[0],br[1],br[2],br[3]};
      f32x4 az = {bz[0],bz[1],bz[2],bz[3]};
      f32x4 an = {bni[0],bni[1],bni[2],bni[3]};
      f32x4 hn = {bnh[0],bnh[1],bnh[2],bnh[3]};
      ar = mfma_f16(Ai_r[0], in0, ar);
      az = mfma_f16(Ai_z[0], in0, az);
      an = mfma_f16(Ai_n[0], in0, an);
      if (grp){
        ar = mfma_f16(Ai_r[1], in1, ar);
        az = mfma_f16(Ai_z[1], in1, az);
        an = mfma_f16(Ai_n[1], in1, an);
      }
      ar = mfma_f16(Ah_r[0], st0, ar); ar = mfma_f16(Ah_r[1], st1, ar);
      az = mfma_f16(Ah_z[0], st0, az); az = mfma_f16(Ah_z[1], st1, az);
      hn = mfma_f16(Ah_n[0], st0, hn); hn = mfma_f16(Ah_n[1], st1, hn);
      #pragma unroll
      for (int q=0;q<4;q++){
        float r = sigmoidf_(ar[q]);
        float z = sigmoidf_(az[q]);
        float n = tanhf_(an[q] + r*hn[q]);
        hm[q] = (1.f - z)*n + z*hm[q];
      }
      char* outb = grp ? (char*)H1h[cur^1] : (char*)H0h[cur^1];
      *(uint*)(outb + wo + ( wba      ^ swz)) = pkhalf(hm[0], hm[1]);
      *(uint*)(outb + wo + ((wba + 4) ^ swz)) = pkhalf(hm[2], hm[3]);
    }
    __syncthreads();
  }

  if (base + node < C){
    int nd = nod[node];
    int off = grp ? 64 : 0;
    #pragma unroll
    for (int q=0;q<4;q++){
      int j = off + 16*ws + hi*4 + q;
      Hf[(size_t)nd*128 + j] = hm[q];
      Hb[(size_t)nd*128 + j] = f2bf(hm[q]);
    }
  }
}

// ---- CSR build -------------------------------------------------------------------
__global__ __launch_bounds__(1024) void k_scan(const int* __restrict__ deg,
    int* __restrict__ rowptr, int* __restrict__ cursor, int N){
  __shared__ int wsum[16];
  __shared__ int carry_s;
  int tid = threadIdx.x, lane = tid & 63, wid = tid >> 6;
  if (tid == 0) carry_s = 0;
  __syncthreads();
  int nch = (N + 1023) / 1024;
  for (int c=0; c<nch; ++c){
    int i = c*1024 + tid;
    int v = (i < N) ? deg[i] : 0;
    int x = v;
    #pragma unroll
    for (int off=1; off<64; off<<=1){
      int t = __shfl_up(x, off, 64);
      if (lane >= off) x += t;
    }
    if (lane == 63) wsum[wid] = x;
    __syncthreads();
    int base = carry_s;
    int woff = 0;
    for (int w2=0; w2<wid; ++w2) woff += wsum[w2];
    int excl = base + woff + x - v;
    if (i < N){ rowptr[i] = excl; cursor[i] = excl; }
    __syncthreads();
    if (tid == 0){
      int s = 0;
      for (int w2=0; w2<16; ++w2) s += wsum[w2];
      carry_s = base + s;
    }
    __syncthreads();
  }
  if (tid == 0) rowptr[N] = carry_s;
}

__global__ __launch_bounds__(256) void k_scatter(const int* __restrict__ src,
    const int* __restrict__ dst, const int* __restrict__ etype, const int* __restrict__ typ,
    int* __restrict__ cursor, int* __restrict__ es_src, int* __restrict__ es_tab, int E){
  int e = blockIdx.x*256 + threadIdx.x;
  if (e < E){
    int d = dst[e];
    int pos = atomicAdd(&cursor[d], 1);
    es_src[pos] = src[e];
    es_tab[pos] = etype[e]*16 + typ[d];
  }
}

// ---- attention: one wave per dst node, online softmax, 2-edge unrolled -----------
__global__ __launch_bounds__(256) void k_attn(
    const uint* __restrict__ QKV, const uint* __restrict__ KVT,
    const int* __restrict__ rowptr, const int* __restrict__ es_src, const int* __restrict__ es_tab,
    uint* __restrict__ aggr, int N){
  int w = threadIdx.x >> 6, lane = threadIdx.x & 63;
  int dst = blockIdx.x*4 + w;
  if (dst >= N) return;
  uint qu = QKV[(size_t)dst*192 + lane];
  const float scale = 0.08838834764831845f;  // 1/sqrt(128)
  float q0 = bfl(qu)*scale, q1 = bfh(qu)*scale;
  int s0 = rowptr[dst], s1 = rowptr[dst+1];
  float m = -1e30f, den = 0.f, a0 = 0.f, a1 = 0.f;
  int p = s0;
  for (; p + 2 <= s1; p += 2){
    int srcA = es_src[p],   tbA = es_tab[p];
    int srcB = es_src[p+1], tbB = es_tab[p+1];
    uint kuA = QKV[(size_t)srcA*192 + 64 + lane],  ktA = KVT[(size_t)tbA*128 + lane];
    uint vuA = QKV[(size_t)srcA*192 + 128 + lane], vtA = KVT[(size_t)tbA*128 + 64 + lane];
    uint kuB = QKV[(size_t)srcB*192 + 64 + lane],  ktB = KVT[(size_t)tbB*128 + lane];
    uint vuB = QKV[(size_t)srcB*192 + 128 + lane], vtB = KVT[(size_t)tbB*128 + 64 + lane];
    float sA = q0*(bfl(kuA)+bfl(ktA)) + q1*(bfh(kuA)+bfh(ktA));
    float sB = q0*(bfl(kuB)+bfl(ktB)) + q1*(bfh(kuB)+bfh(ktB));
    #pragma unroll
    for (int off=32; off; off>>=1){
      sA += __shfl_xor(sA, off);
      sB += __shfl_xor(sB, off);
    }
    float nm = fmaxf(m, fmaxf(sA, sB));
    float c  = __expf(m - nm);
    float pA = __expf(sA - nm), pB = __expf(sB - nm);
    den = den*c + pA + pB;
    a0  = a0*c + pA*(bfl(vuA)+bfl(vtA)) + pB*(bfl(vuB)+bfl(vtB));
    a1  = a1*c + pA*(bfh(vuA)+bfh(vtA)) + pB*(bfh(vuB)+bfh(vtB));
    m = nm;
  }
  for (; p < s1; ++p){
    int src = es_src[p], tb = es_tab[p];
    uint ku = QKV[(size_t)src*192 + 64 + lane],  kt = KVT[(size_t)tb*128 + lane];
    uint vu = QKV[(size_t)src*192 + 128 + lane], vt = KVT[(size_t)tb*128 + 64 + lane];
    float s = q0*(bfl(ku)+bfl(kt)) + q1*(bfh(ku)+bfh(kt));
    #pragma unroll
    for (int off=32; off; off>>=1) s += __shfl_xor(s, off);
    float nm = fmaxf(m, s);
    float c  = __expf(m - nm);
    float pw = __expf(s - nm);
    den = den*c + pw;
    a0  = a0*c + pw*(bfl(vu)+bfl(vt));
    a1  = a1*c + pw*(bfh(vu)+bfh(vt));
    m = nm;
  }
  float inv = 1.0f/(den + 1e-9f);
  a0 *= inv; a1 *= inv;
  aggr[(size_t)dst*64 + lane] = ((uint)f2bf(a1) << 16) | (uint)f2bf(a0);
}

// ---- fused MLP1 + MLP2 + GRU cell -------------------------------------------------
// Per 32-node block: T = relu(Ag@W1^T+b1) -> LDS; X = T@W2^T+b2 -> LDS;
// gates via MFMA with fused r/z accumulation (gi+gh in one chain), in-lane update.
// NOTE: Hbf aliases Hb_out, Hf_in may alias Hf_out — no __restrict__ on those.
__global__ __launch_bounds__(256) void k_fused(
    const ushort* __restrict__ Ag,
    const ushort* __restrict__ W1b, const float* __restrict__ b1,
    const ushort* __restrict__ W2b, const float* __restrict__ b2,
    const ushort* __restrict__ Wih, const ushort* __restrict__ Whh,
    const float* __restrict__ bih, const float* __restrict__ bhh,
    const ushort* Hbf, const float* Hf_in,
    float* Hf_out, ushort* Hb_out, int M){
  int lane = threadIdx.x & 63, wv = threadIdx.x >> 6;
  int nb = blockIdx.x * 32;
  int r16 = lane & 15, kq = lane >> 4;

  __shared__ __align__(16) ushort T[32*128];   // 8 KB swizzled intermediate

  // ---------- phase 1: T = relu(Ag @ W1^T + b1) ----------
  {
    f32x4 acc[2][2];
    #pragma unroll
    for (int i=0;i<2;i++)
      #pragma unroll
      for (int j=0;j<2;j++) acc[i][j] = (f32x4)0.0f;
    #pragma unroll
    for (int ks=0; ks<4; ++ks){
      bf8 a[2], b[2];
      #pragma unroll
      for (int i=0;i<2;i++){
        int row = nb + i*16 + r16; if (row > M-1) row = M-1;
        a[i] = *(const bf8*)(Ag + (size_t)row*128 + ks*32 + kq*8);
      }
      #pragma unroll
      for (int j=0;j<2;j++)
        b[j] = *(const bf8*)(W1b + (size_t)(wv*32 + j*16 + r16)*128 + ks*32 + kq*8);
      #pragma unroll
      for (int i=0;i<2;i++)
        #pragma unroll
        for (int j=0;j<2;j++) acc[i][j] = mfma_bf(a[i], b[j], acc[i][j]);
    }
    #pragma unroll
    for (int i=0;i<2;i++)
      #pragma unroll
      for (int j=0;j<2;j++){
        int col = wv*32 + j*16 + r16;
        float bs = b1[col];
        #pragma unroll
        for (int q=0;q<4;q++){
          int row = i*16 + kq*4 + q;
          float v = fmaxf(acc[i][j][q] + bs, 0.0f);
          *(ushort*)((char*)T + ((row*256 + col*2) ^ ((row&7)<<4))) = f2bf(v);
        }
      }
  }
  __syncthreads();

  // ---------- phase 2: X = T @ W2^T + b2 (re-uses T buffer after read barrier) ----
  {
    f32x4 acc[2][2];
    #pragma unroll
    for (int i=0;i<2;i++)
      #pragma unroll
      for (int j=0;j<2;j++) acc[i][j] = (f32x4)0.0f;
    #pragma unroll
    for (int ks=0; ks<4; ++ks){
      bf8 a[2], b[2];
      #pragma unroll
      for (int i=0;i<2;i++){
        int row = i*16 + r16;
        a[i] = *(const bf8*)((const char*)T + row*256 + ((ks*64 + kq*16) ^ ((row&7)<<4)));
      }
      #pragma unroll
      for (int j=0;j<2;j++)
        b[j] = *(const bf8*)(W2b + (size_t)(wv*32 + j*16 + r16)*128 + ks*32 + kq*8);
      #pragma unroll
      for (int i=0;i<2;i++)
        #pragma unroll
        for (int j=0;j<2;j++) acc[i][j] = mfma_bf(a[i], b[j], acc[i][j]);
    }
    __syncthreads();   // all T reads complete before overwrite
    #pragma unroll
    for (int i=0;i<2;i++)
      #pragma unroll
      for (int j=0;j<2;j++){
        int col = wv*32 + j*16 + r16;
        float bs = b2[col];
        #pragma unroll
        for (int q=0;q<4;q++){
          int row = i*16 + kq*4 + q;
          *(ushort*)((char*)T + ((row*256 + col*2) ^ ((row&7)<<4))) = f2bf(acc[i][j][q] + bs);
        }
      }
  }
  __syncthreads();

  // ---------- phase 3: GRU — fused r/z chains, n split ----------
  f32x4 ar[2][2], az[2][2], ani[2][2], anh[2][2];
  #pragma unroll
  for (int i=0;i<2;i++)
    #pragma unroll
    for (int p2=0;p2<2;p2++){
      ar[i][p2] = (f32x4)0.0f; az[i][p2] = (f32x4)0.0f;
      ani[i][p2] = (f32x4)0.0f; anh[i][p2] = (f32x4)0.0f;
    }
  #pragma unroll
  for (int ks=0; ks<4; ++ks){
    bf8 ax[2], ah[2];
    #pragma unroll
    for (int i=0;i<2;i++){
      int row = i*16 + r16;
      ax[i] = *(const bf8*)((const char*)T + row*256 + ((ks*64 + kq*16) ^ ((row&7)<<4)));
      int grow = nb + row; if (grow > M-1) grow = M-1;
      ah[i] = *(const bf8*)(Hbf + (size_t)grow*128 + ks*32 + kq*8);
    }
    #pragma unroll
    for (int p2=0;p2<2;p2++){
      int cb = wv*32 + p2*16 + r16;
      bf8 wri = *(const bf8*)(Wih + (size_t)cb*128        + ks*32 + kq*8);
      bf8 wrh = *(const bf8*)(Whh + (size_t)cb*128        + ks*32 + kq*8);
      bf8 wzi = *(const bf8*)(Wih + (size_t)(128+cb)*128  + ks*32 + kq*8);
      bf8 wzh = *(const bf8*)(Whh + (size_t)(128+cb)*128  + ks*32 + kq*8);
      bf8 wni = *(const bf8*)(Wih + (size_t)(256+cb)*128  + ks*32 + kq*8);
      bf8 wnh = *(const bf8*)(Whh + (size_t)(256+cb)*128  + ks*32 + kq*8);
      #pragma unroll
      for (int i=0;i<2;i++){
        ar[i][p2]  = mfma_bf(ax[i], wri, ar[i][p2]);
        ar[i][p2]  = mfma_bf(ah[i], wrh, ar[i][p2]);
        az[i][p2]  = mfma_bf(ax[i], wzi, az[i][p2]);
        az[i][p2]  = mfma_bf(ah[i], wzh, az[i][p2]);
        ani[i][p2] = mfma_bf(ax[i], wni, ani[i][p2]);
        anh[i][p2] = mfma_bf(ah[i], wnh, anh[i][p2]);
      }
    }
  }
  __syncthreads();   // all Hbf reads in this block done before in-place writes
  #pragma unroll
  for (int i=0;i<2;i++)
    #pragma unroll
    for (int p2=0;p2<2;p2++){
      int jcol = wv*32 + p2*16 + r16;
      float br_  = bih[jcol]     + bhh[jcol];
      float bz_  = bih[128+jcol] + bhh[128+jcol];
      float bni_ = bih[256+jcol];
      float bnh_ = bhh[256+jcol];
      #pragma unroll
      for (int q=0;q<4;q++){
        int node = nb + i*16 + kq*4 + q;
        if (node < M){
          float r = sigmoidf_(ar[i][p2][q] + br_);
          float z = sigmoidf_(az[i][p2][q] + bz_);
          float n = tanhf_(ani[i][p2][q] + bni_ + r*(anh[i][p2][q] + bnh_));
          float h = Hf_in[(size_t)node*128 + jcol];
          float o = (1.f - z)*n + z*h;
          Hf_out[(size_t)node*128 + jcol] = o;
          Hb_out[(size_t)node*128 + jcol] = f2bf(o);
        }
      }
    }
}

extern "C" void kernel_launch(void* const* d_in, const int* in_sizes, int n_in,
                              void* d_out, int out_size, void* d_ws, size_t ws_size,
                              hipStream_t stream){
  const float* x       = (const float*)d_in[0];
  const int*   ei      = (const int*)d_in[1];
  const int*   etype   = (const int*)d_in[2];
  const float* sim_res = (const float*)d_in[3];
  const int*   seqlen  = (const int*)d_in[4];
  const float* eWih0 = (const float*)d_in[5];
  const float* eWhh0 = (const float*)d_in[6];
  const float* ebih0 = (const float*)d_in[7];
  const float* ebhh0 = (const float*)d_in[8];
  const float* eWih1 = (const float*)d_in[9];
  const float* eWhh1 = (const float*)d_in[10];
  const float* ebih1 = (const float*)d_in[11];
  const float* ebhh1 = (const float*)d_in[12];
  const float* Wq = (const float*)d_in[13];
  const float* Wk = (const float*)d_in[14];
  const float* Wv = (const float*)d_in[15];
  const float* op_emb = (const float*)d_in[16];
  const float* W1 = (const float*)d_in[17];
  const float* b1 = (const float*)d_in[18];
  const float* W2 = (const float*)d_in[19];
  const float* b2 = (const float*)d_in[20];
  const float* gWih = (const float*)d_in[21];
  const float* gWhh = (const float*)d_in[22];
  const float* gbih = (const float*)d_in[23];
  const float* gbhh = (const float*)d_in[24];

  const int N = in_sizes[0] / 16;
  const int E = in_sizes[2];

  char* p = (char*)d_ws;
  auto take = [&](size_t b)->void*{ void* r = (void*)p; p += (b + 255) & ~(size_t)255; return r; };

  float*  Hf    = (float*) take((size_t)N*128*4);
  ushort* Hb    = (ushort*)take((size_t)N*128*2);
  ushort* QKV   = (ushort*)take((size_t)N*384*2);
  ushort* Ag    = (ushort*)take((size_t)N*128*2);
  ushort* EF    = (ushort*)take((size_t)512*128*2);
  ushort* KVtab = (ushort*)take((size_t)512*256*2);
  ushort* wqkv  = (ushort*)take((size_t)3*16384*2);   // [wq | wk | wv] rows
  ushort* w1_b  = (ushort*)take((size_t)16384*2);
  ushort* w2_b  = (ushort*)take((size_t)16384*2);
  ushort* wih_b = (ushort*)take((size_t)49152*2);
  ushort* whh_b = (ushort*)take((size_t)49152*2);
  int* typ    = (int*)take((size_t)N*4);
  int* mlist  = (int*)take((size_t)N*4);
  int* cnt    = (int*)take(256);
  int* deg    = (int*)take((size_t)N*4);
  int* rowptr = (int*)take((size_t)(N+1)*4);
  int* cursor = (int*)take((size_t)N*4);
  int* es_src = (int*)take((size_t)E*4);
  int* es_tab = (int*)take((size_t)E*4);

  hipMemsetAsync(cnt, 0, 4, stream);
  hipMemsetAsync(deg, 0, (size_t)N*4, stream);

  int gE = (E + 255) / 256;
  k_prep<<<gE, 256, 0, stream>>>(x, ei + E, typ, mlist, cnt, deg, Hf, Hb, N, E);
  k_cvt<<<256, 256, 0, stream>>>(Wq, Wk, Wv, W1, W2, gWih, gWhh, op_emb,
                                 wqkv, w1_b, w2_b, wih_b, whh_b, EF);
  k_gemm<0,0><<<dim3(8,4), 256, 0, stream>>>(EF, wqkv + 16384, nullptr, KVtab, 512, 256);
  k_enc4<<<(N+15)/16, 512, 0, stream>>>(sim_res, seqlen, eWih0, eWhh0, ebih0, ebhh0,
                                        eWih1, eWhh1, ebih1, ebhh1, mlist, cnt, Hf, Hb);
  k_scan<<<1, 1024, 0, stream>>>(deg, rowptr, cursor, N);
  k_scatter<<<gE, 256, 0, stream>>>(ei, ei + E, etype, typ, cursor, es_src, es_tab, E);

  dim3 gq((N+63)/64, 6);   // fused QKV: N_out = 384
  for (int r=0; r<2; ++r){
    k_gemm<0,0><<<gq, 256, 0, stream>>>(Hb, wqkv, nullptr, QKV, N, 384);
    k_attn<<<(N+3)/4, 256, 0, stream>>>((const uint*)QKV, (const uint*)KVtab,
                                        rowptr, es_src, es_tab, (uint*)Ag, N);
    float* hf_out = (r == 1) ? (float*)d_out : Hf;
    k_fused<<<(N+31)/32, 256, 0, stream>>>(Ag, w1_b, b1, w2_b, b2,
                                           wih_b, whh_b, gbih, gbhh,
                                           Hb, Hf, hf_out, Hb, N);
  }
}

// Round 9
// 309.970 us; speedup vs baseline: 1.8548x; 1.0151x over previous
//
#include <hip/hip_runtime.h>

typedef unsigned int uint;
typedef unsigned short ushort;

typedef __attribute__((ext_vector_type(8))) short bf8;
typedef __attribute__((ext_vector_type(4))) float f32x4;
typedef _Float16 half_t;
typedef __attribute__((ext_vector_type(8))) half_t h8;

__device__ __forceinline__ ushort f2bf(float f){
  uint u = __builtin_bit_cast(uint, f);
  u = u + 0x7FFFu + ((u >> 16) & 1u);
  return (ushort)(u >> 16);
}
__device__ __forceinline__ float bfl(uint u){ return __builtin_bit_cast(float, u << 16); }
__device__ __forceinline__ float bfh(uint u){ return __builtin_bit_cast(float, u & 0xFFFF0000u); }
__device__ __forceinline__ uint pkhalf(float a, float b){
  ushort lo = __builtin_bit_cast(ushort, (half_t)a);
  ushort hi = __builtin_bit_cast(ushort, (half_t)b);
  return (uint)lo | ((uint)hi << 16);
}
__device__ __forceinline__ float sigmoidf_(float x){ return 1.0f/(1.0f + __expf(-x)); }
__device__ __forceinline__ float tanhf_(float x){
  x = fminf(15.0f, fmaxf(-15.0f, x));
  float t = __expf(-2.0f*x);
  return (1.0f - t)/(1.0f + t);
}
__device__ __forceinline__ f32x4 mfma_f16(h8 a, h8 b, f32x4 c){
  return __builtin_amdgcn_mfma_f32_16x16x32_f16(a, b, c, 0, 0, 0);
}
__device__ __forceinline__ f32x4 mfma_bf(bf8 a, bf8 b, f32x4 c){
  return __builtin_amdgcn_mfma_f32_16x16x32_bf16(a, b, c, 0, 0, 0);
}
__device__ __forceinline__ h8 ldw8(const float* p){
  f32x4 a = *(const f32x4*)p, b = *(const f32x4*)(p+4);
  h8 v;
  #pragma unroll
  for (int j=0;j<4;j++){ v[j] = (half_t)a[j]; v[4+j] = (half_t)b[j]; }
  return v;
}

// ---- fused prep: node type + mask-compact + edge degree + Hf/Hb zero-init ------
__global__ __launch_bounds__(256) void k_prep(const float* __restrict__ x,
    const int* __restrict__ dst,
    int* __restrict__ typ, int* __restrict__ mlist, int* __restrict__ cnt,
    int* __restrict__ deg, float* __restrict__ Hf, ushort* __restrict__ Hb,
    int N, int E){
  int i = blockIdx.x*256 + threadIdx.x;
  int total = gridDim.x*256;
  if (i < N){
    const float* xr = x + (size_t)i*16;
    int t = 0;
    #pragma unroll
    for (int j=0;j<16;j++) if (xr[j] > 0.5f) t = j;
    typ[i] = t;
    if (t < 2){
      int p = atomicAdd(cnt, 1);
      mlist[p] = i;
    }
  }
  if (i < E) atomicAdd(&deg[dst[i]], 1);
  f32x4 z4 = (f32x4)0.0f;
  for (int j = i; j < N*32; j += total) ((f32x4*)Hf)[j] = z4;
  uint2 z2; z2.x = 0u; z2.y = 0u;
  for (int j = i; j < N*32; j += total) ((uint2*)Hb)[j] = z2;
}

// ---- fused weight-convert + edge-feature table EF[512][128] ---------------------
__global__ __launch_bounds__(256) void k_cvt(
    const float* wq, const float* wk, const float* wv,
    const float* w1, const float* w2, const float* wih, const float* whh,
    const float* __restrict__ op_emb,
    ushort* oqkv, ushort* o1, ushort* o2, ushort* oih, ushort* ohh,
    ushort* __restrict__ EF){
  int i = blockIdx.x*256 + threadIdx.x;
  int stride = gridDim.x*256;
  for (int j=i; j<16384; j+=stride){
    oqkv[j]       = f2bf(wq[j]);
    oqkv[16384+j] = f2bf(wk[j]);
    oqkv[32768+j] = f2bf(wv[j]);
    o1[j] = f2bf(w1[j]);
    o2[j] = f2bf(w2[j]);
  }
  for (int j=i; j<49152; j+=stride){ oih[j]=f2bf(wih[j]); ohh[j]=f2bf(whh[j]); }
  for (int idx=i; idx<512*128; idx+=stride){
    int r = idx >> 7, d = idx & 127;
    int et = r >> 4, op = r & 15;
    int j = d >> 1;
    float inv = __expf(-0.1439115683f * (float)j);   // 10000^(-j/64)
    float ang = (float)et * inv;
    float v = (d & 1) ? __cosf(ang) : __sinf(ang);
    EF[idx] = f2bf(v + op_emb[op*128 + d]);
  }
}

// ---- generic bf16 MFMA GEMM: C[M,N] = act(A[M,128] @ B[N,128]^T + bias) --------
template<int RELU, int HASBIAS>
__global__ __launch_bounds__(256) void k_gemm(
    const ushort* __restrict__ A, const ushort* __restrict__ B,
    const float* __restrict__ bias, ushort* __restrict__ C, int M, int N){
  int lane = threadIdx.x & 63, wv = threadIdx.x >> 6;
  int tM = blockIdx.x*64 + (wv>>1)*32;
  int tN = blockIdx.y*64 + (wv&1)*32;
  int r16 = lane & 15, kg = (lane>>4)*8;
  f32x4 acc[2][2];
  #pragma unroll
  for (int i=0;i<2;i++)
    #pragma unroll
    for (int j=0;j<2;j++) acc[i][j] = (f32x4)0.0f;
  #pragma unroll
  for (int k0=0;k0<128;k0+=32){
    bf8 a[2], b[2];
    #pragma unroll
    for (int i=0;i<2;i++){
      int row = tM + i*16 + r16; if (row > M-1) row = M-1;
      a[i] = *(const bf8*)(A + (size_t)row*128 + k0 + kg);
    }
    #pragma unroll
    for (int j=0;j<2;j++){
      int col = tN + j*16 + r16;
      b[j] = *(const bf8*)(B + (size_t)col*128 + k0 + kg);
    }
    #pragma unroll
    for (int i=0;i<2;i++)
      #pragma unroll
      for (int j=0;j<2;j++)
        acc[i][j] = __builtin_amdgcn_mfma_f32_16x16x32_bf16(a[i], b[j], acc[i][j], 0, 0, 0);
  }
  #pragma unroll
  for (int i=0;i<2;i++)
    #pragma unroll
    for (int j=0;j<2;j++){
      int col = tN + j*16 + r16;
      float bs = HASBIAS ? bias[col] : 0.0f;
      #pragma unroll
      for (int q=0;q<4;q++){
        int row = tM + i*16 + (lane>>4)*4 + q;
        if (row < M){
          float v = acc[i][j][q] + bs;
          if (RELU) v = fmaxf(v, 0.0f);
          C[(size_t)row*N + col] = f2bf(v);
        }
      }
    }
}

// ---- pipelined swapped-MFMA 2-layer GRU encoder ---------------------------------
__global__ __launch_bounds__(512, 1) void k_enc4(
    const float* __restrict__ sim_res, const int* __restrict__ seqlen,
    const float* __restrict__ Wih0, const float* __restrict__ Whh0,
    const float* __restrict__ bih0, const float* __restrict__ bhh0,
    const float* __restrict__ Wih1, const float* __restrict__ Whh1,
    const float* __restrict__ bih1, const float* __restrict__ bhh1,
    const int* __restrict__ mlist, const int* __restrict__ cntp,
    float* __restrict__ Hf, ushort* __restrict__ Hb){
  int C = *cntp;
  int base = blockIdx.x * 16;
  if (C == 0 || base >= C) return;
  int tid = threadIdx.x;
  int w = tid >> 6, l = tid & 63;
  int node = l & 15, hi = l >> 4;
  int grp = w >> 2;          // 0 = layer 0 group, 1 = layer 1 group
  int ws  = w & 3;           // hidden-slice owner within group

  __shared__ int nod[16];
  __shared__ __align__(16) float  Xs[16*32*32];               // 64 KB
  __shared__ __align__(16) ushort H0h[2][16*64], H1h[2][16*64];

  if (tid < 16){
    int idx = base + tid;
    nod[tid] = mlist[idx < C ? idx : C-1];
  }
  for (int i = tid; i < 16*64; i += 512){
    H0h[0][i] = 0; H0h[1][i] = 0; H1h[0][i] = 0; H1h[1][i] = 0;
  }
  __syncthreads();   // nod ready

  for (int m = tid; m < 4096; m += 512){
    int nm = m >> 8, tt = (m >> 3) & 31, c = m & 7;
    int cs = c ^ (nm & 7);
    f32x4 v = *(const f32x4*)(sim_res + (size_t)nod[nm]*1024 + tt*32 + cs*4);
    *(f32x4*)(Xs + m*4) = v;
  }

  int rr = 16*ws + node;
  h8 zf;
  #pragma unroll
  for (int j=0;j<8;j++) zf[j] = (half_t)0.f;
  h8 Ai_r[2] = {zf, zf}, Ai_z[2] = {zf, zf}, Ai_n[2] = {zf, zf};
  h8 Ah_r[2], Ah_z[2], Ah_n[2];
  if (grp == 0){
    Ai_r[0] = ldw8(Wih0 + (size_t)rr*32        + hi*8);
    Ai_z[0] = ldw8(Wih0 + (size_t)(64+rr)*32   + hi*8);
    Ai_n[0] = ldw8(Wih0 + (size_t)(128+rr)*32  + hi*8);
    #pragma unroll
    for (int s=0;s<2;s++){
      Ah_r[s] = ldw8(Whh0 + (size_t)rr*64       + s*32 + hi*8);
      Ah_z[s] = ldw8(Whh0 + (size_t)(64+rr)*64  + s*32 + hi*8);
      Ah_n[s] = ldw8(Whh0 + (size_t)(128+rr)*64 + s*32 + hi*8);
    }
  } else {
    #pragma unroll
    for (int s=0;s<2;s++){
      Ai_r[s] = ldw8(Wih1 + (size_t)rr*64       + s*32 + hi*8);
      Ai_z[s] = ldw8(Wih1 + (size_t)(64+rr)*64  + s*32 + hi*8);
      Ai_n[s] = ldw8(Wih1 + (size_t)(128+rr)*64 + s*32 + hi*8);
      Ah_r[s] = ldw8(Whh1 + (size_t)rr*64       + s*32 + hi*8);
      Ah_z[s] = ldw8(Whh1 + (size_t)(64+rr)*64  + s*32 + hi*8);
      Ah_n[s] = ldw8(Whh1 + (size_t)(128+rr)*64 + s*32 + hi*8);
    }
  }
  const float* bi = grp ? bih1 : bih0;
  const float* bh = grp ? bhh1 : bhh0;
  float br[4], bz[4], bni[4], bnh[4];
  #pragma unroll
  for (int q=0;q<4;q++){
    int row = 16*ws + hi*4 + q;
    br[q]  = bi[row]      + bh[row];
    bz[q]  = bi[64+row]   + bh[64+row];
    bni[q] = bi[128+row];
    bnh[q] = bh[128+row];
  }

  int T = *seqlen; if (T > 32) T = 32; if (T < 0) T = 0;
  float hm[4] = {0.f, 0.f, 0.f, 0.f};

  const int swz = (node & 7) << 4;
  const int wo  = node * 128;
  const int wba = 32*ws + 8*hi;
  const int rd0 = wo + ((16*hi) ^ swz);
  const int rd1 = wo + ((64 + 16*hi) ^ swz);
  const int xc0 = (2*hi)   ^ (node & 7);
  const int xc1 = (2*hi+1) ^ (node & 7);
  const float* xrow = Xs + node*1024;

  __syncthreads();   // Xs + zeroed state buffers ready

  for (int k = 0; k <= T; ++k){
    int cur = k & 1;
    bool act = grp ? (k >= 1) : (k < T);
    if (act){
      h8 in0 = zf, in1 = zf, st0, st1;
      if (grp == 0){
        f32x4 xa = *(const f32x4*)(xrow + k*32 + xc0*4);
        f32x4 xb = *(const f32x4*)(xrow + k*32 + xc1*4);
        #pragma unroll
        for (int j=0;j<4;j++){ in0[j] = (half_t)xa[j]; in0[4+j] = (half_t)xb[j]; }
        st0 = *(const h8*)((const char*)H0h[cur] + rd0);
        st1 = *(const h8*)((const char*)H0h[cur] + rd1);
      } else {
        in0 = *(const h8*)((const char*)H0h[cur] + rd0);
        in1 = *(const h8*)((const char*)H0h[cur] + rd1);
        st0 = *(const h8*)((const char*)H1h[cur] + rd0);
        st1 = *(const h8*)((const char*)H1h[cur] + rd1);
      }
      f32x4 ar = {br[0],br[1],br[2],br[3]};
      f32x4 az = {bz[0],bz[1],bz[2],bz[3]};
      f32x4 an = {bni[0],bni[1],bni[2],bni[3]};
      f32x4 hn = {bnh[0],bnh[1],bnh[2],bnh[3]};
      ar = mfma_f16(Ai_r[0], in0, ar);
      az = mfma_f16(Ai_z[0], in0, az);
      an = mfma_f16(Ai_n[0], in0, an);
      if (grp){
        ar = mfma_f16(Ai_r[1], in1, ar);
        az = mfma_f16(Ai_z[1], in1, az);
        an = mfma_f16(Ai_n[1], in1, an);
      }
      ar = mfma_f16(Ah_r[0], st0, ar); ar = mfma_f16(Ah_r[1], st1, ar);
      az = mfma_f16(Ah_z[0], st0, az); az = mfma_f16(Ah_z[1], st1, az);
      hn = mfma_f16(Ah_n[0], st0, hn); hn = mfma_f16(Ah_n[1], st1, hn);
      #pragma unroll
      for (int q=0;q<4;q++){
        float r = sigmoidf_(ar[q]);
        float z = sigmoidf_(az[q]);
        float n = tanhf_(an[q] + r*hn[q]);
        hm[q] = (1.f - z)*n + z*hm[q];
      }
      char* outb = grp ? (char*)H1h[cur^1] : (char*)H0h[cur^1];
      *(uint*)(outb + wo + ( wba      ^ swz)) = pkhalf(hm[0], hm[1]);
      *(uint*)(outb + wo + ((wba + 4) ^ swz)) = pkhalf(hm[2], hm[3]);
    }
    __syncthreads();
  }

  if (base + node < C){
    int nd = nod[node];
    int off = grp ? 64 : 0;
    #pragma unroll
    for (int q=0;q<4;q++){
      int j = off + 16*ws + hi*4 + q;
      Hf[(size_t)nd*128 + j] = hm[q];
      Hb[(size_t)nd*128 + j] = f2bf(hm[q]);
    }
  }
}

// ---- CSR build -------------------------------------------------------------------
__global__ __launch_bounds__(1024) void k_scan(const int* __restrict__ deg,
    int* __restrict__ rowptr, int* __restrict__ cursor, int N){
  __shared__ int wsum[16];
  __shared__ int carry_s;
  int tid = threadIdx.x, lane = tid & 63, wid = tid >> 6;
  if (tid == 0) carry_s = 0;
  __syncthreads();
  int nch = (N + 1023) / 1024;
  for (int c=0; c<nch; ++c){
    int i = c*1024 + tid;
    int v = (i < N) ? deg[i] : 0;
    int x = v;
    #pragma unroll
    for (int off=1; off<64; off<<=1){
      int t = __shfl_up(x, off, 64);
      if (lane >= off) x += t;
    }
    if (lane == 63) wsum[wid] = x;
    __syncthreads();
    int base = carry_s;
    int woff = 0;
    for (int w2=0; w2<wid; ++w2) woff += wsum[w2];
    int excl = base + woff + x - v;
    if (i < N){ rowptr[i] = excl; cursor[i] = excl; }
    __syncthreads();
    if (tid == 0){
      int s = 0;
      for (int w2=0; w2<16; ++w2) s += wsum[w2];
      carry_s = base + s;
    }
    __syncthreads();
  }
  if (tid == 0) rowptr[N] = carry_s;
}

__global__ __launch_bounds__(256) void k_scatter(const int* __restrict__ src,
    const int* __restrict__ dst, const int* __restrict__ etype, const int* __restrict__ typ,
    int* __restrict__ cursor, int* __restrict__ es_src, int* __restrict__ es_tab, int E){
  int e = blockIdx.x*256 + threadIdx.x;
  if (e < E){
    int d = dst[e];
    int pos = atomicAdd(&cursor[d], 1);
    es_src[pos] = src[e];
    es_tab[pos] = etype[e]*16 + typ[d];
  }
}

// ---- attention: one wave per dst node, online softmax, 2-edge unrolled -----------
__global__ __launch_bounds__(256) void k_attn(
    const uint* __restrict__ QKV, const uint* __restrict__ KVT,
    const int* __restrict__ rowptr, const int* __restrict__ es_src, const int* __restrict__ es_tab,
    uint* __restrict__ aggr, int N){
  int w = threadIdx.x >> 6, lane = threadIdx.x & 63;
  int dst = blockIdx.x*4 + w;
  if (dst >= N) return;
  uint qu = QKV[(size_t)dst*192 + lane];
  const float scale = 0.08838834764831845f;  // 1/sqrt(128)
  float q0 = bfl(qu)*scale, q1 = bfh(qu)*scale;
  int s0 = rowptr[dst], s1 = rowptr[dst+1];
  float m = -1e30f, den = 0.f, a0 = 0.f, a1 = 0.f;
  int p = s0;
  for (; p + 2 <= s1; p += 2){
    int srcA = es_src[p],   tbA = es_tab[p];
    int srcB = es_src[p+1], tbB = es_tab[p+1];
    uint kuA = QKV[(size_t)srcA*192 + 64 + lane],  ktA = KVT[(size_t)tbA*128 + lane];
    uint vuA = QKV[(size_t)srcA*192 + 128 + lane], vtA = KVT[(size_t)tbA*128 + 64 + lane];
    uint kuB = QKV[(size_t)srcB*192 + 64 + lane],  ktB = KVT[(size_t)tbB*128 + lane];
    uint vuB = QKV[(size_t)srcB*192 + 128 + lane], vtB = KVT[(size_t)tbB*128 + 64 + lane];
    float sA = q0*(bfl(kuA)+bfl(ktA)) + q1*(bfh(kuA)+bfh(ktA));
    float sB = q0*(bfl(kuB)+bfl(ktB)) + q1*(bfh(kuB)+bfh(ktB));
    #pragma unroll
    for (int off=32; off; off>>=1){
      sA += __shfl_xor(sA, off);
      sB += __shfl_xor(sB, off);
    }
    float nm = fmaxf(m, fmaxf(sA, sB));
    float c  = __expf(m - nm);
    float pA = __expf(sA - nm), pB = __expf(sB - nm);
    den = den*c + pA + pB;
    a0  = a0*c + pA*(bfl(vuA)+bfl(vtA)) + pB*(bfl(vuB)+bfl(vtB));
    a1  = a1*c + pA*(bfh(vuA)+bfh(vtA)) + pB*(bfh(vuB)+bfh(vtB));
    m = nm;
  }
  for (; p < s1; ++p){
    int src = es_src[p], tb = es_tab[p];
    uint ku = QKV[(size_t)src*192 + 64 + lane],  kt = KVT[(size_t)tb*128 + lane];
    uint vu = QKV[(size_t)src*192 + 128 + lane], vt = KVT[(size_t)tb*128 + 64 + lane];
    float s = q0*(bfl(ku)+bfl(kt)) + q1*(bfh(ku)+bfh(kt));
    #pragma unroll
    for (int off=32; off; off>>=1) s += __shfl_xor(s, off);
    float nm = fmaxf(m, s);
    float c  = __expf(m - nm);
    float pw = __expf(s - nm);
    den = den*c + pw;
    a0  = a0*c + pw*(bfl(vu)+bfl(vt));
    a1  = a1*c + pw*(bfh(vu)+bfh(vt));
    m = nm;
  }
  float inv = 1.0f/(den + 1e-9f);
  a0 *= inv; a1 *= inv;
  aggr[(size_t)dst*64 + lane] = ((uint)f2bf(a1) << 16) | (uint)f2bf(a0);
}

// ---- fused MLP1 + MLP2 + GRU cell, issue-early + 2-deep weight pipeline -----------
// NOTE: Hbf aliases Hb_out, Hf_in may alias Hf_out — no __restrict__ on those.
struct W12 { bf8 ri0, rh0, zi0, zh0, ni0, nh0, ri1, rh1, zi1, zh1, ni1, nh1; };
__device__ __forceinline__ W12 ldw12(const ushort* __restrict__ Wih,
                                     const ushort* __restrict__ Whh,
                                     int cb0, int cb1, int off){
  W12 w;
  w.ri0 = *(const bf8*)(Wih + (size_t)cb0*128       + off);
  w.rh0 = *(const bf8*)(Whh + (size_t)cb0*128       + off);
  w.zi0 = *(const bf8*)(Wih + (size_t)(128+cb0)*128 + off);
  w.zh0 = *(const bf8*)(Whh + (size_t)(128+cb0)*128 + off);
  w.ni0 = *(const bf8*)(Wih + (size_t)(256+cb0)*128 + off);
  w.nh0 = *(const bf8*)(Whh + (size_t)(256+cb0)*128 + off);
  w.ri1 = *(const bf8*)(Wih + (size_t)cb1*128       + off);
  w.rh1 = *(const bf8*)(Whh + (size_t)cb1*128       + off);
  w.zi1 = *(const bf8*)(Wih + (size_t)(128+cb1)*128 + off);
  w.zh1 = *(const bf8*)(Whh + (size_t)(128+cb1)*128 + off);
  w.ni1 = *(const bf8*)(Wih + (size_t)(256+cb1)*128 + off);
  w.nh1 = *(const bf8*)(Whh + (size_t)(256+cb1)*128 + off);
  return w;
}

__global__ __launch_bounds__(256, 2) void k_fused(
    const ushort* __restrict__ Ag,
    const ushort* __restrict__ W1b, const float* __restrict__ b1,
    const ushort* __restrict__ W2b, const float* __restrict__ b2,
    const ushort* __restrict__ Wih, const ushort* __restrict__ Whh,
    const float* __restrict__ bih, const float* __restrict__ bhh,
    const ushort* Hbf, const float* Hf_in,
    float* Hf_out, ushort* Hb_out, int M){
  int lane = threadIdx.x & 63, wv = threadIdx.x >> 6;
  int nb = blockIdx.x * 32;
  int r16 = lane & 15, kq = lane >> 4;

  __shared__ __align__(16) ushort T[32*128];   // 8 KB swizzled intermediate

  // ---------- issue-early: all global operands into registers ----------
  bf8 agld[2][4], ahld[2][4];
  #pragma unroll
  for (int i=0;i<2;i++){
    int grow = nb + i*16 + r16; if (grow > M-1) grow = M-1;
    #pragma unroll
    for (int ks=0;ks<4;ks++){
      agld[i][ks] = *(const bf8*)(Ag  + (size_t)grow*128 + ks*32 + kq*8);
      ahld[i][ks] = *(const bf8*)(Hbf + (size_t)grow*128 + ks*32 + kq*8);
    }
  }
  float hprev[2][2][4];
  #pragma unroll
  for (int i=0;i<2;i++)
    #pragma unroll
    for (int p2=0;p2<2;p2++){
      int jcol = wv*32 + p2*16 + r16;
      #pragma unroll
      for (int q=0;q<4;q++){
        int node = nb + i*16 + kq*4 + q;
        hprev[i][p2][q] = Hf_in[(size_t)(node < M ? node : M-1)*128 + jcol];
      }
    }

  const int col0 = wv*32 + r16, col1 = col0 + 16;

  // ---------- phase 1: T = relu(Ag @ W1^T + b1), 2-deep W pipeline ----------
  {
    f32x4 acc[2][2];
    #pragma unroll
    for (int i=0;i<2;i++)
      #pragma unroll
      for (int j=0;j<2;j++) acc[i][j] = (f32x4)0.0f;
    bf8 wb0 = *(const bf8*)(W1b + (size_t)col0*128 + kq*8);
    bf8 wb1 = *(const bf8*)(W1b + (size_t)col1*128 + kq*8);
    #pragma unroll
    for (int ks=0; ks<4; ++ks){
      bf8 n0, n1;
      if (ks < 3){
        n0 = *(const bf8*)(W1b + (size_t)col0*128 + (ks+1)*32 + kq*8);
        n1 = *(const bf8*)(W1b + (size_t)col1*128 + (ks+1)*32 + kq*8);
      }
      #pragma unroll
      for (int i=0;i<2;i++){
        acc[i][0] = mfma_bf(agld[i][ks], wb0, acc[i][0]);
        acc[i][1] = mfma_bf(agld[i][ks], wb1, acc[i][1]);
      }
      if (ks < 3){ wb0 = n0; wb1 = n1; }
    }
    #pragma unroll
    for (int i=0;i<2;i++)
      #pragma unroll
      for (int j=0;j<2;j++){
        int col = wv*32 + j*16 + r16;
        float bs = b1[col];
        #pragma unroll
        for (int q=0;q<4;q++){
          int row = i*16 + kq*4 + q;
          float v = fmaxf(acc[i][j][q] + bs, 0.0f);
          *(ushort*)((char*)T + ((row*256 + col*2) ^ ((row&7)<<4))) = f2bf(v);
        }
      }
  }
  __syncthreads();

  // ---------- phase 2: X = T @ W2^T + b2 (re-uses T after read barrier) ----------
  {
    f32x4 acc[2][2];
    #pragma unroll
    for (int i=0;i<2;i++)
      #pragma unroll
      for (int j=0;j<2;j++) acc[i][j] = (f32x4)0.0f;
    bf8 wb0 = *(const bf8*)(W2b + (size_t)col0*128 + kq*8);
    bf8 wb1 = *(const bf8*)(W2b + (size_t)col1*128 + kq*8);
    #pragma unroll
    for (int ks=0; ks<4; ++ks){
      bf8 n0, n1;
      if (ks < 3){
        n0 = *(const bf8*)(W2b + (size_t)col0*128 + (ks+1)*32 + kq*8);
        n1 = *(const bf8*)(W2b + (size_t)col1*128 + (ks+1)*32 + kq*8);
      }
      bf8 ax0, ax1;
      {
        int row = r16;
        ax0 = *(const bf8*)((const char*)T + row*256 + ((ks*64 + kq*16) ^ ((row&7)<<4)));
      }
      {
        int row = 16 + r16;
        ax1 = *(const bf8*)((const char*)T + row*256 + ((ks*64 + kq*16) ^ ((row&7)<<4)));
      }
      acc[0][0] = mfma_bf(ax0, wb0, acc[0][0]);
      acc[0][1] = mfma_bf(ax0, wb1, acc[0][1]);
      acc[1][0] = mfma_bf(ax1, wb0, acc[1][0]);
      acc[1][1] = mfma_bf(ax1, wb1, acc[1][1]);
      if (ks < 3){ wb0 = n0; wb1 = n1; }
    }
    __syncthreads();   // all T reads complete before overwrite
    #pragma unroll
    for (int i=0;i<2;i++)
      #pragma unroll
      for (int j=0;j<2;j++){
        int col = wv*32 + j*16 + r16;
        float bs = b2[col];
        #pragma unroll
        for (int q=0;q<4;q++){
          int row = i*16 + kq*4 + q;
          *(ushort*)((char*)T + ((row*256 + col*2) ^ ((row&7)<<4))) = f2bf(acc[i][j][q] + bs);
        }
      }
  }
  __syncthreads();

  // ---------- phase 3: GRU gates, 2-deep weight pipeline ----------
  f32x4 ar[2][2], az[2][2], ani[2][2], anh[2][2];
  #pragma unroll
  for (int i=0;i<2;i++)
    #pragma unroll
    for (int p2=0;p2<2;p2++){
      ar[i][p2] = (f32x4)0.0f; az[i][p2] = (f32x4)0.0f;
      ani[i][p2] = (f32x4)0.0f; anh[i][p2] = (f32x4)0.0f;
    }
  W12 wc = ldw12(Wih, Whh, col0, col1, kq*8);
  #pragma unroll
  for (int ks=0; ks<4; ++ks){
    W12 wn;
    if (ks < 3) wn = ldw12(Wih, Whh, col0, col1, (ks+1)*32 + kq*8);
    bf8 ax0, ax1;
    {
      int row = r16;
      ax0 = *(const bf8*)((const char*)T + row*256 + ((ks*64 + kq*16) ^ ((row&7)<<4)));
    }
    {
      int row = 16 + r16;
      ax1 = *(const bf8*)((const char*)T + row*256 + ((ks*64 + kq*16) ^ ((row&7)<<4)));
    }
    // p2 = 0
    ar[0][0]  = mfma_bf(ax0,          wc.ri0, ar[0][0]);
    ar[0][0]  = mfma_bf(ahld[0][ks],  wc.rh0, ar[0][0]);
    az[0][0]  = mfma_bf(ax0,          wc.zi0, az[0][0]);
    az[0][0]  = mfma_bf(ahld[0][ks],  wc.zh0, az[0][0]);
    ani[0][0] = mfma_bf(ax0,          wc.ni0, ani[0][0]);
    anh[0][0] = mfma_bf(ahld[0][ks],  wc.nh0, anh[0][0]);
    ar[1][0]  = mfma_bf(ax1,          wc.ri0, ar[1][0]);
    ar[1][0]  = mfma_bf(ahld[1][ks],  wc.rh0, ar[1][0]);
    az[1][0]  = mfma_bf(ax1,          wc.zi0, az[1][0]);
    az[1][0]  = mfma_bf(ahld[1][ks],  wc.zh0, az[1][0]);
    ani[1][0] = mfma_bf(ax1,          wc.ni0, ani[1][0]);
    anh[1][0] = mfma_bf(ahld[1][ks],  wc.nh0, anh[1][0]);
    // p2 = 1
    ar[0][1]  = mfma_bf(ax0,          wc.ri1, ar[0][1]);
    ar[0][1]  = mfma_bf(ahld[0][ks],  wc.rh1, ar[0][1]);
    az[0][1]  = mfma_bf(ax0,          wc.zi1, az[0][1]);
    az[0][1]  = mfma_bf(ahld[0][ks],  wc.zh1, az[0][1]);
    ani[0][1] = mfma_bf(ax0,          wc.ni1, ani[0][1]);
    anh[0][1] = mfma_bf(ahld[0][ks],  wc.nh1, anh[0][1]);
    ar[1][1]  = mfma_bf(ax1,          wc.ri1, ar[1][1]);
    ar[1][1]  = mfma_bf(ahld[1][ks],  wc.rh1, ar[1][1]);
    az[1][1]  = mfma_bf(ax1,          wc.zi1, az[1][1]);
    az[1][1]  = mfma_bf(ahld[1][ks],  wc.zh1, az[1][1]);
    ani[1][1] = mfma_bf(ax1,          wc.ni1, ani[1][1]);
    anh[1][1] = mfma_bf(ahld[1][ks],  wc.nh1, anh[1][1]);
    if (ks < 3) wc = wn;
  }
  // epilogue: gates + in-lane h update (no barrier needed — all Hbf/Hf_in reads
  // happened at kernel entry; each block owns its 32 rows exclusively)
  #pragma unroll
  for (int i=0;i<2;i++)
    #pragma unroll
    for (int p2=0;p2<2;p2++){
      int jcol = wv*32 + p2*16 + r16;
      float br_  = bih[jcol]     + bhh[jcol];
      float bz_  = bih[128+jcol] + bhh[128+jcol];
      float bni_ = bih[256+jcol];
      float bnh_ = bhh[256+jcol];
      #pragma unroll
      for (int q=0;q<4;q++){
        int node = nb + i*16 + kq*4 + q;
        if (node < M){
          float r = sigmoidf_(ar[i][p2][q] + br_);
          float z = sigmoidf_(az[i][p2][q] + bz_);
          float n = tanhf_(ani[i][p2][q] + bni_ + r*(anh[i][p2][q] + bnh_));
          float h = hprev[i][p2][q];
          float o = (1.f - z)*n + z*h;
          Hf_out[(size_t)node*128 + jcol] = o;
          Hb_out[(size_t)node*128 + jcol] = f2bf(o);
        }
      }
    }
}

extern "C" void kernel_launch(void* const* d_in, const int* in_sizes, int n_in,
                              void* d_out, int out_size, void* d_ws, size_t ws_size,
                              hipStream_t stream){
  const float* x       = (const float*)d_in[0];
  const int*   ei      = (const int*)d_in[1];
  const int*   etype   = (const int*)d_in[2];
  const float* sim_res = (const float*)d_in[3];
  const int*   seqlen  = (const int*)d_in[4];
  const float* eWih0 = (const float*)d_in[5];
  const float* eWhh0 = (const float*)d_in[6];
  const float* ebih0 = (const float*)d_in[7];
  const float* ebhh0 = (const float*)d_in[8];
  const float* eWih1 = (const float*)d_in[9];
  const float* eWhh1 = (const float*)d_in[10];
  const float* ebih1 = (const float*)d_in[11];
  const float* ebhh1 = (const float*)d_in[12];
  const float* Wq = (const float*)d_in[13];
  const float* Wk = (const float*)d_in[14];
  const float* Wv = (const float*)d_in[15];
  const float* op_emb = (const float*)d_in[16];
  const float* W1 = (const float*)d_in[17];
  const float* b1 = (const float*)d_in[18];
  const float* W2 = (const float*)d_in[19];
  const float* b2 = (const float*)d_in[20];
  const float* gWih = (const float*)d_in[21];
  const float* gWhh = (const float*)d_in[22];
  const float* gbih = (const float*)d_in[23];
  const float* gbhh = (const float*)d_in[24];

  const int N = in_sizes[0] / 16;
  const int E = in_sizes[2];

  char* p = (char*)d_ws;
  auto take = [&](size_t b)->void*{ void* r = (void*)p; p += (b + 255) & ~(size_t)255; return r; };

  float*  Hf    = (float*) take((size_t)N*128*4);
  ushort* Hb    = (ushort*)take((size_t)N*128*2);
  ushort* QKV   = (ushort*)take((size_t)N*384*2);
  ushort* Ag    = (ushort*)take((size_t)N*128*2);
  ushort* EF    = (ushort*)take((size_t)512*128*2);
  ushort* KVtab = (ushort*)take((size_t)512*256*2);
  ushort* wqkv  = (ushort*)take((size_t)3*16384*2);   // [wq | wk | wv] rows
  ushort* w1_b  = (ushort*)take((size_t)16384*2);
  ushort* w2_b  = (ushort*)take((size_t)16384*2);
  ushort* wih_b = (ushort*)take((size_t)49152*2);
  ushort* whh_b = (ushort*)take((size_t)49152*2);
  int* typ    = (int*)take((size_t)N*4);
  int* mlist  = (int*)take((size_t)N*4);
  int* cnt    = (int*)take(256);
  int* deg    = (int*)take((size_t)N*4);
  int* rowptr = (int*)take((size_t)(N+1)*4);
  int* cursor = (int*)take((size_t)N*4);
  int* es_src = (int*)take((size_t)E*4);
  int* es_tab = (int*)take((size_t)E*4);

  hipMemsetAsync(cnt, 0, 4, stream);
  hipMemsetAsync(deg, 0, (size_t)N*4, stream);

  int gE = (E + 255) / 256;
  k_prep<<<gE, 256, 0, stream>>>(x, ei + E, typ, mlist, cnt, deg, Hf, Hb, N, E);
  k_cvt<<<256, 256, 0, stream>>>(Wq, Wk, Wv, W1, W2, gWih, gWhh, op_emb,
                                 wqkv, w1_b, w2_b, wih_b, whh_b, EF);
  k_gemm<0,0><<<dim3(8,4), 256, 0, stream>>>(EF, wqkv + 16384, nullptr, KVtab, 512, 256);
  k_enc4<<<(N+15)/16, 512, 0, stream>>>(sim_res, seqlen, eWih0, eWhh0, ebih0, ebhh0,
                                        eWih1, eWhh1, ebih1, ebhh1, mlist, cnt, Hf, Hb);
  k_scan<<<1, 1024, 0, stream>>>(deg, rowptr, cursor, N);
  k_scatter<<<gE, 256, 0, stream>>>(ei, ei + E, etype, typ, cursor, es_src, es_tab, E);

  dim3 gq((N+63)/64, 6);   // fused QKV: N_out = 384
  for (int r=0; r<2; ++r){
    k_gemm<0,0><<<gq, 256, 0, stream>>>(Hb, wqkv, nullptr, QKV, N, 384);
    k_attn<<<(N+3)/4, 256, 0, stream>>>((const uint*)QKV, (const uint*)KVtab,
                                        rowptr, es_src, es_tab, (uint*)Ag, N);
    float* hf_out = (r == 1) ? (float*)d_out : Hf;
    k_fused<<<(N+31)/32, 256, 0, stream>>>(Ag, w1_b, b1, w2_b, b2,
                                           wih_b, whh_b, gbih, gbhh,
                                           Hb, Hf, hf_out, Hb, N);
  }
}

// Round 10
// 309.018 us; speedup vs baseline: 1.8605x; 1.0031x over previous
//
#include <hip/hip_runtime.h>

typedef unsigned int uint;
typedef unsigned short ushort;

typedef __attribute__((ext_vector_type(8))) short bf8;
typedef __attribute__((ext_vector_type(4))) float f32x4;
typedef _Float16 half_t;
typedef __attribute__((ext_vector_type(8))) half_t h8;

__device__ __forceinline__ ushort f2bf(float f){
  uint u = __builtin_bit_cast(uint, f);
  u = u + 0x7FFFu + ((u >> 16) & 1u);
  return (ushort)(u >> 16);
}
__device__ __forceinline__ float bfl(uint u){ return __builtin_bit_cast(float, u << 16); }
__device__ __forceinline__ float bfh(uint u){ return __builtin_bit_cast(float, u & 0xFFFF0000u); }
__device__ __forceinline__ uint pkhalf(float a, float b){
  ushort lo = __builtin_bit_cast(ushort, (half_t)a);
  ushort hi = __builtin_bit_cast(ushort, (half_t)b);
  return (uint)lo | ((uint)hi << 16);
}
__device__ __forceinline__ float sigmoidf_(float x){ return 1.0f/(1.0f + __expf(-x)); }
__device__ __forceinline__ float tanhf_(float x){
  x = fminf(15.0f, fmaxf(-15.0f, x));
  float t = __expf(-2.0f*x);
  return (1.0f - t)/(1.0f + t);
}
__device__ __forceinline__ f32x4 mfma_f16(h8 a, h8 b, f32x4 c){
  return __builtin_amdgcn_mfma_f32_16x16x32_f16(a, b, c, 0, 0, 0);
}
__device__ __forceinline__ f32x4 mfma_bf(bf8 a, bf8 b, f32x4 c){
  return __builtin_amdgcn_mfma_f32_16x16x32_bf16(a, b, c, 0, 0, 0);
}
__device__ __forceinline__ h8 ldw8(const float* p){
  f32x4 a = *(const f32x4*)p, b = *(const f32x4*)(p+4);
  h8 v;
  #pragma unroll
  for (int j=0;j<4;j++){ v[j] = (half_t)a[j]; v[4+j] = (half_t)b[j]; }
  return v;
}

// ---- fused prep: node type + mask-compact + edge degree + Hf/Hb zero-init ------
__global__ __launch_bounds__(256) void k_prep(const float* __restrict__ x,
    const int* __restrict__ dst,
    int* __restrict__ typ, int* __restrict__ mlist, int* __restrict__ cnt,
    int* __restrict__ deg, float* __restrict__ Hf, ushort* __restrict__ Hb,
    int N, int E){
  int i = blockIdx.x*256 + threadIdx.x;
  int total = gridDim.x*256;
  if (i < N){
    const float* xr = x + (size_t)i*16;
    int t = 0;
    #pragma unroll
    for (int j=0;j<16;j++) if (xr[j] > 0.5f) t = j;
    typ[i] = t;
    if (t < 2){
      int p = atomicAdd(cnt, 1);
      mlist[p] = i;
    }
  }
  if (i < E) atomicAdd(&deg[dst[i]], 1);
  f32x4 z4 = (f32x4)0.0f;
  for (int j = i; j < N*32; j += total) ((f32x4*)Hf)[j] = z4;
  uint2 z2; z2.x = 0u; z2.y = 0u;
  for (int j = i; j < N*32; j += total) ((uint2*)Hb)[j] = z2;
}

// ---- fused weight-convert + edge-feature table EF[512][128] ---------------------
__global__ __launch_bounds__(256) void k_cvt(
    const float* wq, const float* wk, const float* wv,
    const float* w1, const float* w2, const float* wih, const float* whh,
    const float* __restrict__ op_emb,
    ushort* oqkv, ushort* o1, ushort* o2, ushort* oih, ushort* ohh,
    ushort* __restrict__ EF){
  int i = blockIdx.x*256 + threadIdx.x;
  int stride = gridDim.x*256;
  for (int j=i; j<16384; j+=stride){
    oqkv[j]       = f2bf(wq[j]);
    oqkv[16384+j] = f2bf(wk[j]);
    oqkv[32768+j] = f2bf(wv[j]);
    o1[j] = f2bf(w1[j]);
    o2[j] = f2bf(w2[j]);
  }
  for (int j=i; j<49152; j+=stride){ oih[j]=f2bf(wih[j]); ohh[j]=f2bf(whh[j]); }
  for (int idx=i; idx<512*128; idx+=stride){
    int r = idx >> 7, d = idx & 127;
    int et = r >> 4, op = r & 15;
    int j = d >> 1;
    float inv = __expf(-0.1439115683f * (float)j);   // 10000^(-j/64)
    float ang = (float)et * inv;
    float v = (d & 1) ? __cosf(ang) : __sinf(ang);
    EF[idx] = f2bf(v + op_emb[op*128 + d]);
  }
}

// ---- generic bf16 MFMA GEMM: C[M,N] = act(A[M,128] @ B[N,128]^T + bias) --------
template<int RELU, int HASBIAS>
__global__ __launch_bounds__(256) void k_gemm(
    const ushort* __restrict__ A, const ushort* __restrict__ B,
    const float* __restrict__ bias, ushort* __restrict__ C, int M, int N){
  int lane = threadIdx.x & 63, wv = threadIdx.x >> 6;
  int tM = blockIdx.x*64 + (wv>>1)*32;
  int tN = blockIdx.y*64 + (wv&1)*32;
  int r16 = lane & 15, kg = (lane>>4)*8;
  f32x4 acc[2][2];
  #pragma unroll
  for (int i=0;i<2;i++)
    #pragma unroll
    for (int j=0;j<2;j++) acc[i][j] = (f32x4)0.0f;
  #pragma unroll
  for (int k0=0;k0<128;k0+=32){
    bf8 a[2], b[2];
    #pragma unroll
    for (int i=0;i<2;i++){
      int row = tM + i*16 + r16; if (row > M-1) row = M-1;
      a[i] = *(const bf8*)(A + (size_t)row*128 + k0 + kg);
    }
    #pragma unroll
    for (int j=0;j<2;j++){
      int col = tN + j*16 + r16;
      b[j] = *(const bf8*)(B + (size_t)col*128 + k0 + kg);
    }
    #pragma unroll
    for (int i=0;i<2;i++)
      #pragma unroll
      for (int j=0;j<2;j++)
        acc[i][j] = __builtin_amdgcn_mfma_f32_16x16x32_bf16(a[i], b[j], acc[i][j], 0, 0, 0);
  }
  #pragma unroll
  for (int i=0;i<2;i++)
    #pragma unroll
    for (int j=0;j<2;j++){
      int col = tN + j*16 + r16;
      float bs = HASBIAS ? bias[col] : 0.0f;
      #pragma unroll
      for (int q=0;q<4;q++){
        int row = tM + i*16 + (lane>>4)*4 + q;
        if (row < M){
          float v = acc[i][j][q] + bs;
          if (RELU) v = fmaxf(v, 0.0f);
          C[(size_t)row*N + col] = f2bf(v);
        }
      }
    }
}

// ---- pipelined swapped-MFMA 2-layer GRU encoder ---------------------------------
__global__ __launch_bounds__(512, 1) void k_enc4(
    const float* __restrict__ sim_res, const int* __restrict__ seqlen,
    const float* __restrict__ Wih0, const float* __restrict__ Whh0,
    const float* __restrict__ bih0, const float* __restrict__ bhh0,
    const float* __restrict__ Wih1, const float* __restrict__ Whh1,
    const float* __restrict__ bih1, const float* __restrict__ bhh1,
    const int* __restrict__ mlist, const int* __restrict__ cntp,
    float* __restrict__ Hf, ushort* __restrict__ Hb){
  int C = *cntp;
  int base = blockIdx.x * 16;
  if (C == 0 || base >= C) return;
  int tid = threadIdx.x;
  int w = tid >> 6, l = tid & 63;
  int node = l & 15, hi = l >> 4;
  int grp = w >> 2;          // 0 = layer 0 group, 1 = layer 1 group
  int ws  = w & 3;           // hidden-slice owner within group

  __shared__ int nod[16];
  __shared__ __align__(16) float  Xs[16*32*32];               // 64 KB
  __shared__ __align__(16) ushort H0h[2][16*64], H1h[2][16*64];

  if (tid < 16){
    int idx = base + tid;
    nod[tid] = mlist[idx < C ? idx : C-1];
  }
  for (int i = tid; i < 16*64; i += 512){
    H0h[0][i] = 0; H0h[1][i] = 0; H1h[0][i] = 0; H1h[1][i] = 0;
  }
  __syncthreads();   // nod ready

  for (int m = tid; m < 4096; m += 512){
    int nm = m >> 8, tt = (m >> 3) & 31, c = m & 7;
    int cs = c ^ (nm & 7);
    f32x4 v = *(const f32x4*)(sim_res + (size_t)nod[nm]*1024 + tt*32 + cs*4);
    *(f32x4*)(Xs + m*4) = v;
  }

  int rr = 16*ws + node;
  h8 zf;
  #pragma unroll
  for (int j=0;j<8;j++) zf[j] = (half_t)0.f;
  h8 Ai_r[2] = {zf, zf}, Ai_z[2] = {zf, zf}, Ai_n[2] = {zf, zf};
  h8 Ah_r[2], Ah_z[2], Ah_n[2];
  if (grp == 0){
    Ai_r[0] = ldw8(Wih0 + (size_t)rr*32        + hi*8);
    Ai_z[0] = ldw8(Wih0 + (size_t)(64+rr)*32   + hi*8);
    Ai_n[0] = ldw8(Wih0 + (size_t)(128+rr)*32  + hi*8);
    #pragma unroll
    for (int s=0;s<2;s++){
      Ah_r[s] = ldw8(Whh0 + (size_t)rr*64       + s*32 + hi*8);
      Ah_z[s] = ldw8(Whh0 + (size_t)(64+rr)*64  + s*32 + hi*8);
      Ah_n[s] = ldw8(Whh0 + (size_t)(128+rr)*64 + s*32 + hi*8);
    }
  } else {
    #pragma unroll
    for (int s=0;s<2;s++){
      Ai_r[s] = ldw8(Wih1 + (size_t)rr*64       + s*32 + hi*8);
      Ai_z[s] = ldw8(Wih1 + (size_t)(64+rr)*64  + s*32 + hi*8);
      Ai_n[s] = ldw8(Wih1 + (size_t)(128+rr)*64 + s*32 + hi*8);
      Ah_r[s] = ldw8(Whh1 + (size_t)rr*64       + s*32 + hi*8);
      Ah_z[s] = ldw8(Whh1 + (size_t)(64+rr)*64  + s*32 + hi*8);
      Ah_n[s] = ldw8(Whh1 + (size_t)(128+rr)*64 + s*32 + hi*8);
    }
  }
  const float* bi = grp ? bih1 : bih0;
  const float* bh = grp ? bhh1 : bhh0;
  float br[4], bz[4], bni[4], bnh[4];
  #pragma unroll
  for (int q=0;q<4;q++){
    int row = 16*ws + hi*4 + q;
    br[q]  = bi[row]      + bh[row];
    bz[q]  = bi[64+row]   + bh[64+row];
    bni[q] = bi[128+row];
    bnh[q] = bh[128+row];
  }

  int T = *seqlen; if (T > 32) T = 32; if (T < 0) T = 0;
  float hm[4] = {0.f, 0.f, 0.f, 0.f};

  const int swz = (node & 7) << 4;
  const int wo  = node * 128;
  const int wba = 32*ws + 8*hi;
  const int rd0 = wo + ((16*hi) ^ swz);
  const int rd1 = wo + ((64 + 16*hi) ^ swz);
  const int xc0 = (2*hi)   ^ (node & 7);
  const int xc1 = (2*hi+1) ^ (node & 7);
  const float* xrow = Xs + node*1024;

  __syncthreads();   // Xs + zeroed state buffers ready

  for (int k = 0; k <= T; ++k){
    int cur = k & 1;
    bool act = grp ? (k >= 1) : (k < T);
    if (act){
      h8 in0 = zf, in1 = zf, st0, st1;
      if (grp == 0){
        f32x4 xa = *(const f32x4*)(xrow + k*32 + xc0*4);
        f32x4 xb = *(const f32x4*)(xrow + k*32 + xc1*4);
        #pragma unroll
        for (int j=0;j<4;j++){ in0[j] = (half_t)xa[j]; in0[4+j] = (half_t)xb[j]; }
        st0 = *(const h8*)((const char*)H0h[cur] + rd0);
        st1 = *(const h8*)((const char*)H0h[cur] + rd1);
      } else {
        in0 = *(const h8*)((const char*)H0h[cur] + rd0);
        in1 = *(const h8*)((const char*)H0h[cur] + rd1);
        st0 = *(const h8*)((const char*)H1h[cur] + rd0);
        st1 = *(const h8*)((const char*)H1h[cur] + rd1);
      }
      f32x4 ar = {br[0],br[1],br[2],br[3]};
      f32x4 az = {bz[0],bz[1],bz[2],bz[3]};
      f32x4 an = {bni[0],bni[1],bni[2],bni[3]};
      f32x4 hn = {bnh[0],bnh[1],bnh[2],bnh[3]};
      ar = mfma_f16(Ai_r[0], in0, ar);
      az = mfma_f16(Ai_z[0], in0, az);
      an = mfma_f16(Ai_n[0], in0, an);
      if (grp){
        ar = mfma_f16(Ai_r[1], in1, ar);
        az = mfma_f16(Ai_z[1], in1, az);
        an = mfma_f16(Ai_n[1], in1, an);
      }
      ar = mfma_f16(Ah_r[0], st0, ar); ar = mfma_f16(Ah_r[1], st1, ar);
      az = mfma_f16(Ah_z[0], st0, az); az = mfma_f16(Ah_z[1], st1, az);
      hn = mfma_f16(Ah_n[0], st0, hn); hn = mfma_f16(Ah_n[1], st1, hn);
      #pragma unroll
      for (int q=0;q<4;q++){
        float r = sigmoidf_(ar[q]);
        float z = sigmoidf_(az[q]);
        float n = tanhf_(an[q] + r*hn[q]);
        hm[q] = (1.f - z)*n + z*hm[q];
      }
      char* outb = grp ? (char*)H1h[cur^1] : (char*)H0h[cur^1];
      *(uint*)(outb + wo + ( wba      ^ swz)) = pkhalf(hm[0], hm[1]);
      *(uint*)(outb + wo + ((wba + 4) ^ swz)) = pkhalf(hm[2], hm[3]);
    }
    __syncthreads();
  }

  if (base + node < C){
    int nd = nod[node];
    int off = grp ? 64 : 0;
    #pragma unroll
    for (int q=0;q<4;q++){
      int j = off + 16*ws + hi*4 + q;
      Hf[(size_t)nd*128 + j] = hm[q];
      Hb[(size_t)nd*128 + j] = f2bf(hm[q]);
    }
  }
}

// ---- CSR build -------------------------------------------------------------------
__global__ __launch_bounds__(1024) void k_scan(const int* __restrict__ deg,
    int* __restrict__ rowptr, int* __restrict__ cursor, int N){
  __shared__ int wsum[16];
  __shared__ int carry_s;
  int tid = threadIdx.x, lane = tid & 63, wid = tid >> 6;
  if (tid == 0) carry_s = 0;
  __syncthreads();
  int nch = (N + 1023) / 1024;
  for (int c=0; c<nch; ++c){
    int i = c*1024 + tid;
    int v = (i < N) ? deg[i] : 0;
    int x = v;
    #pragma unroll
    for (int off=1; off<64; off<<=1){
      int t = __shfl_up(x, off, 64);
      if (lane >= off) x += t;
    }
    if (lane == 63) wsum[wid] = x;
    __syncthreads();
    int base = carry_s;
    int woff = 0;
    for (int w2=0; w2<wid; ++w2) woff += wsum[w2];
    int excl = base + woff + x - v;
    if (i < N){ rowptr[i] = excl; cursor[i] = excl; }
    __syncthreads();
    if (tid == 0){
      int s = 0;
      for (int w2=0; w2<16; ++w2) s += wsum[w2];
      carry_s = base + s;
    }
    __syncthreads();
  }
  if (tid == 0) rowptr[N] = carry_s;
}

__global__ __launch_bounds__(256) void k_scatter(const int* __restrict__ src,
    const int* __restrict__ dst, const int* __restrict__ etype, const int* __restrict__ typ,
    int* __restrict__ cursor, int* __restrict__ es_src, int* __restrict__ es_tab, int E){
  int e = blockIdx.x*256 + threadIdx.x;
  if (e < E){
    int d = dst[e];
    int pos = atomicAdd(&cursor[d], 1);
    es_src[pos] = src[e];
    es_tab[pos] = etype[e]*16 + typ[d];
  }
}

// ---- attention: one wave per dst node, online softmax, 4-edge unrolled -----------
__global__ __launch_bounds__(256) void k_attn(
    const uint* __restrict__ QKV, const uint* __restrict__ KVT,
    const int* __restrict__ rowptr, const int* __restrict__ es_src, const int* __restrict__ es_tab,
    uint* __restrict__ aggr, int N){
  int w = threadIdx.x >> 6, lane = threadIdx.x & 63;
  int dst = blockIdx.x*4 + w;
  if (dst >= N) return;
  uint qu = QKV[(size_t)dst*192 + lane];
  const float scale = 0.08838834764831845f;  // 1/sqrt(128)
  float q0 = bfl(qu)*scale, q1 = bfh(qu)*scale;
  int s0 = rowptr[dst], s1 = rowptr[dst+1];
  float m = -1e30f, den = 0.f, a0 = 0.f, a1 = 0.f;
  int p = s0;
  for (; p + 4 <= s1; p += 4){
    int se[4], te[4];
    #pragma unroll
    for (int e=0;e<4;e++){ se[e] = es_src[p+e]; te[e] = es_tab[p+e]; }
    uint ku[4], kt[4], vu[4], vt[4];
    #pragma unroll
    for (int e=0;e<4;e++){
      ku[e] = QKV[(size_t)se[e]*192 + 64 + lane];
      kt[e] = KVT[(size_t)te[e]*128 + lane];
      vu[e] = QKV[(size_t)se[e]*192 + 128 + lane];
      vt[e] = KVT[(size_t)te[e]*128 + 64 + lane];
    }
    float s[4];
    #pragma unroll
    for (int e=0;e<4;e++)
      s[e] = q0*(bfl(ku[e])+bfl(kt[e])) + q1*(bfh(ku[e])+bfh(kt[e]));
    #pragma unroll
    for (int off=32; off; off>>=1){
      #pragma unroll
      for (int e=0;e<4;e++) s[e] += __shfl_xor(s[e], off);
    }
    float nm = fmaxf(fmaxf(m, fmaxf(s[0], s[1])), fmaxf(s[2], s[3]));
    float c  = __expf(m - nm);
    float pw[4];
    #pragma unroll
    for (int e=0;e<4;e++) pw[e] = __expf(s[e] - nm);
    den = den*c + pw[0] + pw[1] + pw[2] + pw[3];
    a0 = a0*c; a1 = a1*c;
    #pragma unroll
    for (int e=0;e<4;e++){
      a0 += pw[e]*(bfl(vu[e])+bfl(vt[e]));
      a1 += pw[e]*(bfh(vu[e])+bfh(vt[e]));
    }
    m = nm;
  }
  for (; p < s1; ++p){
    int src = es_src[p], tb = es_tab[p];
    uint ku = QKV[(size_t)src*192 + 64 + lane],  kt = KVT[(size_t)tb*128 + lane];
    uint vu = QKV[(size_t)src*192 + 128 + lane], vt = KVT[(size_t)tb*128 + 64 + lane];
    float s = q0*(bfl(ku)+bfl(kt)) + q1*(bfh(ku)+bfh(kt));
    #pragma unroll
    for (int off=32; off; off>>=1) s += __shfl_xor(s, off);
    float nm = fmaxf(m, s);
    float c  = __expf(m - nm);
    float pw = __expf(s - nm);
    den = den*c + pw;
    a0  = a0*c + pw*(bfl(vu)+bfl(vt));
    a1  = a1*c + pw*(bfh(vu)+bfh(vt));
    m = nm;
  }
  float inv = 1.0f/(den + 1e-9f);
  a0 *= inv; a1 *= inv;
  aggr[(size_t)dst*64 + lane] = ((uint)f2bf(a1) << 16) | (uint)f2bf(a0);
}

// ---- fused MLP1 + MLP2 + GRU cell — 8 waves × 16 cols (TLP-doubled) --------------
// NOTE: Hbf aliases Hb_out, Hf_in may alias Hf_out — no __restrict__ on those.
__global__ __launch_bounds__(512, 2) void k_fused(
    const ushort* __restrict__ Ag,
    const ushort* __restrict__ W1b, const float* __restrict__ b1,
    const ushort* __restrict__ W2b, const float* __restrict__ b2,
    const ushort* __restrict__ Wih, const ushort* __restrict__ Whh,
    const float* __restrict__ bih, const float* __restrict__ bhh,
    const ushort* Hbf, const float* Hf_in,
    float* Hf_out, ushort* Hb_out, int M){
  int lane = threadIdx.x & 63, w = threadIdx.x >> 6;   // w: 0..7, 16 cols each
  int nb = blockIdx.x * 32;
  int r16 = lane & 15, kq = lane >> 4;
  const int col = w*16 + r16;                          // 0..127

  __shared__ __align__(16) ushort T[32*128];   // 8 KB swizzled intermediate

  // entry loads (A-operands shared across phases)
  bf8 agld[2][4], ahld[2][4];
  #pragma unroll
  for (int i=0;i<2;i++){
    int grow = nb + i*16 + r16; if (grow > M-1) grow = M-1;
    #pragma unroll
    for (int ks=0;ks<4;ks++){
      agld[i][ks] = *(const bf8*)(Ag  + (size_t)grow*128 + ks*32 + kq*8);
      ahld[i][ks] = *(const bf8*)(Hbf + (size_t)grow*128 + ks*32 + kq*8);
    }
  }
  float hprev[2][4];
  #pragma unroll
  for (int i=0;i<2;i++)
    #pragma unroll
    for (int q=0;q<4;q++){
      int node = nb + i*16 + kq*4 + q;
      hprev[i][q] = Hf_in[(size_t)(node < M ? node : M-1)*128 + col];
    }

  // ---------- phase 1: T = relu(Ag @ W1^T + b1) ----------
  {
    f32x4 a0 = (f32x4)0.0f, a1v = (f32x4)0.0f;
    #pragma unroll
    for (int ks=0; ks<4; ++ks){
      bf8 wb = *(const bf8*)(W1b + (size_t)col*128 + ks*32 + kq*8);
      a0  = mfma_bf(agld[0][ks], wb, a0);
      a1v = mfma_bf(agld[1][ks], wb, a1v);
    }
    float bs = b1[col];
    #pragma unroll
    for (int q=0;q<4;q++){
      int row0 = kq*4 + q, row1 = 16 + kq*4 + q;
      *(ushort*)((char*)T + ((row0*256 + col*2) ^ ((row0&7)<<4))) = f2bf(fmaxf(a0[q]  + bs, 0.0f));
      *(ushort*)((char*)T + ((row1*256 + col*2) ^ ((row1&7)<<4))) = f2bf(fmaxf(a1v[q] + bs, 0.0f));
    }
  }
  __syncthreads();

  // ---------- phase 2: X = T @ W2^T + b2 ----------
  {
    f32x4 a0 = (f32x4)0.0f, a1v = (f32x4)0.0f;
    #pragma unroll
    for (int ks=0; ks<4; ++ks){
      bf8 wb = *(const bf8*)(W2b + (size_t)col*128 + ks*32 + kq*8);
      bf8 ax0, ax1;
      {
        int row = r16;
        ax0 = *(const bf8*)((const char*)T + row*256 + ((ks*64 + kq*16) ^ ((row&7)<<4)));
      }
      {
        int row = 16 + r16;
        ax1 = *(const bf8*)((const char*)T + row*256 + ((ks*64 + kq*16) ^ ((row&7)<<4)));
      }
      a0  = mfma_bf(ax0, wb, a0);
      a1v = mfma_bf(ax1, wb, a1v);
    }
    __syncthreads();   // all T reads complete before overwrite
    float bs = b2[col];
    #pragma unroll
    for (int q=0;q<4;q++){
      int row0 = kq*4 + q, row1 = 16 + kq*4 + q;
      *(ushort*)((char*)T + ((row0*256 + col*2) ^ ((row0&7)<<4))) = f2bf(a0[q]  + bs);
      *(ushort*)((char*)T + ((row1*256 + col*2) ^ ((row1&7)<<4))) = f2bf(a1v[q] + bs);
    }
  }
  __syncthreads();

  // ---------- phase 3: GRU gates ----------
  f32x4 ar[2], az[2], ani[2], anh[2];
  #pragma unroll
  for (int i=0;i<2;i++){
    ar[i] = (f32x4)0.0f; az[i] = (f32x4)0.0f;
    ani[i] = (f32x4)0.0f; anh[i] = (f32x4)0.0f;
  }
  #pragma unroll
  for (int ks=0; ks<4; ++ks){
    int off = ks*32 + kq*8;
    bf8 wri = *(const bf8*)(Wih + (size_t)col*128       + off);
    bf8 wrh = *(const bf8*)(Whh + (size_t)col*128       + off);
    bf8 wzi = *(const bf8*)(Wih + (size_t)(128+col)*128 + off);
    bf8 wzh = *(const bf8*)(Whh + (size_t)(128+col)*128 + off);
    bf8 wni = *(const bf8*)(Wih + (size_t)(256+col)*128 + off);
    bf8 wnh = *(const bf8*)(Whh + (size_t)(256+col)*128 + off);
    bf8 ax0, ax1;
    {
      int row = r16;
      ax0 = *(const bf8*)((const char*)T + row*256 + ((ks*64 + kq*16) ^ ((row&7)<<4)));
    }
    {
      int row = 16 + r16;
      ax1 = *(const bf8*)((const char*)T + row*256 + ((ks*64 + kq*16) ^ ((row&7)<<4)));
    }
    ar[0]  = mfma_bf(ax0,         wri, ar[0]);
    ar[0]  = mfma_bf(ahld[0][ks], wrh, ar[0]);
    az[0]  = mfma_bf(ax0,         wzi, az[0]);
    az[0]  = mfma_bf(ahld[0][ks], wzh, az[0]);
    ani[0] = mfma_bf(ax0,         wni, ani[0]);
    anh[0] = mfma_bf(ahld[0][ks], wnh, anh[0]);
    ar[1]  = mfma_bf(ax1,         wri, ar[1]);
    ar[1]  = mfma_bf(ahld[1][ks], wrh, ar[1]);
    az[1]  = mfma_bf(ax1,         wzi, az[1]);
    az[1]  = mfma_bf(ahld[1][ks], wzh, az[1]);
    ani[1] = mfma_bf(ax1,         wni, ani[1]);
    anh[1] = mfma_bf(ahld[1][ks], wnh, anh[1]);
  }
  // epilogue: gates + in-lane h update (each block owns its 32 rows exclusively;
  // all Hbf/Hf_in reads happened at entry)
  float br_  = bih[col]     + bhh[col];
  float bz_  = bih[128+col] + bhh[128+col];
  float bni_ = bih[256+col];
  float bnh_ = bhh[256+col];
  #pragma unroll
  for (int i=0;i<2;i++)
    #pragma unroll
    for (int q=0;q<4;q++){
      int node = nb + i*16 + kq*4 + q;
      if (node < M){
        float r = sigmoidf_(ar[i][q] + br_);
        float z = sigmoidf_(az[i][q] + bz_);
        float n = tanhf_(ani[i][q] + bni_ + r*(anh[i][q] + bnh_));
        float h = hprev[i][q];
        float o = (1.f - z)*n + z*h;
        Hf_out[(size_t)node*128 + col] = o;
        Hb_out[(size_t)node*128 + col] = f2bf(o);
      }
    }
}

extern "C" void kernel_launch(void* const* d_in, const int* in_sizes, int n_in,
                              void* d_out, int out_size, void* d_ws, size_t ws_size,
                              hipStream_t stream){
  const float* x       = (const float*)d_in[0];
  const int*   ei      = (const int*)d_in[1];
  const int*   etype   = (const int*)d_in[2];
  const float* sim_res = (const float*)d_in[3];
  const int*   seqlen  = (const int*)d_in[4];
  const float* eWih0 = (const float*)d_in[5];
  const float* eWhh0 = (const float*)d_in[6];
  const float* ebih0 = (const float*)d_in[7];
  const float* ebhh0 = (const float*)d_in[8];
  const float* eWih1 = (const float*)d_in[9];
  const float* eWhh1 = (const float*)d_in[10];
  const float* ebih1 = (const float*)d_in[11];
  const float* ebhh1 = (const float*)d_in[12];
  const float* Wq = (const float*)d_in[13];
  const float* Wk = (const float*)d_in[14];
  const float* Wv = (const float*)d_in[15];
  const float* op_emb = (const float*)d_in[16];
  const float* W1 = (const float*)d_in[17];
  const float* b1 = (const float*)d_in[18];
  const float* W2 = (const float*)d_in[19];
  const float* b2 = (const float*)d_in[20];
  const float* gWih = (const float*)d_in[21];
  const float* gWhh = (const float*)d_in[22];
  const float* gbih = (const float*)d_in[23];
  const float* gbhh = (const float*)d_in[24];

  const int N = in_sizes[0] / 16;
  const int E = in_sizes[2];

  char* p = (char*)d_ws;
  auto take = [&](size_t b)->void*{ void* r = (void*)p; p += (b + 255) & ~(size_t)255; return r; };

  float*  Hf    = (float*) take((size_t)N*128*4);
  ushort* Hb    = (ushort*)take((size_t)N*128*2);
  ushort* QKV   = (ushort*)take((size_t)N*384*2);
  ushort* Ag    = (ushort*)take((size_t)N*128*2);
  ushort* EF    = (ushort*)take((size_t)512*128*2);
  ushort* KVtab = (ushort*)take((size_t)512*256*2);
  ushort* wqkv  = (ushort*)take((size_t)3*16384*2);   // [wq | wk | wv] rows
  ushort* w1_b  = (ushort*)take((size_t)16384*2);
  ushort* w2_b  = (ushort*)take((size_t)16384*2);
  ushort* wih_b = (ushort*)take((size_t)49152*2);
  ushort* whh_b = (ushort*)take((size_t)49152*2);
  int* typ    = (int*)take((size_t)N*4);
  int* mlist  = (int*)take((size_t)N*4);
  int* cnt    = (int*)take(256);
  int* deg    = (int*)take((size_t)N*4);
  int* rowptr = (int*)take((size_t)(N+1)*4);
  int* cursor = (int*)take((size_t)N*4);
  int* es_src = (int*)take((size_t)E*4);
  int* es_tab = (int*)take((size_t)E*4);

  hipMemsetAsync(cnt, 0, 4, stream);
  hipMemsetAsync(deg, 0, (size_t)N*4, stream);

  int gE = (E + 255) / 256;
  k_prep<<<gE, 256, 0, stream>>>(x, ei + E, typ, mlist, cnt, deg, Hf, Hb, N, E);
  k_cvt<<<256, 256, 0, stream>>>(Wq, Wk, Wv, W1, W2, gWih, gWhh, op_emb,
                                 wqkv, w1_b, w2_b, wih_b, whh_b, EF);
  k_gemm<0,0><<<dim3(8,4), 256, 0, stream>>>(EF, wqkv + 16384, nullptr, KVtab, 512, 256);
  k_enc4<<<(N+15)/16, 512, 0, stream>>>(sim_res, seqlen, eWih0, eWhh0, ebih0, ebhh0,
                                        eWih1, eWhh1, ebih1, ebhh1, mlist, cnt, Hf, Hb);
  k_scan<<<1, 1024, 0, stream>>>(deg, rowptr, cursor, N);
  k_scatter<<<gE, 256, 0, stream>>>(ei, ei + E, etype, typ, cursor, es_src, es_tab, E);

  dim3 gq((N+63)/64, 6);   // fused QKV: N_out = 384
  for (int r=0; r<2; ++r){
    k_gemm<0,0><<<gq, 256, 0, stream>>>(Hb, wqkv, nullptr, QKV, N, 384);
    k_attn<<<(N+3)/4, 256, 0, stream>>>((const uint*)QKV, (const uint*)KVtab,
                                        rowptr, es_src, es_tab, (uint*)Ag, N);
    float* hf_out = (r == 1) ? (float*)d_out : Hf;
    k_fused<<<(N+31)/32, 512, 0, stream>>>(Ag, w1_b, b1, w2_b, b2,
                                           wih_b, whh_b, gbih, gbhh,
                                           Hb, Hf, hf_out, Hb, N);
  }
}